// Round 4
// baseline (2004.129 us; speedup 1.0000x reference)
//
#include <hip/hip_runtime.h>
#include <math.h>

#define N     50000
#define F_IN  128
#define HID   256
#define E     800000
#define OUTD  64
#define NEG   0.2f
#define N8    (N * 8)
#define NTOT  (4 * N)

// hierarchical scan geometry
#define SC_TPB   256
#define SC_PERB  2048
#define SC_NB    ((NTOT + SC_PERB - 1) / SC_PERB)   // 98

// bucket sort geometry
#define BSH   7                      // bucket = dst >> 7 (128 dsts/bucket)
#define NBUK  ((N + 127) / 128)      // 391
#define NBT   (4 * NBUK)             // 1564
#define EPB1  4096
#define NB1   ((E + EPB1 - 1) / EPB1) // 196

typedef float4 f4;
typedef unsigned int u32;
typedef unsigned short ush;
typedef float f32x4 __attribute__((ext_vector_type(4)));
typedef short bf16x8 __attribute__((ext_vector_type(8)));

static __device__ __forceinline__ float lrelu(float x) { return x >= 0.f ? x : NEG * x; }
static __device__ __forceinline__ u32 bfr(float x) {
  u32 u = __float_as_uint(x);
  return (u + 0x7fffu + ((u >> 16) & 1u)) >> 16;
}
static __device__ __forceinline__ u32 pk2(float a, float b) { return bfr(a) | (bfr(b) << 16); }
static __device__ __forceinline__ float bf2f(u32 us) { return __uint_as_float(us << 16); }

// ---------------------------------------------------------------------------
// Projection + fused per-node attention scores.
// ---------------------------------------------------------------------------
__global__ __launch_bounds__(256) void proj_kernel(
    const float* __restrict__ x, const float* __restrict__ W, const float* __restrict__ b,
    const float* __restrict__ a0, const float* __restrict__ a1,
    const float* __restrict__ a2, const float* __restrict__ a3,
    ush* __restrict__ hb, float* __restrict__ sdst)
{
  __shared__ float xT[F_IN * 16];   // [k][i]
  const int t = threadIdx.x;
  const int base = blockIdx.x * 16;
  for (int idx = t; idx < 16 * F_IN; idx += 256) {
    int r = idx & 15, c = idx >> 4;
    xT[c * 16 + r] = x[(size_t)(base + r) * F_IN + c];
  }
  __syncthreads();
  const int ig = t >> 6;
  const int lane = t & 63;
  const int j0 = lane * 4;
  float acc[4][4] = {};
  for (int k = 0; k < F_IN; ++k) {
    f4 w  = *(const f4*)&W[k * HID + j0];
    f4 xv = *(const f4*)&xT[k * 16 + ig * 4];
    const float wa[4] = {w.x, w.y, w.z, w.w};
    const float xa[4] = {xv.x, xv.y, xv.z, xv.w};
#pragma unroll
    for (int i = 0; i < 4; ++i)
#pragma unroll
      for (int j = 0; j < 4; ++j) acc[i][j] = fmaf(xa[i], wa[j], acc[i][j]);
  }
  f4 bv = *(const f4*)&b[j0];
  const float ba[4] = {bv.x, bv.y, bv.z, bv.w};
#pragma unroll
  for (int i = 0; i < 4; ++i) {
#pragma unroll
    for (int j = 0; j < 4; ++j) acc[i][j] += ba[j];
    ushort4 o;
    o.x = (ush)bfr(acc[i][0]); o.y = (ush)bfr(acc[i][1]);
    o.z = (ush)bfr(acc[i][2]); o.w = (ush)bfr(acc[i][3]);
    *(ushort4*)&hb[(size_t)(base + ig * 4 + i) * HID + j0] = o;
  }
  const int head = lane >> 3;
  const float* av[4] = {a0, a1, a2, a3};
#pragma unroll
  for (int k = 0; k < 4; ++k) {
    f4 a = *(const f4*)&av[k][j0];
#pragma unroll
    for (int i = 0; i < 4; ++i) {
      float p = acc[i][0] * a.x + acc[i][1] * a.y + acc[i][2] * a.z + acc[i][3] * a.w;
      p += __shfl_xor(p, 1);
      p += __shfl_xor(p, 2);
      p += __shfl_xor(p, 4);
      if ((lane & 7) == 0)
        sdst[(size_t)k * N8 + (size_t)(base + ig * 4 + i) * 8 + head] = p;
    }
  }
}

// ---------------------------------------------------------------------------
__global__ void wkt_kernel(const float* __restrict__ Wk, ush* __restrict__ wkT)
{
  int idx = blockIdx.x * 256 + threadIdx.x;
  int n = idx >> 8, k = idx & 255;
  wkT[idx] = (ush)bfr(Wk[k * HID + n]);
}

// ---------------------------------------------------------------------------
// CSR build, two-level binning (kills scatter write amplification):
//  histB  : bucket histogram (LDS-aggregated)
//  bscan  : exclusive scan of 1564 bucket counts -> bstart, bcur
//  scat   : edges -> bucket staging (packed dst<<16|src) + fine count atomics
//  scanA/B/C : fine exclusive scan -> start
//  fillb  : per-bucket LDS-cursor fill of csr (hot 8KB region, no global atomics)
// ---------------------------------------------------------------------------
__global__ __launch_bounds__(256) void histb_kernel(
    const int* __restrict__ d0, const int* __restrict__ d1,
    const int* __restrict__ d2, const int* __restrict__ d3,
    int* __restrict__ bcnt)
{
  __shared__ int lh[NBUK];
  const int rel = blockIdx.x / NB1;
  const int blk = blockIdx.x % NB1;
  for (int j = threadIdx.x; j < NBUK; j += 256) lh[j] = 0;
  __syncthreads();
  const int* dp = rel == 0 ? d0 : rel == 1 ? d1 : rel == 2 ? d2 : d3;
  const int base = blk * EPB1;
#pragma unroll
  for (int k = 0; k < EPB1 / 256; ++k) {
    int i = base + k * 256 + threadIdx.x;
    if (i < E) atomicAdd(&lh[dp[i] >> BSH], 1);
  }
  __syncthreads();
  for (int j = threadIdx.x; j < NBUK; j += 256)
    if (lh[j]) atomicAdd(&bcnt[rel * NBUK + j], lh[j]);
}

__global__ __launch_bounds__(256) void bscan_kernel(
    const int* __restrict__ bcnt, int* __restrict__ bstart, int* __restrict__ bcur)
{
  __shared__ int part[256];
  const int t = threadIdx.x;
  const int chunk = (NBT + 255) / 256;   // 7
  const int b = t * chunk;
  const int e = min(NBT, b + chunk);
  int s = 0;
  for (int i = b; i < e; ++i) s += bcnt[i];
  part[t] = s;
  __syncthreads();
  for (int off = 1; off < 256; off <<= 1) {
    int u = (t >= off) ? part[t - off] : 0;
    __syncthreads();
    part[t] += u;
    __syncthreads();
  }
  int run = part[t] - s;
  for (int i = b; i < e; ++i) {
    bstart[i] = run;
    bcur[i] = run;
    run += bcnt[i];
  }
}

#define EB (E / 256)
__global__ void scat_kernel(const int* __restrict__ s0, const int* __restrict__ d0,
                            const int* __restrict__ s1, const int* __restrict__ d1,
                            const int* __restrict__ s2, const int* __restrict__ d2,
                            const int* __restrict__ s3, const int* __restrict__ d3,
                            int* __restrict__ bcur, int* __restrict__ count,
                            u32* __restrict__ bstage)
{
  int blk = blockIdx.x;
  int rel = blk / EB;
  int i = (blk % EB) * 256 + threadIdx.x;
  const int* sp = rel == 0 ? s0 : rel == 1 ? s1 : rel == 2 ? s2 : s3;
  const int* dp = rel == 0 ? d0 : rel == 1 ? d1 : rel == 2 ? d2 : d3;
  int src = sp[i], dst = dp[i];
  atomicAdd(&count[rel * N + dst], 1);
  int pos = atomicAdd(&bcur[rel * NBUK + (dst >> BSH)], 1);
  bstage[pos] = ((u32)dst << 16) | (u32)src;
}

__global__ __launch_bounds__(SC_TPB) void scanA_kernel(
    const int* __restrict__ count, int* __restrict__ bsum)
{
  __shared__ int red[4];
  const int t = threadIdx.x;
  const int base = blockIdx.x * SC_PERB + t * 8;
  int s = 0;
  if (base + 8 <= NTOT) {
    int4 a = *(const int4*)&count[base];
    int4 b = *(const int4*)&count[base + 4];
    s = a.x + a.y + a.z + a.w + b.x + b.y + b.z + b.w;
  } else {
    for (int i = 0; i < 8; ++i) { int idx = base + i; if (idx < NTOT) s += count[idx]; }
  }
#pragma unroll
  for (int off = 1; off < 64; off <<= 1) s += __shfl_xor(s, off);
  if ((t & 63) == 0) red[t >> 6] = s;
  __syncthreads();
  if (t == 0) bsum[blockIdx.x] = red[0] + red[1] + red[2] + red[3];
}

__global__ __launch_bounds__(128) void scanB_kernel(int* __restrict__ bsum)
{
  __shared__ int tmp[128];
  const int t = threadIdx.x;
  int v = (t < SC_NB) ? bsum[t] : 0;
  tmp[t] = v;
  __syncthreads();
  for (int off = 1; off < 128; off <<= 1) {
    int u = (t >= off) ? tmp[t - off] : 0;
    __syncthreads();
    tmp[t] += u;
    __syncthreads();
  }
  if (t < SC_NB) bsum[t] = tmp[t] - v;  // exclusive
}

__global__ __launch_bounds__(SC_TPB) void scanC_kernel(
    const int* __restrict__ count, const int* __restrict__ bsum,
    int* __restrict__ start)
{
  __shared__ int ts[SC_TPB];
  const int t = threadIdx.x;
  const int base = blockIdx.x * SC_PERB + t * 8;
  int c[8];
  int s = 0;
#pragma unroll
  for (int i = 0; i < 8; ++i) {
    int idx = base + i;
    c[i] = (idx < NTOT) ? count[idx] : 0;
    s += c[i];
  }
  ts[t] = s;
  __syncthreads();
  for (int off = 1; off < SC_TPB; off <<= 1) {
    int u = (t >= off) ? ts[t - off] : 0;
    __syncthreads();
    ts[t] += u;
    __syncthreads();
  }
  int run = ts[t] - s + bsum[blockIdx.x];
#pragma unroll
  for (int i = 0; i < 8; ++i) {
    int idx = base + i;
    if (idx < NTOT) {
      start[idx] = run;
      run += c[i];
    }
  }
}

__global__ __launch_bounds__(256) void fillb_kernel(
    const u32* __restrict__ bstage, const int* __restrict__ bstart,
    const int* __restrict__ bcnt, const int* __restrict__ start,
    int* __restrict__ csr)
{
  __shared__ int lcur[128];
  const int bb = blockIdx.x;           // rel*NBUK + b
  const int rel = bb / NBUK, b = bb % NBUK;
  const int fb = rel * N + b * 128;
  const int lim = min(128, N - b * 128);
  if (threadIdx.x < lim) lcur[threadIdx.x] = start[fb + threadIdx.x];
  __syncthreads();
  const int rb = bstart[bb];
  const int cnt = bcnt[bb];
  for (int k = threadIdx.x; k < cnt; k += 256) {
    u32 pk = bstage[rb + k];
    int ldst = (pk >> 16) & 127;
    int pos = atomicAdd(&lcur[ldst], 1);
    csr[pos] = (int)(pk & 0xffffu);
  }
}

// ---------------------------------------------------------------------------
// Relation conv, bf16 row gathers (512B/edge), fp32 accumulate, 2-edge unroll.
// ---------------------------------------------------------------------------
__global__ __launch_bounds__(256) void conv_kernel(
    const ush* __restrict__ xsb, const float* __restrict__ ss,
    const float* __restrict__ sd, const int* __restrict__ csr,
    const int* __restrict__ start, const int* __restrict__ count,
    float* __restrict__ z)
{
  const int dst = blockIdx.x * 4 + (threadIdx.x >> 6);
  const int lane = threadIdx.x & 63;
  const int e0 = start[dst];
  const int ne = count[dst];

  const int h1 = lane & 7;
  const float sdv1 = sd[dst * 8 + h1];
  float den = 0.f;
  for (int j = lane >> 3; j < ne; j += 8)
    den += __expf(lrelu(ss[csr[e0 + j] * 8 + h1] + sdv1));
  den += __shfl_xor(den, 8);
  den += __shfl_xor(den, 16);
  den += __shfl_xor(den, 32);
  const int h2 = lane >> 3;
  const float inv_den = 1.f / (__shfl(den, h2) + 1e-16f);
  const float sdv2 = sd[dst * 8 + h2];

  float a0 = 0.f, a1 = 0.f, a2 = 0.f, a3 = 0.f;
  int j = 0;
  for (; j + 2 <= ne; j += 2) {
    int sA = csr[e0 + j], sB = csr[e0 + j + 1];
    float lA = ss[sA * 8 + h2], lB = ss[sB * 8 + h2];
    ushort4 vA = *(const ushort4*)&xsb[(size_t)sA * HID + lane * 4];
    ushort4 vB = *(const ushort4*)&xsb[(size_t)sB * HID + lane * 4];
    float alA = __expf(lrelu(lA + sdv2)) * inv_den;
    float alB = __expf(lrelu(lB + sdv2)) * inv_den;
    a0 = fmaf(alA, bf2f(vA.x), a0);
    a1 = fmaf(alA, bf2f(vA.y), a1);
    a2 = fmaf(alA, bf2f(vA.z), a2);
    a3 = fmaf(alA, bf2f(vA.w), a3);
    a0 = fmaf(alB, bf2f(vB.x), a0);
    a1 = fmaf(alB, bf2f(vB.y), a1);
    a2 = fmaf(alB, bf2f(vB.z), a2);
    a3 = fmaf(alB, bf2f(vB.w), a3);
  }
  if (j < ne) {
    int sA = csr[e0 + j];
    float alA = __expf(lrelu(ss[sA * 8 + h2] + sdv2)) * inv_den;
    ushort4 vA = *(const ushort4*)&xsb[(size_t)sA * HID + lane * 4];
    a0 = fmaf(alA, bf2f(vA.x), a0);
    a1 = fmaf(alA, bf2f(vA.y), a1);
    a2 = fmaf(alA, bf2f(vA.z), a2);
    a3 = fmaf(alA, bf2f(vA.w), a3);
  }
  f4 o = {fmaxf(a0, 0.f), fmaxf(a1, 0.f), fmaxf(a2, 0.f), fmaxf(a3, 0.f)};
  *(f4*)&z[(size_t)dst * HID + lane * 4] = o;
}

// ---------------------------------------------------------------------------
// Semantic scores via bf16 MFMA 16x16x32.
// ---------------------------------------------------------------------------
__global__ __launch_bounds__(256) void semscore_kernel(
    const float* __restrict__ z0, const float* __restrict__ z1,
    const ush* __restrict__ wkT, const float* __restrict__ bk,
    const float* __restrict__ q, float* __restrict__ score)
{
  __shared__ u32 Bs[8192];
  __shared__ u32 As0[2048];
  __shared__ u32 As1[2048];
  const int t = threadIdx.x;
  const int base = blockIdx.x * 64;
  const int w = t >> 6;
  const int l = t & 63;
  const int lrow = l & 15;
  const int kgrp = l >> 4;

  f32x4 acc0[16], acc1[16];
  const f32x4 zz = {0.f, 0.f, 0.f, 0.f};
#pragma unroll
  for (int nt = 0; nt < 16; ++nt) { acc0[nt] = zz; acc1[nt] = zz; }

  for (int kc = 0; kc < 4; ++kc) {
#pragma unroll
    for (int it = 0; it < 8; ++it) {
      int cid = it * 256 + t;
      int n = cid >> 3, g = cid & 7;
      uint4 v = *(const uint4*)&wkT[n * HID + kc * 64 + g * 8];
      *(uint4*)&Bs[(n * 32 + g * 4) ^ ((n & 7) << 2)] = v;
    }
#pragma unroll
    for (int m = 0; m < 2; ++m) {
      const float* zp = m ? z1 : z0;
      u32* ap = m ? As1 : As0;
#pragma unroll
      for (int it = 0; it < 2; ++it) {
        int cid = it * 256 + t;
        int r = cid >> 3, g = cid & 7;
        int gr = base + r;
        if (gr >= N) gr = N - 1;
        const float* sp = &zp[(size_t)gr * HID + kc * 64 + g * 8];
        f4 v0 = *(const f4*)sp;
        f4 v1 = *(const f4*)(sp + 4);
        int di = (r * 32 + g * 4) ^ ((r & 7) << 2);
        ap[di + 0] = pk2(v0.x, v0.y);
        ap[di + 1] = pk2(v0.z, v0.w);
        ap[di + 2] = pk2(v1.x, v1.y);
        ap[di + 3] = pk2(v1.z, v1.w);
      }
    }
    __syncthreads();
#pragma unroll
    for (int kk = 0; kk < 2; ++kk) {
      int ai = ((w * 16 + lrow) * 32 + kk * 16 + kgrp * 4) ^ ((lrow & 7) << 2);
      bf16x8 af0 = *(const bf16x8*)&As0[ai];
      bf16x8 af1 = *(const bf16x8*)&As1[ai];
#pragma unroll
      for (int nt = 0; nt < 16; ++nt) {
        int n = nt * 16 + lrow;
        int bi = (n * 32 + kk * 16 + kgrp * 4) ^ ((n & 7) << 2);
        bf16x8 bf = *(const bf16x8*)&Bs[bi];
        acc0[nt] = __builtin_amdgcn_mfma_f32_16x16x32_bf16(af0, bf, acc0[nt], 0, 0, 0);
        acc1[nt] = __builtin_amdgcn_mfma_f32_16x16x32_bf16(af1, bf, acc1[nt], 0, 0, 0);
      }
    }
    __syncthreads();
  }

  float s0 = 0.f, s1 = 0.f;
#pragma unroll
  for (int nt = 0; nt < 16; ++nt) {
    int col = nt * 16 + lrow;
    float bkv = bk[col], qv = q[col];
#pragma unroll
    for (int i = 0; i < 4; ++i) {
      int gr = base + w * 16 + kgrp * 4 + i;
      if (gr < N) {
        s0 += tanhf(acc0[nt][i] + bkv) * qv;
        s1 += tanhf(acc1[nt][i] + bkv) * qv;
      }
    }
  }
#pragma unroll
  for (int off = 1; off < 64; off <<= 1) {
    s0 += __shfl_xor(s0, off);
    s1 += __shfl_xor(s1, off);
  }
  if (l == 0) {
    atomicAdd(&score[0], s0);
    atomicAdd(&score[1], s1);
  }
}

__global__ void attn_kernel(float* __restrict__ score, float inv_n)
{
  float s0 = score[0] * inv_n, s1 = score[1] * inv_n;
  float m = fmaxf(s0, s1);
  float e0 = __expf(s0 - m), e1 = __expf(s1 - m);
  float d = e0 + e1;
  score[2] = e0 / d;
  score[3] = e1 / d;
}

// ---------------------------------------------------------------------------
__global__ __launch_bounds__(256) void final_kernel(
    const float* __restrict__ z0, const float* __restrict__ z1,
    const float* __restrict__ attn, const float* __restrict__ Wl,
    const float* __restrict__ bl, float* __restrict__ out)
{
  __shared__ float zT[HID * 16];
  const int t = threadIdx.x;
  const int base = blockIdx.x * 16;
  const float a0 = attn[0], a1 = attn[1];
  for (int idx = t; idx < 16 * HID; idx += 256) {
    int r = idx & 15, c = idx >> 4;
    zT[c * 16 + r] = a0 * z0[(size_t)(base + r) * HID + c]
                   + a1 * z1[(size_t)(base + r) * HID + c];
  }
  __syncthreads();
  const int ig = t >> 6;
  const int cc = t & 63;
  float acc[4] = {};
  for (int k = 0; k < HID; ++k) {
    float w = Wl[k * OUTD + cc];
    f4 xv = *(const f4*)&zT[k * 16 + ig * 4];
    acc[0] = fmaf(xv.x, w, acc[0]);
    acc[1] = fmaf(xv.y, w, acc[1]);
    acc[2] = fmaf(xv.z, w, acc[2]);
    acc[3] = fmaf(xv.w, w, acc[3]);
  }
  float bb = bl[cc];
#pragma unroll
  for (int i = 0; i < 4; ++i)
    out[(size_t)(base + ig * 4 + i) * OUTD + cc] = acc[i] + bb;
}

// ---------------------------------------------------------------------------
extern "C" void kernel_launch(void* const* d_in, const int* in_sizes, int n_in,
                              void* d_out, int out_size, void* d_ws, size_t ws_size,
                              hipStream_t stream)
{
  const float* x_user = (const float*)d_in[0];
  const float* x_item = (const float*)d_in[1];
  const int*   e_ui   = (const int*)d_in[2];
  const int*   e_iu   = (const int*)d_in[3];
  const int*   e_uu   = (const int*)d_in[4];
  const int*   e_ii   = (const int*)d_in[5];
  const float* Wp_u   = (const float*)d_in[6];
  const float* bp_u   = (const float*)d_in[7];
  const float* Wp_i   = (const float*)d_in[8];
  const float* bp_i   = (const float*)d_in[9];
  const float* as_ui  = (const float*)d_in[10];
  const float* ad_ui  = (const float*)d_in[11];
  const float* as_iu  = (const float*)d_in[12];
  const float* ad_iu  = (const float*)d_in[13];
  const float* as_uu  = (const float*)d_in[14];
  const float* ad_uu  = (const float*)d_in[15];
  const float* as_ii  = (const float*)d_in[16];
  const float* ad_ii  = (const float*)d_in[17];
  const float* Wk     = (const float*)d_in[18];
  const float* bk     = (const float*)d_in[19];
  const float* q      = (const float*)d_in[20];
  const float* Wl     = (const float*)d_in[21];
  const float* bl     = (const float*)d_in[22];

  const size_t NH = (size_t)N * HID;
  size_t need = (2 * NH + 8 * (size_t)N8 + 4) * 4            // z0,z1,su,si,sc
              + (2 * NH + HID * HID) * 2                     // hub,hib,wkT
              + ((size_t)8 * N + 4 * (size_t)E + 3 * NBT + 128 + 64) * 4;
  if (ws_size < need) {
    hipMemsetAsync(d_out, 0x7f, (size_t)out_size * sizeof(float), stream);
    return;
  }
  float* z0 = (float*)d_ws;
  float* z1 = z0 + NH;
  float* su = z1 + NH;
  float* si = su + 4 * (size_t)N8;
  float* sc = si + 4 * (size_t)N8;
  ush* hub  = (ush*)(sc + 4);
  ush* hib  = hub + NH;
  ush* wkT  = hib + NH;
  int* count  = (int*)(wkT + HID * HID);
  int* bcnt   = count + NTOT;       // adjacent to count -> single memset
  int* start  = bcnt + NBT;
  int* bstart = start + NTOT;
  int* bcur   = bstart + NBT;
  int* bsum   = bcur + NBT;
  int* csr    = bsum + 128;
  u32* bstage = (u32*)z0;           // aliases z0 (dead until first conv)

  float* out_u = (float*)d_out;
  float* out_i = out_u + (size_t)N * OUTD;

  wkt_kernel<<<HID * HID / 256, 256, 0, stream>>>(Wk, wkT);

  proj_kernel<<<N / 16, 256, 0, stream>>>(x_user, Wp_u, bp_u,
                                          ad_iu, as_uu, ad_uu, as_ui, hub, su);
  proj_kernel<<<N / 16, 256, 0, stream>>>(x_item, Wp_i, bp_i,
                                          as_iu, ad_ui, as_ii, ad_ii, hib, si);

  // batched CSR build via two-level binning: rel 0=iu, 1=uu, 2=ui, 3=ii
  hipMemsetAsync(count, 0, (NTOT + NBT) * sizeof(int), stream);
  histb_kernel<<<4 * NB1, 256, 0, stream>>>(e_iu + E, e_uu + E, e_ui + E, e_ii + E, bcnt);
  bscan_kernel<<<1, 256, 0, stream>>>(bcnt, bstart, bcur);
  scat_kernel<<<4 * EB, 256, 0, stream>>>(e_iu, e_iu + E, e_uu, e_uu + E,
                                          e_ui, e_ui + E, e_ii, e_ii + E,
                                          bcur, count, bstage);
  scanA_kernel<<<SC_NB, SC_TPB, 0, stream>>>(count, bsum);
  scanB_kernel<<<1, 128, 0, stream>>>(bsum);
  scanC_kernel<<<SC_NB, SC_TPB, 0, stream>>>(count, bsum, start);
  fillb_kernel<<<NBT, 256, 0, stream>>>(bstage, bstart, bcnt, start, csr);

  const int SEMG = (N + 63) / 64;

  // ---- user side
  conv_kernel<<<N / 4, 256, 0, stream>>>(hib, si, su, csr, start, count, z0);
  conv_kernel<<<N / 4, 256, 0, stream>>>(hub, su + N8, su + 2 * (size_t)N8, csr,
                                         start + N, count + N, z1);
  hipMemsetAsync(sc, 0, 2 * sizeof(float), stream);
  semscore_kernel<<<SEMG, 256, 0, stream>>>(z0, z1, wkT, bk, q, sc);
  attn_kernel<<<1, 1, 0, stream>>>(sc, 1.0f / (float)N);
  final_kernel<<<N / 16, 256, 0, stream>>>(z0, z1, sc + 2, Wl, bl, out_u);

  // ---- item side
  conv_kernel<<<N / 4, 256, 0, stream>>>(hub, su + 3 * (size_t)N8, si + N8, csr,
                                         start + 2 * N, count + 2 * N, z0);
  conv_kernel<<<N / 4, 256, 0, stream>>>(hib, si + 2 * (size_t)N8, si + 3 * (size_t)N8, csr,
                                         start + 3 * N, count + 3 * N, z1);
  hipMemsetAsync(sc, 0, 2 * sizeof(float), stream);
  semscore_kernel<<<SEMG, 256, 0, stream>>>(z0, z1, wkT, bk, q, sc);
  attn_kernel<<<1, 1, 0, stream>>>(sc, 1.0f / (float)N);
  final_kernel<<<N / 16, 256, 0, stream>>>(z0, z1, sc + 2, Wl, bl, out_i);
}

// Round 5
// 1018.539 us; speedup vs baseline: 1.9677x; 1.9677x over previous
//
#include <hip/hip_runtime.h>
#include <math.h>

#define N     50000
#define F_IN  128
#define HID   256
#define E     800000
#define OUTD  64
#define NEG   0.2f
#define N8    (N * 8)
#define NTOT  (4 * N)

// hierarchical scan geometry
#define SC_TPB   256
#define SC_PERB  2048
#define SC_NB    ((NTOT + SC_PERB - 1) / SC_PERB)   // 98

// bucket sort geometry
#define BSH   7                      // bucket = dst >> 7 (128 dsts/bucket)
#define NBUK  ((N + 127) / 128)      // 391
#define NBT   (4 * NBUK)             // 1564
#define EPB1  8192
#define NB1   ((E + EPB1 - 1) / EPB1) // 98

typedef float4 f4;
typedef unsigned int u32;
typedef unsigned short ush;
typedef float f32x4 __attribute__((ext_vector_type(4)));
typedef short bf16x8 __attribute__((ext_vector_type(8)));

static __device__ __forceinline__ float lrelu(float x) { return x >= 0.f ? x : NEG * x; }
static __device__ __forceinline__ u32 bfr(float x) {
  u32 u = __float_as_uint(x);
  return (u + 0x7fffu + ((u >> 16) & 1u)) >> 16;
}
static __device__ __forceinline__ u32 pk2(float a, float b) { return bfr(a) | (bfr(b) << 16); }
static __device__ __forceinline__ float bf2f(u32 us) { return __uint_as_float(us << 16); }

// ---------------------------------------------------------------------------
// Projection + fused per-node attention scores.
// ---------------------------------------------------------------------------
__global__ __launch_bounds__(256) void proj_kernel(
    const float* __restrict__ x, const float* __restrict__ W, const float* __restrict__ b,
    const float* __restrict__ a0, const float* __restrict__ a1,
    const float* __restrict__ a2, const float* __restrict__ a3,
    ush* __restrict__ hb, float* __restrict__ sdst)
{
  __shared__ float xT[F_IN * 16];   // [k][i]
  const int t = threadIdx.x;
  const int base = blockIdx.x * 16;
  for (int idx = t; idx < 16 * F_IN; idx += 256) {
    int r = idx & 15, c = idx >> 4;
    xT[c * 16 + r] = x[(size_t)(base + r) * F_IN + c];
  }
  __syncthreads();
  const int ig = t >> 6;
  const int lane = t & 63;
  const int j0 = lane * 4;
  float acc[4][4] = {};
  for (int k = 0; k < F_IN; ++k) {
    f4 w  = *(const f4*)&W[k * HID + j0];
    f4 xv = *(const f4*)&xT[k * 16 + ig * 4];
    const float wa[4] = {w.x, w.y, w.z, w.w};
    const float xa[4] = {xv.x, xv.y, xv.z, xv.w};
#pragma unroll
    for (int i = 0; i < 4; ++i)
#pragma unroll
      for (int j = 0; j < 4; ++j) acc[i][j] = fmaf(xa[i], wa[j], acc[i][j]);
  }
  f4 bv = *(const f4*)&b[j0];
  const float ba[4] = {bv.x, bv.y, bv.z, bv.w};
#pragma unroll
  for (int i = 0; i < 4; ++i) {
#pragma unroll
    for (int j = 0; j < 4; ++j) acc[i][j] += ba[j];
    ushort4 o;
    o.x = (ush)bfr(acc[i][0]); o.y = (ush)bfr(acc[i][1]);
    o.z = (ush)bfr(acc[i][2]); o.w = (ush)bfr(acc[i][3]);
    *(ushort4*)&hb[(size_t)(base + ig * 4 + i) * HID + j0] = o;
  }
  const int head = lane >> 3;
  const float* av[4] = {a0, a1, a2, a3};
#pragma unroll
  for (int k = 0; k < 4; ++k) {
    f4 a = *(const f4*)&av[k][j0];
#pragma unroll
    for (int i = 0; i < 4; ++i) {
      float p = acc[i][0] * a.x + acc[i][1] * a.y + acc[i][2] * a.z + acc[i][3] * a.w;
      p += __shfl_xor(p, 1);
      p += __shfl_xor(p, 2);
      p += __shfl_xor(p, 4);
      if ((lane & 7) == 0)
        sdst[(size_t)k * N8 + (size_t)(base + ig * 4 + i) * 8 + head] = p;
    }
  }
}

// ---------------------------------------------------------------------------
__global__ void wkt_kernel(const float* __restrict__ Wk, ush* __restrict__ wkT)
{
  int idx = blockIdx.x * 256 + threadIdx.x;
  int n = idx >> 8, k = idx & 255;
  wkT[idx] = (ush)bfr(Wk[k * HID + n]);
}

// ---------------------------------------------------------------------------
// CSR build, per-block multisplit (block-aggregated reservations; no per-edge
// global atomics except 1 per block x non-empty bucket):
//  histB : bucket histogram (LDS-aggregated)
//  bscan : exclusive scan of 1564 bucket counts -> bstart, bcur
//  scat2 : per-block LDS histogram -> 1 reservation atomic per (blk,bucket),
//          LDS-ranked contiguous writes of packed (dst<<16|src)
//  cntb  : per-bucket fine counts from staging (plain stores, no atomics)
//  scanA/B/C : fine exclusive scan -> start
//  fillb : per-bucket LDS-cursor fill of csr
// ---------------------------------------------------------------------------
__global__ __launch_bounds__(256) void histb_kernel(
    const int* __restrict__ d0, const int* __restrict__ d1,
    const int* __restrict__ d2, const int* __restrict__ d3,
    int* __restrict__ bcnt)
{
  __shared__ int lh[NBUK];
  const int rel = blockIdx.x / NB1;
  const int blk = blockIdx.x % NB1;
  for (int j = threadIdx.x; j < NBUK; j += 256) lh[j] = 0;
  __syncthreads();
  const int* dp = rel == 0 ? d0 : rel == 1 ? d1 : rel == 2 ? d2 : d3;
  const int base = blk * EPB1;
#pragma unroll 4
  for (int k = 0; k < EPB1 / 256; ++k) {
    int i = base + k * 256 + threadIdx.x;
    if (i < E) atomicAdd(&lh[dp[i] >> BSH], 1);
  }
  __syncthreads();
  for (int j = threadIdx.x; j < NBUK; j += 256)
    if (lh[j]) atomicAdd(&bcnt[rel * NBUK + j], lh[j]);
}

__global__ __launch_bounds__(256) void bscan_kernel(
    const int* __restrict__ bcnt, int* __restrict__ bstart, int* __restrict__ bcur)
{
  __shared__ int part[256];
  const int t = threadIdx.x;
  const int chunk = (NBT + 255) / 256;   // 7
  const int b = t * chunk;
  const int e = min(NBT, b + chunk);
  int s = 0;
  for (int i = b; i < e; ++i) s += bcnt[i];
  part[t] = s;
  __syncthreads();
  for (int off = 1; off < 256; off <<= 1) {
    int u = (t >= off) ? part[t - off] : 0;
    __syncthreads();
    part[t] += u;
    __syncthreads();
  }
  int run = part[t] - s;
  for (int i = b; i < e; ++i) {
    bstart[i] = run;
    bcur[i] = run;
    run += bcnt[i];
  }
}

__global__ __launch_bounds__(256) void scat2_kernel(
    const int* __restrict__ s0, const int* __restrict__ d0,
    const int* __restrict__ s1, const int* __restrict__ d1,
    const int* __restrict__ s2, const int* __restrict__ d2,
    const int* __restrict__ s3, const int* __restrict__ d3,
    int* __restrict__ bcur, u32* __restrict__ bstage)
{
  __shared__ int lh[NBUK];
  const int rel = blockIdx.x / NB1;
  const int blk = blockIdx.x % NB1;
  const int* sp = rel == 0 ? s0 : rel == 1 ? s1 : rel == 2 ? s2 : s3;
  const int* dp = rel == 0 ? d0 : rel == 1 ? d1 : rel == 2 ? d2 : d3;
  for (int j = threadIdx.x; j < NBUK; j += 256) lh[j] = 0;
  __syncthreads();
  const int base = blk * EPB1;
#pragma unroll 4
  for (int k = 0; k < EPB1 / 256; ++k) {
    int i = base + k * 256 + threadIdx.x;
    if (i < E) atomicAdd(&lh[dp[i] >> BSH], 1);
  }
  __syncthreads();
  // one reservation atomic per non-empty (block,bucket); lh becomes cursor
  for (int j = threadIdx.x; j < NBUK; j += 256) {
    int c = lh[j];
    lh[j] = c ? atomicAdd(&bcur[rel * NBUK + j], c) : 0;
  }
  __syncthreads();
#pragma unroll 4
  for (int k = 0; k < EPB1 / 256; ++k) {
    int i = base + k * 256 + threadIdx.x;
    if (i < E) {
      int dst = dp[i], src = sp[i];
      int pos = atomicAdd(&lh[dst >> BSH], 1);   // LDS atomic (fast)
      bstage[pos] = ((u32)dst << 16) | (u32)src;
    }
  }
}

__global__ __launch_bounds__(256) void cntb_kernel(
    const u32* __restrict__ bstage, const int* __restrict__ bstart,
    const int* __restrict__ bcnt, int* __restrict__ count)
{
  __shared__ int lcnt[128];
  const int bb = blockIdx.x;
  const int rel = bb / NBUK, b = bb % NBUK;
  if (threadIdx.x < 128) lcnt[threadIdx.x] = 0;
  __syncthreads();
  const int rb = bstart[bb];
  const int cnt = bcnt[bb];
  for (int k = threadIdx.x; k < cnt; k += 256)
    atomicAdd(&lcnt[(bstage[rb + k] >> 16) & 127], 1);
  __syncthreads();
  const int fb = rel * N + b * 128;
  const int lim = min(128, N - b * 128);
  if (threadIdx.x < lim) count[fb + threadIdx.x] = lcnt[threadIdx.x];
}

__global__ __launch_bounds__(SC_TPB) void scanA_kernel(
    const int* __restrict__ count, int* __restrict__ bsum)
{
  __shared__ int red[4];
  const int t = threadIdx.x;
  const int base = blockIdx.x * SC_PERB + t * 8;
  int s = 0;
  if (base + 8 <= NTOT) {
    int4 a = *(const int4*)&count[base];
    int4 b = *(const int4*)&count[base + 4];
    s = a.x + a.y + a.z + a.w + b.x + b.y + b.z + b.w;
  } else {
    for (int i = 0; i < 8; ++i) { int idx = base + i; if (idx < NTOT) s += count[idx]; }
  }
#pragma unroll
  for (int off = 1; off < 64; off <<= 1) s += __shfl_xor(s, off);
  if ((t & 63) == 0) red[t >> 6] = s;
  __syncthreads();
  if (t == 0) bsum[blockIdx.x] = red[0] + red[1] + red[2] + red[3];
}

__global__ __launch_bounds__(128) void scanB_kernel(int* __restrict__ bsum)
{
  __shared__ int tmp[128];
  const int t = threadIdx.x;
  int v = (t < SC_NB) ? bsum[t] : 0;
  tmp[t] = v;
  __syncthreads();
  for (int off = 1; off < 128; off <<= 1) {
    int u = (t >= off) ? tmp[t - off] : 0;
    __syncthreads();
    tmp[t] += u;
    __syncthreads();
  }
  if (t < SC_NB) bsum[t] = tmp[t] - v;  // exclusive
}

__global__ __launch_bounds__(SC_TPB) void scanC_kernel(
    const int* __restrict__ count, const int* __restrict__ bsum,
    int* __restrict__ start)
{
  __shared__ int ts[SC_TPB];
  const int t = threadIdx.x;
  const int base = blockIdx.x * SC_PERB + t * 8;
  int c[8];
  int s = 0;
#pragma unroll
  for (int i = 0; i < 8; ++i) {
    int idx = base + i;
    c[i] = (idx < NTOT) ? count[idx] : 0;
    s += c[i];
  }
  ts[t] = s;
  __syncthreads();
  for (int off = 1; off < SC_TPB; off <<= 1) {
    int u = (t >= off) ? ts[t - off] : 0;
    __syncthreads();
    ts[t] += u;
    __syncthreads();
  }
  int run = ts[t] - s + bsum[blockIdx.x];
#pragma unroll
  for (int i = 0; i < 8; ++i) {
    int idx = base + i;
    if (idx < NTOT) {
      start[idx] = run;
      run += c[i];
    }
  }
}

__global__ __launch_bounds__(256) void fillb_kernel(
    const u32* __restrict__ bstage, const int* __restrict__ bstart,
    const int* __restrict__ bcnt, const int* __restrict__ start,
    int* __restrict__ csr)
{
  __shared__ int lcur[128];
  const int bb = blockIdx.x;           // rel*NBUK + b
  const int rel = bb / NBUK, b = bb % NBUK;
  const int fb = rel * N + b * 128;
  const int lim = min(128, N - b * 128);
  if (threadIdx.x < lim) lcur[threadIdx.x] = start[fb + threadIdx.x];
  __syncthreads();
  const int rb = bstart[bb];
  const int cnt = bcnt[bb];
  for (int k = threadIdx.x; k < cnt; k += 256) {
    u32 pk = bstage[rb + k];
    int ldst = (pk >> 16) & 127;
    int pos = atomicAdd(&lcur[ldst], 1);
    csr[pos] = (int)(pk & 0xffffu);
  }
}

// ---------------------------------------------------------------------------
// Relation conv, bf16 row gathers (512B/edge), fp32 accumulate, 2-edge unroll.
// ---------------------------------------------------------------------------
__global__ __launch_bounds__(256) void conv_kernel(
    const ush* __restrict__ xsb, const float* __restrict__ ss,
    const float* __restrict__ sd, const int* __restrict__ csr,
    const int* __restrict__ start, const int* __restrict__ count,
    float* __restrict__ z)
{
  const int dst = blockIdx.x * 4 + (threadIdx.x >> 6);
  const int lane = threadIdx.x & 63;
  const int e0 = start[dst];
  const int ne = count[dst];

  const int h1 = lane & 7;
  const float sdv1 = sd[dst * 8 + h1];
  float den = 0.f;
  for (int j = lane >> 3; j < ne; j += 8)
    den += __expf(lrelu(ss[csr[e0 + j] * 8 + h1] + sdv1));
  den += __shfl_xor(den, 8);
  den += __shfl_xor(den, 16);
  den += __shfl_xor(den, 32);
  const int h2 = lane >> 3;
  const float inv_den = 1.f / (__shfl(den, h2) + 1e-16f);
  const float sdv2 = sd[dst * 8 + h2];

  float a0 = 0.f, a1 = 0.f, a2 = 0.f, a3 = 0.f;
  int j = 0;
  for (; j + 2 <= ne; j += 2) {
    int sA = csr[e0 + j], sB = csr[e0 + j + 1];
    float lA = ss[sA * 8 + h2], lB = ss[sB * 8 + h2];
    ushort4 vA = *(const ushort4*)&xsb[(size_t)sA * HID + lane * 4];
    ushort4 vB = *(const ushort4*)&xsb[(size_t)sB * HID + lane * 4];
    float alA = __expf(lrelu(lA + sdv2)) * inv_den;
    float alB = __expf(lrelu(lB + sdv2)) * inv_den;
    a0 = fmaf(alA, bf2f(vA.x), a0);
    a1 = fmaf(alA, bf2f(vA.y), a1);
    a2 = fmaf(alA, bf2f(vA.z), a2);
    a3 = fmaf(alA, bf2f(vA.w), a3);
    a0 = fmaf(alB, bf2f(vB.x), a0);
    a1 = fmaf(alB, bf2f(vB.y), a1);
    a2 = fmaf(alB, bf2f(vB.z), a2);
    a3 = fmaf(alB, bf2f(vB.w), a3);
  }
  if (j < ne) {
    int sA = csr[e0 + j];
    float alA = __expf(lrelu(ss[sA * 8 + h2] + sdv2)) * inv_den;
    ushort4 vA = *(const ushort4*)&xsb[(size_t)sA * HID + lane * 4];
    a0 = fmaf(alA, bf2f(vA.x), a0);
    a1 = fmaf(alA, bf2f(vA.y), a1);
    a2 = fmaf(alA, bf2f(vA.z), a2);
    a3 = fmaf(alA, bf2f(vA.w), a3);
  }
  f4 o = {fmaxf(a0, 0.f), fmaxf(a1, 0.f), fmaxf(a2, 0.f), fmaxf(a3, 0.f)};
  *(f4*)&z[(size_t)dst * HID + lane * 4] = o;
}

// ---------------------------------------------------------------------------
// Semantic scores via bf16 MFMA 16x16x32.
// ---------------------------------------------------------------------------
__global__ __launch_bounds__(256) void semscore_kernel(
    const float* __restrict__ z0, const float* __restrict__ z1,
    const ush* __restrict__ wkT, const float* __restrict__ bk,
    const float* __restrict__ q, float* __restrict__ score)
{
  __shared__ u32 Bs[8192];
  __shared__ u32 As0[2048];
  __shared__ u32 As1[2048];
  const int t = threadIdx.x;
  const int base = blockIdx.x * 64;
  const int w = t >> 6;
  const int l = t & 63;
  const int lrow = l & 15;
  const int kgrp = l >> 4;

  f32x4 acc0[16], acc1[16];
  const f32x4 zz = {0.f, 0.f, 0.f, 0.f};
#pragma unroll
  for (int nt = 0; nt < 16; ++nt) { acc0[nt] = zz; acc1[nt] = zz; }

  for (int kc = 0; kc < 4; ++kc) {
#pragma unroll
    for (int it = 0; it < 8; ++it) {
      int cid = it * 256 + t;
      int n = cid >> 3, g = cid & 7;
      uint4 v = *(const uint4*)&wkT[n * HID + kc * 64 + g * 8];
      *(uint4*)&Bs[(n * 32 + g * 4) ^ ((n & 7) << 2)] = v;
    }
#pragma unroll
    for (int m = 0; m < 2; ++m) {
      const float* zp = m ? z1 : z0;
      u32* ap = m ? As1 : As0;
#pragma unroll
      for (int it = 0; it < 2; ++it) {
        int cid = it * 256 + t;
        int r = cid >> 3, g = cid & 7;
        int gr = base + r;
        if (gr >= N) gr = N - 1;
        const float* sp = &zp[(size_t)gr * HID + kc * 64 + g * 8];
        f4 v0 = *(const f4*)sp;
        f4 v1 = *(const f4*)(sp + 4);
        int di = (r * 32 + g * 4) ^ ((r & 7) << 2);
        ap[di + 0] = pk2(v0.x, v0.y);
        ap[di + 1] = pk2(v0.z, v0.w);
        ap[di + 2] = pk2(v1.x, v1.y);
        ap[di + 3] = pk2(v1.z, v1.w);
      }
    }
    __syncthreads();
#pragma unroll
    for (int kk = 0; kk < 2; ++kk) {
      int ai = ((w * 16 + lrow) * 32 + kk * 16 + kgrp * 4) ^ ((lrow & 7) << 2);
      bf16x8 af0 = *(const bf16x8*)&As0[ai];
      bf16x8 af1 = *(const bf16x8*)&As1[ai];
#pragma unroll
      for (int nt = 0; nt < 16; ++nt) {
        int n = nt * 16 + lrow;
        int bi = (n * 32 + kk * 16 + kgrp * 4) ^ ((n & 7) << 2);
        bf16x8 bf = *(const bf16x8*)&Bs[bi];
        acc0[nt] = __builtin_amdgcn_mfma_f32_16x16x32_bf16(af0, bf, acc0[nt], 0, 0, 0);
        acc1[nt] = __builtin_amdgcn_mfma_f32_16x16x32_bf16(af1, bf, acc1[nt], 0, 0, 0);
      }
    }
    __syncthreads();
  }

  float s0 = 0.f, s1 = 0.f;
#pragma unroll
  for (int nt = 0; nt < 16; ++nt) {
    int col = nt * 16 + lrow;
    float bkv = bk[col], qv = q[col];
#pragma unroll
    for (int i = 0; i < 4; ++i) {
      int gr = base + w * 16 + kgrp * 4 + i;
      if (gr < N) {
        s0 += tanhf(acc0[nt][i] + bkv) * qv;
        s1 += tanhf(acc1[nt][i] + bkv) * qv;
      }
    }
  }
#pragma unroll
  for (int off = 1; off < 64; off <<= 1) {
    s0 += __shfl_xor(s0, off);
    s1 += __shfl_xor(s1, off);
  }
  if (l == 0) {
    atomicAdd(&score[0], s0);
    atomicAdd(&score[1], s1);
  }
}

__global__ void attn_kernel(float* __restrict__ score, float inv_n)
{
  float s0 = score[0] * inv_n, s1 = score[1] * inv_n;
  float m = fmaxf(s0, s1);
  float e0 = __expf(s0 - m), e1 = __expf(s1 - m);
  float d = e0 + e1;
  score[2] = e0 / d;
  score[3] = e1 / d;
}

// ---------------------------------------------------------------------------
__global__ __launch_bounds__(256) void final_kernel(
    const float* __restrict__ z0, const float* __restrict__ z1,
    const float* __restrict__ attn, const float* __restrict__ Wl,
    const float* __restrict__ bl, float* __restrict__ out)
{
  __shared__ float zT[HID * 16];
  const int t = threadIdx.x;
  const int base = blockIdx.x * 16;
  const float a0 = attn[0], a1 = attn[1];
  for (int idx = t; idx < 16 * HID; idx += 256) {
    int r = idx & 15, c = idx >> 4;
    zT[c * 16 + r] = a0 * z0[(size_t)(base + r) * HID + c]
                   + a1 * z1[(size_t)(base + r) * HID + c];
  }
  __syncthreads();
  const int ig = t >> 6;
  const int cc = t & 63;
  float acc[4] = {};
  for (int k = 0; k < HID; ++k) {
    float w = Wl[k * OUTD + cc];
    f4 xv = *(const f4*)&zT[k * 16 + ig * 4];
    acc[0] = fmaf(xv.x, w, acc[0]);
    acc[1] = fmaf(xv.y, w, acc[1]);
    acc[2] = fmaf(xv.z, w, acc[2]);
    acc[3] = fmaf(xv.w, w, acc[3]);
  }
  float bb = bl[cc];
#pragma unroll
  for (int i = 0; i < 4; ++i)
    out[(size_t)(base + ig * 4 + i) * OUTD + cc] = acc[i] + bb;
}

// ---------------------------------------------------------------------------
extern "C" void kernel_launch(void* const* d_in, const int* in_sizes, int n_in,
                              void* d_out, int out_size, void* d_ws, size_t ws_size,
                              hipStream_t stream)
{
  const float* x_user = (const float*)d_in[0];
  const float* x_item = (const float*)d_in[1];
  const int*   e_ui   = (const int*)d_in[2];
  const int*   e_iu   = (const int*)d_in[3];
  const int*   e_uu   = (const int*)d_in[4];
  const int*   e_ii   = (const int*)d_in[5];
  const float* Wp_u   = (const float*)d_in[6];
  const float* bp_u   = (const float*)d_in[7];
  const float* Wp_i   = (const float*)d_in[8];
  const float* bp_i   = (const float*)d_in[9];
  const float* as_ui  = (const float*)d_in[10];
  const float* ad_ui  = (const float*)d_in[11];
  const float* as_iu  = (const float*)d_in[12];
  const float* ad_iu  = (const float*)d_in[13];
  const float* as_uu  = (const float*)d_in[14];
  const float* ad_uu  = (const float*)d_in[15];
  const float* as_ii  = (const float*)d_in[16];
  const float* ad_ii  = (const float*)d_in[17];
  const float* Wk     = (const float*)d_in[18];
  const float* bk     = (const float*)d_in[19];
  const float* q      = (const float*)d_in[20];
  const float* Wl     = (const float*)d_in[21];
  const float* bl     = (const float*)d_in[22];

  const size_t NH = (size_t)N * HID;
  size_t need = (2 * NH + 8 * (size_t)N8 + 4) * 4            // z0,z1,su,si,sc
              + (2 * NH + HID * HID) * 2                     // hub,hib,wkT
              + ((size_t)8 * N + 4 * (size_t)E + 3 * NBT + 128 + 64) * 4;
  if (ws_size < need) {
    hipMemsetAsync(d_out, 0x7f, (size_t)out_size * sizeof(float), stream);
    return;
  }
  float* z0 = (float*)d_ws;
  float* z1 = z0 + NH;
  float* su = z1 + NH;
  float* si = su + 4 * (size_t)N8;
  float* sc = si + 4 * (size_t)N8;
  ush* hub  = (ush*)(sc + 4);
  ush* hib  = hub + NH;
  ush* wkT  = hib + NH;
  int* count  = (int*)(wkT + HID * HID);
  int* bcnt   = count + NTOT;
  int* start  = bcnt + NBT;
  int* bstart = start + NTOT;
  int* bcur   = bstart + NBT;
  int* bsum   = bcur + NBT;
  int* csr    = bsum + 128;
  u32* bstage = (u32*)z0;           // aliases z0 (dead until first conv)

  float* out_u = (float*)d_out;
  float* out_i = out_u + (size_t)N * OUTD;

  wkt_kernel<<<HID * HID / 256, 256, 0, stream>>>(Wk, wkT);

  proj_kernel<<<N / 16, 256, 0, stream>>>(x_user, Wp_u, bp_u,
                                          ad_iu, as_uu, ad_uu, as_ui, hub, su);
  proj_kernel<<<N / 16, 256, 0, stream>>>(x_item, Wp_i, bp_i,
                                          as_iu, ad_ui, as_ii, ad_ii, hib, si);

  // batched CSR build via per-block multisplit: rel 0=iu, 1=uu, 2=ui, 3=ii
  hipMemsetAsync(bcnt, 0, NBT * sizeof(int), stream);
  histb_kernel<<<4 * NB1, 256, 0, stream>>>(e_iu + E, e_uu + E, e_ui + E, e_ii + E, bcnt);
  bscan_kernel<<<1, 256, 0, stream>>>(bcnt, bstart, bcur);
  scat2_kernel<<<4 * NB1, 256, 0, stream>>>(e_iu, e_iu + E, e_uu, e_uu + E,
                                            e_ui, e_ui + E, e_ii, e_ii + E,
                                            bcur, bstage);
  cntb_kernel<<<NBT, 256, 0, stream>>>(bstage, bstart, bcnt, count);
  scanA_kernel<<<SC_NB, SC_TPB, 0, stream>>>(count, bsum);
  scanB_kernel<<<1, 128, 0, stream>>>(bsum);
  scanC_kernel<<<SC_NB, SC_TPB, 0, stream>>>(count, bsum, start);
  fillb_kernel<<<NBT, 256, 0, stream>>>(bstage, bstart, bcnt, start, csr);

  const int SEMG = (N + 63) / 64;

  // ---- user side
  conv_kernel<<<N / 4, 256, 0, stream>>>(hib, si, su, csr, start, count, z0);
  conv_kernel<<<N / 4, 256, 0, stream>>>(hub, su + N8, su + 2 * (size_t)N8, csr,
                                         start + N, count + N, z1);
  hipMemsetAsync(sc, 0, 2 * sizeof(float), stream);
  semscore_kernel<<<SEMG, 256, 0, stream>>>(z0, z1, wkT, bk, q, sc);
  attn_kernel<<<1, 1, 0, stream>>>(sc, 1.0f / (float)N);
  final_kernel<<<N / 16, 256, 0, stream>>>(z0, z1, sc + 2, Wl, bl, out_u);

  // ---- item side
  conv_kernel<<<N / 4, 256, 0, stream>>>(hub, su + 3 * (size_t)N8, si + N8, csr,
                                         start + 2 * N, count + 2 * N, z0);
  conv_kernel<<<N / 4, 256, 0, stream>>>(hib, si + 2 * (size_t)N8, si + 3 * (size_t)N8, csr,
                                         start + 3 * N, count + 3 * N, z1);
  hipMemsetAsync(sc, 0, 2 * sizeof(float), stream);
  semscore_kernel<<<SEMG, 256, 0, stream>>>(z0, z1, wkT, bk, q, sc);
  attn_kernel<<<1, 1, 0, stream>>>(sc, 1.0f / (float)N);
  final_kernel<<<N / 16, 256, 0, stream>>>(z0, z1, sc + 2, Wl, bl, out_i);
}

// Round 6
// 945.008 us; speedup vs baseline: 2.1208x; 1.0778x over previous
//
#include <hip/hip_runtime.h>
#include <math.h>

#define N     50000
#define F_IN  128
#define HID   256
#define E     800000
#define OUTD  64
#define NEG   0.2f
#define N8    (N * 8)
#define NTOT  (4 * N)

// hierarchical scan geometry
#define SC_TPB   256
#define SC_PERB  2048
#define SC_NB    ((NTOT + SC_PERB - 1) / SC_PERB)   // 98

// bucket sort geometry
#define BSH   7                      // bucket = dst >> 7 (128 dsts/bucket)
#define NBUK  ((N + 127) / 128)      // 391
#define NBT   (4 * NBUK)             // 1564
#define EPB1  8192
#define NB1   ((E + EPB1 - 1) / EPB1) // 98

typedef float4 f4;
typedef unsigned int u32;
typedef unsigned short ush;
typedef float f32x4 __attribute__((ext_vector_type(4)));
typedef short bf16x8 __attribute__((ext_vector_type(8)));

static __device__ __forceinline__ float lrelu(float x) { return x >= 0.f ? x : NEG * x; }
static __device__ __forceinline__ u32 bfr(float x) {
  u32 u = __float_as_uint(x);
  return (u + 0x7fffu + ((u >> 16) & 1u)) >> 16;
}
static __device__ __forceinline__ float bf2f(u32 us) { return __uint_as_float(us << 16); }
// tanh(x) = 1 - 2/(exp(2x)+1); robust for all x (inf -> 1, 0 -> -1 path ok)
static __device__ __forceinline__ float tanh_fast(float x) {
  float e = __expf(2.f * x);
  return fmaf(-2.f, __builtin_amdgcn_rcpf(e + 1.f), 1.f);
}

// ---------------------------------------------------------------------------
// Projection + fused per-node attention scores.
// ---------------------------------------------------------------------------
__global__ __launch_bounds__(256) void proj_kernel(
    const float* __restrict__ x, const float* __restrict__ W, const float* __restrict__ b,
    const float* __restrict__ a0, const float* __restrict__ a1,
    const float* __restrict__ a2, const float* __restrict__ a3,
    ush* __restrict__ hb, float* __restrict__ sdst)
{
  __shared__ float xT[F_IN * 16];   // [k][i]
  const int t = threadIdx.x;
  const int base = blockIdx.x * 16;
  for (int idx = t; idx < 16 * F_IN; idx += 256) {
    int r = idx & 15, c = idx >> 4;
    xT[c * 16 + r] = x[(size_t)(base + r) * F_IN + c];
  }
  __syncthreads();
  const int ig = t >> 6;
  const int lane = t & 63;
  const int j0 = lane * 4;
  float acc[4][4] = {};
  for (int k = 0; k < F_IN; ++k) {
    f4 w  = *(const f4*)&W[k * HID + j0];
    f4 xv = *(const f4*)&xT[k * 16 + ig * 4];
    const float wa[4] = {w.x, w.y, w.z, w.w};
    const float xa[4] = {xv.x, xv.y, xv.z, xv.w};
#pragma unroll
    for (int i = 0; i < 4; ++i)
#pragma unroll
      for (int j = 0; j < 4; ++j) acc[i][j] = fmaf(xa[i], wa[j], acc[i][j]);
  }
  f4 bv = *(const f4*)&b[j0];
  const float ba[4] = {bv.x, bv.y, bv.z, bv.w};
#pragma unroll
  for (int i = 0; i < 4; ++i) {
#pragma unroll
    for (int j = 0; j < 4; ++j) acc[i][j] += ba[j];
    ushort4 o;
    o.x = (ush)bfr(acc[i][0]); o.y = (ush)bfr(acc[i][1]);
    o.z = (ush)bfr(acc[i][2]); o.w = (ush)bfr(acc[i][3]);
    *(ushort4*)&hb[(size_t)(base + ig * 4 + i) * HID + j0] = o;
  }
  const int head = lane >> 3;
  const float* av[4] = {a0, a1, a2, a3};
#pragma unroll
  for (int k = 0; k < 4; ++k) {
    f4 a = *(const f4*)&av[k][j0];
#pragma unroll
    for (int i = 0; i < 4; ++i) {
      float p = acc[i][0] * a.x + acc[i][1] * a.y + acc[i][2] * a.z + acc[i][3] * a.w;
      p += __shfl_xor(p, 1);
      p += __shfl_xor(p, 2);
      p += __shfl_xor(p, 4);
      if ((lane & 7) == 0)
        sdst[(size_t)k * N8 + (size_t)(base + ig * 4 + i) * 8 + head] = p;
    }
  }
}

// ---------------------------------------------------------------------------
__global__ void wkt_kernel(const float* __restrict__ Wk, ush* __restrict__ wkT)
{
  int idx = blockIdx.x * 256 + threadIdx.x;
  int n = idx >> 8, k = idx & 255;
  wkT[idx] = (ush)bfr(Wk[k * HID + n]);
}

// ---------------------------------------------------------------------------
// CSR build, per-block multisplit (unchanged from R5 — off the critical list)
// ---------------------------------------------------------------------------
__global__ __launch_bounds__(256) void histb_kernel(
    const int* __restrict__ d0, const int* __restrict__ d1,
    const int* __restrict__ d2, const int* __restrict__ d3,
    int* __restrict__ bcnt)
{
  __shared__ int lh[NBUK];
  const int rel = blockIdx.x / NB1;
  const int blk = blockIdx.x % NB1;
  for (int j = threadIdx.x; j < NBUK; j += 256) lh[j] = 0;
  __syncthreads();
  const int* dp = rel == 0 ? d0 : rel == 1 ? d1 : rel == 2 ? d2 : d3;
  const int base = blk * EPB1;
#pragma unroll 4
  for (int k = 0; k < EPB1 / 256; ++k) {
    int i = base + k * 256 + threadIdx.x;
    if (i < E) atomicAdd(&lh[dp[i] >> BSH], 1);
  }
  __syncthreads();
  for (int j = threadIdx.x; j < NBUK; j += 256)
    if (lh[j]) atomicAdd(&bcnt[rel * NBUK + j], lh[j]);
}

__global__ __launch_bounds__(256) void bscan_kernel(
    const int* __restrict__ bcnt, int* __restrict__ bstart, int* __restrict__ bcur)
{
  __shared__ int part[256];
  const int t = threadIdx.x;
  const int chunk = (NBT + 255) / 256;   // 7
  const int b = t * chunk;
  const int e = min(NBT, b + chunk);
  int s = 0;
  for (int i = b; i < e; ++i) s += bcnt[i];
  part[t] = s;
  __syncthreads();
  for (int off = 1; off < 256; off <<= 1) {
    int u = (t >= off) ? part[t - off] : 0;
    __syncthreads();
    part[t] += u;
    __syncthreads();
  }
  int run = part[t] - s;
  for (int i = b; i < e; ++i) {
    bstart[i] = run;
    bcur[i] = run;
    run += bcnt[i];
  }
}

__global__ __launch_bounds__(256) void scat2_kernel(
    const int* __restrict__ s0, const int* __restrict__ d0,
    const int* __restrict__ s1, const int* __restrict__ d1,
    const int* __restrict__ s2, const int* __restrict__ d2,
    const int* __restrict__ s3, const int* __restrict__ d3,
    int* __restrict__ bcur, u32* __restrict__ bstage)
{
  __shared__ int lh[NBUK];
  const int rel = blockIdx.x / NB1;
  const int blk = blockIdx.x % NB1;
  const int* sp = rel == 0 ? s0 : rel == 1 ? s1 : rel == 2 ? s2 : s3;
  const int* dp = rel == 0 ? d0 : rel == 1 ? d1 : rel == 2 ? d2 : d3;
  for (int j = threadIdx.x; j < NBUK; j += 256) lh[j] = 0;
  __syncthreads();
  const int base = blk * EPB1;
#pragma unroll 4
  for (int k = 0; k < EPB1 / 256; ++k) {
    int i = base + k * 256 + threadIdx.x;
    if (i < E) atomicAdd(&lh[dp[i] >> BSH], 1);
  }
  __syncthreads();
  for (int j = threadIdx.x; j < NBUK; j += 256) {
    int c = lh[j];
    lh[j] = c ? atomicAdd(&bcur[rel * NBUK + j], c) : 0;
  }
  __syncthreads();
#pragma unroll 4
  for (int k = 0; k < EPB1 / 256; ++k) {
    int i = base + k * 256 + threadIdx.x;
    if (i < E) {
      int dst = dp[i], src = sp[i];
      int pos = atomicAdd(&lh[dst >> BSH], 1);   // LDS atomic (fast)
      bstage[pos] = ((u32)dst << 16) | (u32)src;
    }
  }
}

__global__ __launch_bounds__(256) void cntb_kernel(
    const u32* __restrict__ bstage, const int* __restrict__ bstart,
    const int* __restrict__ bcnt, int* __restrict__ count)
{
  __shared__ int lcnt[128];
  const int bb = blockIdx.x;
  const int rel = bb / NBUK, b = bb % NBUK;
  if (threadIdx.x < 128) lcnt[threadIdx.x] = 0;
  __syncthreads();
  const int rb = bstart[bb];
  const int cnt = bcnt[bb];
  for (int k = threadIdx.x; k < cnt; k += 256)
    atomicAdd(&lcnt[(bstage[rb + k] >> 16) & 127], 1);
  __syncthreads();
  const int fb = rel * N + b * 128;
  const int lim = min(128, N - b * 128);
  if (threadIdx.x < lim) count[fb + threadIdx.x] = lcnt[threadIdx.x];
}

__global__ __launch_bounds__(SC_TPB) void scanA_kernel(
    const int* __restrict__ count, int* __restrict__ bsum)
{
  __shared__ int red[4];
  const int t = threadIdx.x;
  const int base = blockIdx.x * SC_PERB + t * 8;
  int s = 0;
  if (base + 8 <= NTOT) {
    int4 a = *(const int4*)&count[base];
    int4 b = *(const int4*)&count[base + 4];
    s = a.x + a.y + a.z + a.w + b.x + b.y + b.z + b.w;
  } else {
    for (int i = 0; i < 8; ++i) { int idx = base + i; if (idx < NTOT) s += count[idx]; }
  }
#pragma unroll
  for (int off = 1; off < 64; off <<= 1) s += __shfl_xor(s, off);
  if ((t & 63) == 0) red[t >> 6] = s;
  __syncthreads();
  if (t == 0) bsum[blockIdx.x] = red[0] + red[1] + red[2] + red[3];
}

__global__ __launch_bounds__(128) void scanB_kernel(int* __restrict__ bsum)
{
  __shared__ int tmp[128];
  const int t = threadIdx.x;
  int v = (t < SC_NB) ? bsum[t] : 0;
  tmp[t] = v;
  __syncthreads();
  for (int off = 1; off < 128; off <<= 1) {
    int u = (t >= off) ? tmp[t - off] : 0;
    __syncthreads();
    tmp[t] += u;
    __syncthreads();
  }
  if (t < SC_NB) bsum[t] = tmp[t] - v;  // exclusive
}

__global__ __launch_bounds__(SC_TPB) void scanC_kernel(
    const int* __restrict__ count, const int* __restrict__ bsum,
    int* __restrict__ start)
{
  __shared__ int ts[SC_TPB];
  const int t = threadIdx.x;
  const int base = blockIdx.x * SC_PERB + t * 8;
  int c[8];
  int s = 0;
#pragma unroll
  for (int i = 0; i < 8; ++i) {
    int idx = base + i;
    c[i] = (idx < NTOT) ? count[idx] : 0;
    s += c[i];
  }
  ts[t] = s;
  __syncthreads();
  for (int off = 1; off < SC_TPB; off <<= 1) {
    int u = (t >= off) ? ts[t - off] : 0;
    __syncthreads();
    ts[t] += u;
    __syncthreads();
  }
  int run = ts[t] - s + bsum[blockIdx.x];
#pragma unroll
  for (int i = 0; i < 8; ++i) {
    int idx = base + i;
    if (idx < NTOT) {
      start[idx] = run;
      run += c[i];
    }
  }
}

__global__ __launch_bounds__(256) void fillb_kernel(
    const u32* __restrict__ bstage, const int* __restrict__ bstart,
    const int* __restrict__ bcnt, const int* __restrict__ start,
    int* __restrict__ csr)
{
  __shared__ int lcur[128];
  const int bb = blockIdx.x;           // rel*NBUK + b
  const int rel = bb / NBUK, b = bb % NBUK;
  const int fb = rel * N + b * 128;
  const int lim = min(128, N - b * 128);
  if (threadIdx.x < lim) lcur[threadIdx.x] = start[fb + threadIdx.x];
  __syncthreads();
  const int rb = bstart[bb];
  const int cnt = bcnt[bb];
  for (int k = threadIdx.x; k < cnt; k += 256) {
    u32 pk = bstage[rb + k];
    int ldst = (pk >> 16) & 127;
    int pos = atomicAdd(&lcur[ldst], 1);
    csr[pos] = (int)(pk & 0xffffu);
  }
}

// ---------------------------------------------------------------------------
// Relation conv, bf16 row gathers, fp32 accumulate, bf16 z output.
// ---------------------------------------------------------------------------
__global__ __launch_bounds__(256) void conv_kernel(
    const ush* __restrict__ xsb, const float* __restrict__ ss,
    const float* __restrict__ sd, const int* __restrict__ csr,
    const int* __restrict__ start, const int* __restrict__ count,
    ush* __restrict__ z)
{
  const int dst = blockIdx.x * 4 + (threadIdx.x >> 6);
  const int lane = threadIdx.x & 63;
  const int e0 = start[dst];
  const int ne = count[dst];

  const int h1 = lane & 7;
  const float sdv1 = sd[dst * 8 + h1];
  float den = 0.f;
  for (int j = lane >> 3; j < ne; j += 8)
    den += __expf(lrelu(ss[csr[e0 + j] * 8 + h1] + sdv1));
  den += __shfl_xor(den, 8);
  den += __shfl_xor(den, 16);
  den += __shfl_xor(den, 32);
  const int h2 = lane >> 3;
  const float inv_den = 1.f / (__shfl(den, h2) + 1e-16f);
  const float sdv2 = sd[dst * 8 + h2];

  float a0 = 0.f, a1 = 0.f, a2 = 0.f, a3 = 0.f;
  int j = 0;
  for (; j + 2 <= ne; j += 2) {
    int sA = csr[e0 + j], sB = csr[e0 + j + 1];
    float lA = ss[sA * 8 + h2], lB = ss[sB * 8 + h2];
    ushort4 vA = *(const ushort4*)&xsb[(size_t)sA * HID + lane * 4];
    ushort4 vB = *(const ushort4*)&xsb[(size_t)sB * HID + lane * 4];
    float alA = __expf(lrelu(lA + sdv2)) * inv_den;
    float alB = __expf(lrelu(lB + sdv2)) * inv_den;
    a0 = fmaf(alA, bf2f(vA.x), a0);
    a1 = fmaf(alA, bf2f(vA.y), a1);
    a2 = fmaf(alA, bf2f(vA.z), a2);
    a3 = fmaf(alA, bf2f(vA.w), a3);
    a0 = fmaf(alB, bf2f(vB.x), a0);
    a1 = fmaf(alB, bf2f(vB.y), a1);
    a2 = fmaf(alB, bf2f(vB.z), a2);
    a3 = fmaf(alB, bf2f(vB.w), a3);
  }
  if (j < ne) {
    int sA = csr[e0 + j];
    float alA = __expf(lrelu(ss[sA * 8 + h2] + sdv2)) * inv_den;
    ushort4 vA = *(const ushort4*)&xsb[(size_t)sA * HID + lane * 4];
    a0 = fmaf(alA, bf2f(vA.x), a0);
    a1 = fmaf(alA, bf2f(vA.y), a1);
    a2 = fmaf(alA, bf2f(vA.z), a2);
    a3 = fmaf(alA, bf2f(vA.w), a3);
  }
  ushort4 o;
  o.x = (ush)bfr(fmaxf(a0, 0.f));
  o.y = (ush)bfr(fmaxf(a1, 0.f));
  o.z = (ush)bfr(fmaxf(a2, 0.f));
  o.w = (ush)bfr(fmaxf(a3, 0.f));
  *(ushort4*)&z[(size_t)dst * HID + lane * 4] = o;
}

// ---------------------------------------------------------------------------
// Semantic scores, register-only MFMA (no LDS, no barriers).
// Wave owns 16 rows: A-fragments preloaded from bf16 z (global), B-fragments
// streamed from L2-resident wkT. Fragment layout: lane l -> row l&15,
// k = (l>>4)*8..+8 (matches 16x16x32 A/B operand layout).
// ---------------------------------------------------------------------------
__global__ __launch_bounds__(256) void semscore_kernel(
    const ush* __restrict__ zb0, const ush* __restrict__ zb1,
    const ush* __restrict__ wkT, const float* __restrict__ bk,
    const float* __restrict__ q, float* __restrict__ score)
{
  const int t = threadIdx.x;
  const int w = t >> 6;
  const int l = t & 63;
  const int lrow = l & 15;
  const int kgrp = l >> 4;
  const int rbase = blockIdx.x * 64 + w * 16;
  int arow = rbase + lrow;
  if (arow >= N) arow = N - 1;   // dup row; masked in epilogue

  bf16x8 A0[8], A1[8];
  const ush* pa0 = &zb0[(size_t)arow * HID + kgrp * 8];
  const ush* pa1 = &zb1[(size_t)arow * HID + kgrp * 8];
#pragma unroll
  for (int ks = 0; ks < 8; ++ks) {
    A0[ks] = *(const bf16x8*)(pa0 + ks * 32);
    A1[ks] = *(const bf16x8*)(pa1 + ks * 32);
  }

  float s0 = 0.f, s1 = 0.f;
#pragma unroll
  for (int nt = 0; nt < 16; ++nt) {
    const ush* pb = &wkT[(size_t)(nt * 16 + lrow) * HID + kgrp * 8];
    bf16x8 B[8];
#pragma unroll
    for (int ks = 0; ks < 8; ++ks) B[ks] = *(const bf16x8*)(pb + ks * 32);
    f32x4 acc0 = {0.f, 0.f, 0.f, 0.f};
    f32x4 acc1 = {0.f, 0.f, 0.f, 0.f};
#pragma unroll
    for (int ks = 0; ks < 8; ++ks) {
      acc0 = __builtin_amdgcn_mfma_f32_16x16x32_bf16(A0[ks], B[ks], acc0, 0, 0, 0);
      acc1 = __builtin_amdgcn_mfma_f32_16x16x32_bf16(A1[ks], B[ks], acc1, 0, 0, 0);
    }
    const int col = nt * 16 + lrow;
    const float bkv = bk[col], qv = q[col];
#pragma unroll
    for (int i = 0; i < 4; ++i) {
      int gr = rbase + kgrp * 4 + i;     // D row for this lane/reg
      if (gr < N) {
        s0 += tanh_fast(acc0[i] + bkv) * qv;
        s1 += tanh_fast(acc1[i] + bkv) * qv;
      }
    }
  }
#pragma unroll
  for (int off = 1; off < 64; off <<= 1) {
    s0 += __shfl_xor(s0, off);
    s1 += __shfl_xor(s1, off);
  }
  if (l == 0) {
    atomicAdd(&score[0], s0);
    atomicAdd(&score[1], s1);
  }
}

__global__ void attn_kernel(float* __restrict__ score, float inv_n)
{
  float s0 = score[0] * inv_n, s1 = score[1] * inv_n;
  float m = fmaxf(s0, s1);
  float e0 = __expf(s0 - m), e1 = __expf(s1 - m);
  float d = e0 + e1;
  score[2] = e0 / d;
  score[3] = e1 / d;
}

// ---------------------------------------------------------------------------
// Final: out[n,64] = (a0*z0[n]+a1*z1[n]) @ Wl + bl, z in bf16.
// ---------------------------------------------------------------------------
__global__ __launch_bounds__(256) void final_kernel(
    const ush* __restrict__ zb0, const ush* __restrict__ zb1,
    const float* __restrict__ attn, const float* __restrict__ Wl,
    const float* __restrict__ bl, float* __restrict__ out)
{
  __shared__ float zT[HID * 16];
  const int t = threadIdx.x;
  const int base = blockIdx.x * 16;
  const float a0 = attn[0], a1 = attn[1];
  for (int idx = t; idx < 16 * (HID / 2); idx += 256) {   // 2048 u32 pairs
    int r = idx & 15, cw = idx >> 4;
    u32 v0 = *(const u32*)&zb0[(size_t)(base + r) * HID + cw * 2];
    u32 v1 = *(const u32*)&zb1[(size_t)(base + r) * HID + cw * 2];
    zT[(2 * cw) * 16 + r]     = a0 * bf2f(v0 & 0xffffu) + a1 * bf2f(v1 & 0xffffu);
    zT[(2 * cw + 1) * 16 + r] = a0 * bf2f(v0 >> 16) + a1 * bf2f(v1 >> 16);
  }
  __syncthreads();
  const int ig = t >> 6;
  const int cc = t & 63;
  float acc[4] = {};
  for (int k = 0; k < HID; ++k) {
    float w = Wl[k * OUTD + cc];
    f4 xv = *(const f4*)&zT[k * 16 + ig * 4];
    acc[0] = fmaf(xv.x, w, acc[0]);
    acc[1] = fmaf(xv.y, w, acc[1]);
    acc[2] = fmaf(xv.z, w, acc[2]);
    acc[3] = fmaf(xv.w, w, acc[3]);
  }
  float bb = bl[cc];
#pragma unroll
  for (int i = 0; i < 4; ++i)
    out[(size_t)(base + ig * 4 + i) * OUTD + cc] = acc[i] + bb;
}

// ---------------------------------------------------------------------------
extern "C" void kernel_launch(void* const* d_in, const int* in_sizes, int n_in,
                              void* d_out, int out_size, void* d_ws, size_t ws_size,
                              hipStream_t stream)
{
  const float* x_user = (const float*)d_in[0];
  const float* x_item = (const float*)d_in[1];
  const int*   e_ui   = (const int*)d_in[2];
  const int*   e_iu   = (const int*)d_in[3];
  const int*   e_uu   = (const int*)d_in[4];
  const int*   e_ii   = (const int*)d_in[5];
  const float* Wp_u   = (const float*)d_in[6];
  const float* bp_u   = (const float*)d_in[7];
  const float* Wp_i   = (const float*)d_in[8];
  const float* bp_i   = (const float*)d_in[9];
  const float* as_ui  = (const float*)d_in[10];
  const float* ad_ui  = (const float*)d_in[11];
  const float* as_iu  = (const float*)d_in[12];
  const float* ad_iu  = (const float*)d_in[13];
  const float* as_uu  = (const float*)d_in[14];
  const float* ad_uu  = (const float*)d_in[15];
  const float* as_ii  = (const float*)d_in[16];
  const float* ad_ii  = (const float*)d_in[17];
  const float* Wk     = (const float*)d_in[18];
  const float* bk     = (const float*)d_in[19];
  const float* q      = (const float*)d_in[20];
  const float* Wl     = (const float*)d_in[21];
  const float* bl     = (const float*)d_in[22];

  const size_t NH = (size_t)N * HID;
  size_t need = (8 * (size_t)N8 + 4) * 4                     // su,si,sc (f32)
              + (4 * NH + (size_t)HID * HID) * 2             // zb0,zb1,hub,hib,wkT (bf16)
              + ((size_t)8 * N + 4 * (size_t)E + 3 * NBT + 128 + 64) * 4;
  if (ws_size < need) {
    hipMemsetAsync(d_out, 0x7f, (size_t)out_size * sizeof(float), stream);
    return;
  }
  float* su = (float*)d_ws;
  float* si = su + 4 * (size_t)N8;
  float* sc = si + 4 * (size_t)N8;
  ush* zb0  = (ush*)(sc + 4);
  ush* zb1  = zb0 + NH;
  ush* hub  = zb1 + NH;
  ush* hib  = hub + NH;
  ush* wkT  = hib + NH;
  int* count  = (int*)(wkT + (size_t)HID * HID);
  int* bcnt   = count + NTOT;
  int* start  = bcnt + NBT;
  int* bstart = start + NTOT;
  int* bcur   = bstart + NBT;
  int* bsum   = bcur + NBT;
  int* csr    = bsum + 128;
  u32* bstage = (u32*)zb0;          // aliases zb0 (25.6MB >= 12.8MB; dead until conv)

  float* out_u = (float*)d_out;
  float* out_i = out_u + (size_t)N * OUTD;

  wkt_kernel<<<HID * HID / 256, 256, 0, stream>>>(Wk, wkT);

  proj_kernel<<<N / 16, 256, 0, stream>>>(x_user, Wp_u, bp_u,
                                          ad_iu, as_uu, ad_uu, as_ui, hub, su);
  proj_kernel<<<N / 16, 256, 0, stream>>>(x_item, Wp_i, bp_i,
                                          as_iu, ad_ui, as_ii, ad_ii, hib, si);

  // batched CSR build via per-block multisplit: rel 0=iu, 1=uu, 2=ui, 3=ii
  hipMemsetAsync(bcnt, 0, NBT * sizeof(int), stream);
  histb_kernel<<<4 * NB1, 256, 0, stream>>>(e_iu + E, e_uu + E, e_ui + E, e_ii + E, bcnt);
  bscan_kernel<<<1, 256, 0, stream>>>(bcnt, bstart, bcur);
  scat2_kernel<<<4 * NB1, 256, 0, stream>>>(e_iu, e_iu + E, e_uu, e_uu + E,
                                            e_ui, e_ui + E, e_ii, e_ii + E,
                                            bcur, bstage);
  cntb_kernel<<<NBT, 256, 0, stream>>>(bstage, bstart, bcnt, count);
  scanA_kernel<<<SC_NB, SC_TPB, 0, stream>>>(count, bsum);
  scanB_kernel<<<1, 128, 0, stream>>>(bsum);
  scanC_kernel<<<SC_NB, SC_TPB, 0, stream>>>(count, bsum, start);
  fillb_kernel<<<NBT, 256, 0, stream>>>(bstage, bstart, bcnt, start, csr);

  const int SEMG = (N + 63) / 64;

  // ---- user side
  conv_kernel<<<N / 4, 256, 0, stream>>>(hib, si, su, csr, start, count, zb0);
  conv_kernel<<<N / 4, 256, 0, stream>>>(hub, su + N8, su + 2 * (size_t)N8, csr,
                                         start + N, count + N, zb1);
  hipMemsetAsync(sc, 0, 2 * sizeof(float), stream);
  semscore_kernel<<<SEMG, 256, 0, stream>>>(zb0, zb1, wkT, bk, q, sc);
  attn_kernel<<<1, 1, 0, stream>>>(sc, 1.0f / (float)N);
  final_kernel<<<N / 16, 256, 0, stream>>>(zb0, zb1, sc + 2, Wl, bl, out_u);

  // ---- item side
  conv_kernel<<<N / 4, 256, 0, stream>>>(hub, su + 3 * (size_t)N8, si + N8, csr,
                                         start + 2 * N, count + 2 * N, zb0);
  conv_kernel<<<N / 4, 256, 0, stream>>>(hib, si + 2 * (size_t)N8, si + 3 * (size_t)N8, csr,
                                         start + 3 * N, count + 3 * N, zb1);
  hipMemsetAsync(sc, 0, 2 * sizeof(float), stream);
  semscore_kernel<<<SEMG, 256, 0, stream>>>(zb0, zb1, wkT, bk, q, sc);
  attn_kernel<<<1, 1, 0, stream>>>(sc, 1.0f / (float)N);
  final_kernel<<<N / 16, 256, 0, stream>>>(zb0, zb1, sc + 2, Wl, bl, out_i);
}

// Round 7
// 939.334 us; speedup vs baseline: 2.1336x; 1.0060x over previous
//
#include <hip/hip_runtime.h>
#include <math.h>

#define N     50000
#define F_IN  128
#define HID   256
#define E     800000
#define OUTD  64
#define NEG   0.2f
#define N8    (N * 8)
#define NTOT  (4 * N)
#define SEMG  ((N + 63) / 64)        // 782
#define FING  (N / 16)               // 3125

// hierarchical scan geometry
#define SC_TPB   256
#define SC_PERB  2048
#define SC_NB    ((NTOT + SC_PERB - 1) / SC_PERB)   // 98

// bucket sort geometry
#define BSH   7                      // bucket = dst >> 7 (128 dsts/bucket)
#define NBUK  ((N + 127) / 128)      // 391
#define NBT   (4 * NBUK)             // 1564
#define EPB1  8192
#define NB1   ((E + EPB1 - 1) / EPB1) // 98

typedef float4 f4;
typedef unsigned int u32;
typedef unsigned short ush;
typedef float f32x4 __attribute__((ext_vector_type(4)));
typedef short bf16x8 __attribute__((ext_vector_type(8)));

static __device__ __forceinline__ float lrelu(float x) { return x >= 0.f ? x : NEG * x; }
static __device__ __forceinline__ u32 bfr(float x) {
  u32 u = __float_as_uint(x);
  return (u + 0x7fffu + ((u >> 16) & 1u)) >> 16;
}
static __device__ __forceinline__ float bf2f(u32 us) { return __uint_as_float(us << 16); }
// tanh(x) = 1 - 2/(exp(2x)+1)
static __device__ __forceinline__ float tanh_fast(float x) {
  float e = __expf(2.f * x);
  return fmaf(-2.f, __builtin_amdgcn_rcpf(e + 1.f), 1.f);
}

// ---------------------------------------------------------------------------
// Projection + fused per-node attention scores.
// ---------------------------------------------------------------------------
__global__ __launch_bounds__(256) void proj_kernel(
    const float* __restrict__ x, const float* __restrict__ W, const float* __restrict__ b,
    const float* __restrict__ a0, const float* __restrict__ a1,
    const float* __restrict__ a2, const float* __restrict__ a3,
    ush* __restrict__ hb, float* __restrict__ sdst)
{
  __shared__ float xT[F_IN * 16];   // [k][i]
  const int t = threadIdx.x;
  const int base = blockIdx.x * 16;
  for (int idx = t; idx < 16 * F_IN; idx += 256) {
    int r = idx & 15, c = idx >> 4;
    xT[c * 16 + r] = x[(size_t)(base + r) * F_IN + c];
  }
  __syncthreads();
  const int ig = t >> 6;
  const int lane = t & 63;
  const int j0 = lane * 4;
  float acc[4][4] = {};
  for (int k = 0; k < F_IN; ++k) {
    f4 w  = *(const f4*)&W[k * HID + j0];
    f4 xv = *(const f4*)&xT[k * 16 + ig * 4];
    const float wa[4] = {w.x, w.y, w.z, w.w};
    const float xa[4] = {xv.x, xv.y, xv.z, xv.w};
#pragma unroll
    for (int i = 0; i < 4; ++i)
#pragma unroll
      for (int j = 0; j < 4; ++j) acc[i][j] = fmaf(xa[i], wa[j], acc[i][j]);
  }
  f4 bv = *(const f4*)&b[j0];
  const float ba[4] = {bv.x, bv.y, bv.z, bv.w};
#pragma unroll
  for (int i = 0; i < 4; ++i) {
#pragma unroll
    for (int j = 0; j < 4; ++j) acc[i][j] += ba[j];
    ushort4 o;
    o.x = (ush)bfr(acc[i][0]); o.y = (ush)bfr(acc[i][1]);
    o.z = (ush)bfr(acc[i][2]); o.w = (ush)bfr(acc[i][3]);
    *(ushort4*)&hb[(size_t)(base + ig * 4 + i) * HID + j0] = o;
  }
  const int head = lane >> 3;
  const float* av[4] = {a0, a1, a2, a3};
#pragma unroll
  for (int k = 0; k < 4; ++k) {
    f4 a = *(const f4*)&av[k][j0];
#pragma unroll
    for (int i = 0; i < 4; ++i) {
      float p = acc[i][0] * a.x + acc[i][1] * a.y + acc[i][2] * a.z + acc[i][3] * a.w;
      p += __shfl_xor(p, 1);
      p += __shfl_xor(p, 2);
      p += __shfl_xor(p, 4);
      if ((lane & 7) == 0)
        sdst[(size_t)k * N8 + (size_t)(base + ig * 4 + i) * 8 + head] = p;
    }
  }
}

// ---------------------------------------------------------------------------
__global__ void wkt_kernel(const float* __restrict__ Wk, ush* __restrict__ wkT)
{
  int idx = blockIdx.x * 256 + threadIdx.x;
  int n = idx >> 8, k = idx & 255;
  wkT[idx] = (ush)bfr(Wk[k * HID + n]);
}

// ---------------------------------------------------------------------------
// CSR build, per-block multisplit (unchanged — off the critical list)
// ---------------------------------------------------------------------------
__global__ __launch_bounds__(256) void histb_kernel(
    const int* __restrict__ d0, const int* __restrict__ d1,
    const int* __restrict__ d2, const int* __restrict__ d3,
    int* __restrict__ bcnt)
{
  __shared__ int lh[NBUK];
  const int rel = blockIdx.x / NB1;
  const int blk = blockIdx.x % NB1;
  for (int j = threadIdx.x; j < NBUK; j += 256) lh[j] = 0;
  __syncthreads();
  const int* dp = rel == 0 ? d0 : rel == 1 ? d1 : rel == 2 ? d2 : d3;
  const int base = blk * EPB1;
#pragma unroll 4
  for (int k = 0; k < EPB1 / 256; ++k) {
    int i = base + k * 256 + threadIdx.x;
    if (i < E) atomicAdd(&lh[dp[i] >> BSH], 1);
  }
  __syncthreads();
  for (int j = threadIdx.x; j < NBUK; j += 256)
    if (lh[j]) atomicAdd(&bcnt[rel * NBUK + j], lh[j]);
}

__global__ __launch_bounds__(256) void bscan_kernel(
    const int* __restrict__ bcnt, int* __restrict__ bstart, int* __restrict__ bcur)
{
  __shared__ int part[256];
  const int t = threadIdx.x;
  const int chunk = (NBT + 255) / 256;   // 7
  const int b = t * chunk;
  const int e = min(NBT, b + chunk);
  int s = 0;
  for (int i = b; i < e; ++i) s += bcnt[i];
  part[t] = s;
  __syncthreads();
  for (int off = 1; off < 256; off <<= 1) {
    int u = (t >= off) ? part[t - off] : 0;
    __syncthreads();
    part[t] += u;
    __syncthreads();
  }
  int run = part[t] - s;
  for (int i = b; i < e; ++i) {
    bstart[i] = run;
    bcur[i] = run;
    run += bcnt[i];
  }
}

__global__ __launch_bounds__(256) void scat2_kernel(
    const int* __restrict__ s0, const int* __restrict__ d0,
    const int* __restrict__ s1, const int* __restrict__ d1,
    const int* __restrict__ s2, const int* __restrict__ d2,
    const int* __restrict__ s3, const int* __restrict__ d3,
    int* __restrict__ bcur, u32* __restrict__ bstage)
{
  __shared__ int lh[NBUK];
  const int rel = blockIdx.x / NB1;
  const int blk = blockIdx.x % NB1;
  const int* sp = rel == 0 ? s0 : rel == 1 ? s1 : rel == 2 ? s2 : s3;
  const int* dp = rel == 0 ? d0 : rel == 1 ? d1 : rel == 2 ? d2 : d3;
  for (int j = threadIdx.x; j < NBUK; j += 256) lh[j] = 0;
  __syncthreads();
  const int base = blk * EPB1;
#pragma unroll 4
  for (int k = 0; k < EPB1 / 256; ++k) {
    int i = base + k * 256 + threadIdx.x;
    if (i < E) atomicAdd(&lh[dp[i] >> BSH], 1);
  }
  __syncthreads();
  for (int j = threadIdx.x; j < NBUK; j += 256) {
    int c = lh[j];
    lh[j] = c ? atomicAdd(&bcur[rel * NBUK + j], c) : 0;
  }
  __syncthreads();
#pragma unroll 4
  for (int k = 0; k < EPB1 / 256; ++k) {
    int i = base + k * 256 + threadIdx.x;
    if (i < E) {
      int dst = dp[i], src = sp[i];
      int pos = atomicAdd(&lh[dst >> BSH], 1);   // LDS atomic (fast)
      bstage[pos] = ((u32)dst << 16) | (u32)src;
    }
  }
}

__global__ __launch_bounds__(256) void cntb_kernel(
    const u32* __restrict__ bstage, const int* __restrict__ bstart,
    const int* __restrict__ bcnt, int* __restrict__ count)
{
  __shared__ int lcnt[128];
  const int bb = blockIdx.x;
  const int rel = bb / NBUK, b = bb % NBUK;
  if (threadIdx.x < 128) lcnt[threadIdx.x] = 0;
  __syncthreads();
  const int rb = bstart[bb];
  const int cnt = bcnt[bb];
  for (int k = threadIdx.x; k < cnt; k += 256)
    atomicAdd(&lcnt[(bstage[rb + k] >> 16) & 127], 1);
  __syncthreads();
  const int fb = rel * N + b * 128;
  const int lim = min(128, N - b * 128);
  if (threadIdx.x < lim) count[fb + threadIdx.x] = lcnt[threadIdx.x];
}

__global__ __launch_bounds__(SC_TPB) void scanA_kernel(
    const int* __restrict__ count, int* __restrict__ bsum)
{
  __shared__ int red[4];
  const int t = threadIdx.x;
  const int base = blockIdx.x * SC_PERB + t * 8;
  int s = 0;
  if (base + 8 <= NTOT) {
    int4 a = *(const int4*)&count[base];
    int4 b = *(const int4*)&count[base + 4];
    s = a.x + a.y + a.z + a.w + b.x + b.y + b.z + b.w;
  } else {
    for (int i = 0; i < 8; ++i) { int idx = base + i; if (idx < NTOT) s += count[idx]; }
  }
#pragma unroll
  for (int off = 1; off < 64; off <<= 1) s += __shfl_xor(s, off);
  if ((t & 63) == 0) red[t >> 6] = s;
  __syncthreads();
  if (t == 0) bsum[blockIdx.x] = red[0] + red[1] + red[2] + red[3];
}

__global__ __launch_bounds__(128) void scanB_kernel(int* __restrict__ bsum)
{
  __shared__ int tmp[128];
  const int t = threadIdx.x;
  int v = (t < SC_NB) ? bsum[t] : 0;
  tmp[t] = v;
  __syncthreads();
  for (int off = 1; off < 128; off <<= 1) {
    int u = (t >= off) ? tmp[t - off] : 0;
    __syncthreads();
    tmp[t] += u;
    __syncthreads();
  }
  if (t < SC_NB) bsum[t] = tmp[t] - v;  // exclusive
}

__global__ __launch_bounds__(SC_TPB) void scanC_kernel(
    const int* __restrict__ count, const int* __restrict__ bsum,
    int* __restrict__ start)
{
  __shared__ int ts[SC_TPB];
  const int t = threadIdx.x;
  const int base = blockIdx.x * SC_PERB + t * 8;
  int c[8];
  int s = 0;
#pragma unroll
  for (int i = 0; i < 8; ++i) {
    int idx = base + i;
    c[i] = (idx < NTOT) ? count[idx] : 0;
    s += c[i];
  }
  ts[t] = s;
  __syncthreads();
  for (int off = 1; off < SC_TPB; off <<= 1) {
    int u = (t >= off) ? ts[t - off] : 0;
    __syncthreads();
    ts[t] += u;
    __syncthreads();
  }
  int run = ts[t] - s + bsum[blockIdx.x];
#pragma unroll
  for (int i = 0; i < 8; ++i) {
    int idx = base + i;
    if (idx < NTOT) {
      start[idx] = run;
      run += c[i];
    }
  }
}

__global__ __launch_bounds__(256) void fillb_kernel(
    const u32* __restrict__ bstage, const int* __restrict__ bstart,
    const int* __restrict__ bcnt, const int* __restrict__ start,
    int* __restrict__ csr)
{
  __shared__ int lcur[128];
  const int bb = blockIdx.x;           // rel*NBUK + b
  const int rel = bb / NBUK, b = bb % NBUK;
  const int fb = rel * N + b * 128;
  const int lim = min(128, N - b * 128);
  if (threadIdx.x < lim) lcur[threadIdx.x] = start[fb + threadIdx.x];
  __syncthreads();
  const int rb = bstart[bb];
  const int cnt = bcnt[bb];
  for (int k = threadIdx.x; k < cnt; k += 256) {
    u32 pk = bstage[rb + k];
    int ldst = (pk >> 16) & 127;
    int pos = atomicAdd(&lcur[ldst], 1);
    csr[pos] = (int)(pk & 0xffffu);
  }
}

// ---------------------------------------------------------------------------
// Relation conv, bf16 row gathers, fp32 accumulate, bf16 z output.
// 4-edge unroll: 4 gather rows (2KB) in flight per wave for L3 latency cover.
// ---------------------------------------------------------------------------
__global__ __launch_bounds__(256) void conv_kernel(
    const ush* __restrict__ xsb, const float* __restrict__ ss,
    const float* __restrict__ sd, const int* __restrict__ csr,
    const int* __restrict__ start, const int* __restrict__ count,
    ush* __restrict__ z)
{
  const int dst = blockIdx.x * 4 + (threadIdx.x >> 6);
  const int lane = threadIdx.x & 63;
  const int e0 = start[dst];
  const int ne = count[dst];

  const int h1 = lane & 7;
  const float sdv1 = sd[dst * 8 + h1];
  float den = 0.f;
  for (int j = lane >> 3; j < ne; j += 8)
    den += __expf(lrelu(ss[csr[e0 + j] * 8 + h1] + sdv1));
  den += __shfl_xor(den, 8);
  den += __shfl_xor(den, 16);
  den += __shfl_xor(den, 32);
  const int h2 = lane >> 3;
  const float inv_den = 1.f / (__shfl(den, h2) + 1e-16f);
  const float sdv2 = sd[dst * 8 + h2];

  float a0 = 0.f, a1 = 0.f, a2 = 0.f, a3 = 0.f;
  int j = 0;
  for (; j + 4 <= ne; j += 4) {
    int sA = csr[e0 + j], sB = csr[e0 + j + 1];
    int sC = csr[e0 + j + 2], sD = csr[e0 + j + 3];
    float lA = ss[sA * 8 + h2], lB = ss[sB * 8 + h2];
    float lC = ss[sC * 8 + h2], lD = ss[sD * 8 + h2];
    ushort4 vA = *(const ushort4*)&xsb[(size_t)sA * HID + lane * 4];
    ushort4 vB = *(const ushort4*)&xsb[(size_t)sB * HID + lane * 4];
    ushort4 vC = *(const ushort4*)&xsb[(size_t)sC * HID + lane * 4];
    ushort4 vD = *(const ushort4*)&xsb[(size_t)sD * HID + lane * 4];
    float alA = __expf(lrelu(lA + sdv2)) * inv_den;
    float alB = __expf(lrelu(lB + sdv2)) * inv_den;
    float alC = __expf(lrelu(lC + sdv2)) * inv_den;
    float alD = __expf(lrelu(lD + sdv2)) * inv_den;
    a0 = fmaf(alA, bf2f(vA.x), a0); a1 = fmaf(alA, bf2f(vA.y), a1);
    a2 = fmaf(alA, bf2f(vA.z), a2); a3 = fmaf(alA, bf2f(vA.w), a3);
    a0 = fmaf(alB, bf2f(vB.x), a0); a1 = fmaf(alB, bf2f(vB.y), a1);
    a2 = fmaf(alB, bf2f(vB.z), a2); a3 = fmaf(alB, bf2f(vB.w), a3);
    a0 = fmaf(alC, bf2f(vC.x), a0); a1 = fmaf(alC, bf2f(vC.y), a1);
    a2 = fmaf(alC, bf2f(vC.z), a2); a3 = fmaf(alC, bf2f(vC.w), a3);
    a0 = fmaf(alD, bf2f(vD.x), a0); a1 = fmaf(alD, bf2f(vD.y), a1);
    a2 = fmaf(alD, bf2f(vD.z), a2); a3 = fmaf(alD, bf2f(vD.w), a3);
  }
  for (; j < ne; ++j) {
    int sA = csr[e0 + j];
    float alA = __expf(lrelu(ss[sA * 8 + h2] + sdv2)) * inv_den;
    ushort4 vA = *(const ushort4*)&xsb[(size_t)sA * HID + lane * 4];
    a0 = fmaf(alA, bf2f(vA.x), a0); a1 = fmaf(alA, bf2f(vA.y), a1);
    a2 = fmaf(alA, bf2f(vA.z), a2); a3 = fmaf(alA, bf2f(vA.w), a3);
  }
  ushort4 o;
  o.x = (ush)bfr(fmaxf(a0, 0.f));
  o.y = (ush)bfr(fmaxf(a1, 0.f));
  o.z = (ush)bfr(fmaxf(a2, 0.f));
  o.w = (ush)bfr(fmaxf(a3, 0.f));
  *(ushort4*)&z[(size_t)dst * HID + lane * 4] = o;
}

// ---------------------------------------------------------------------------
// Semantic scores, register-only MFMA, BOTH metapath-sides in one launch
// (grid 2*SEMG) so resident-wave count doubles — this kernel is purely
// latency-bound (R6: MfmaUtil 3.8%, VALU 6.3%, occupancy 24%).
// ---------------------------------------------------------------------------
__global__ __launch_bounds__(256) void semscore_kernel(
    const ush* __restrict__ zbu0, const ush* __restrict__ zbu1,
    const ush* __restrict__ zbi0, const ush* __restrict__ zbi1,
    const ush* __restrict__ wkT, const float* __restrict__ bk,
    const float* __restrict__ q, float* __restrict__ score)
{
  const int bid = blockIdx.x;
  const int side = bid >= SEMG;
  const ush* zA = side ? zbi0 : zbu0;
  const ush* zB = side ? zbi1 : zbu1;
  const int t = threadIdx.x;
  const int w = t >> 6;
  const int l = t & 63;
  const int lrow = l & 15;
  const int kgrp = l >> 4;
  const int rbase = (bid - side * SEMG) * 64 + w * 16;
  int arow = rbase + lrow;
  if (arow >= N) arow = N - 1;   // dup row; masked in epilogue

  bf16x8 A0[8], A1[8];
  const ush* pa0 = &zA[(size_t)arow * HID + kgrp * 8];
  const ush* pa1 = &zB[(size_t)arow * HID + kgrp * 8];
#pragma unroll
  for (int ks = 0; ks < 8; ++ks) {
    A0[ks] = *(const bf16x8*)(pa0 + ks * 32);
    A1[ks] = *(const bf16x8*)(pa1 + ks * 32);
  }

  float s0 = 0.f, s1 = 0.f;
#pragma unroll
  for (int nt = 0; nt < 16; ++nt) {
    const ush* pb = &wkT[(size_t)(nt * 16 + lrow) * HID + kgrp * 8];
    bf16x8 B[8];
#pragma unroll
    for (int ks = 0; ks < 8; ++ks) B[ks] = *(const bf16x8*)(pb + ks * 32);
    f32x4 acc0 = {0.f, 0.f, 0.f, 0.f};
    f32x4 acc1 = {0.f, 0.f, 0.f, 0.f};
#pragma unroll
    for (int ks = 0; ks < 8; ++ks) {
      acc0 = __builtin_amdgcn_mfma_f32_16x16x32_bf16(A0[ks], B[ks], acc0, 0, 0, 0);
      acc1 = __builtin_amdgcn_mfma_f32_16x16x32_bf16(A1[ks], B[ks], acc1, 0, 0, 0);
    }
    const int col = nt * 16 + lrow;
    const float bkv = bk[col], qv = q[col];
#pragma unroll
    for (int i = 0; i < 4; ++i) {
      int gr = rbase + kgrp * 4 + i;     // D row for this lane/reg
      if (gr < N) {
        s0 += tanh_fast(acc0[i] + bkv) * qv;
        s1 += tanh_fast(acc1[i] + bkv) * qv;
      }
    }
  }
#pragma unroll
  for (int off = 1; off < 64; off <<= 1) {
    s0 += __shfl_xor(s0, off);
    s1 += __shfl_xor(s1, off);
  }
  if (l == 0) {
    atomicAdd(&score[side * 2], s0);
    atomicAdd(&score[side * 2 + 1], s1);
  }
}

__global__ void attn2_kernel(float* __restrict__ score, float inv_n)
{
#pragma unroll
  for (int s = 0; s < 2; ++s) {
    float s0 = score[2 * s] * inv_n, s1 = score[2 * s + 1] * inv_n;
    float m = fmaxf(s0, s1);
    float e0 = __expf(s0 - m), e1 = __expf(s1 - m);
    float d = e0 + e1;
    score[4 + 2 * s] = e0 / d;
    score[5 + 2 * s] = e1 / d;
  }
}

// ---------------------------------------------------------------------------
// Final: out[n,64] = (a0*z0[n]+a1*z1[n]) @ Wl + bl, both sides one launch.
// ---------------------------------------------------------------------------
__global__ __launch_bounds__(256) void final_kernel(
    const ush* __restrict__ zbu0, const ush* __restrict__ zbu1,
    const ush* __restrict__ zbi0, const ush* __restrict__ zbi1,
    const float* __restrict__ attn, const float* __restrict__ Wl,
    const float* __restrict__ bl, float* __restrict__ out)
{
  __shared__ float zT[HID * 16];
  const int bid = blockIdx.x;
  const int side = bid >= FING;
  const ush* z0 = side ? zbi0 : zbu0;
  const ush* z1 = side ? zbi1 : zbu1;
  float* op = out + (size_t)side * N * OUTD;
  const int t = threadIdx.x;
  const int base = (bid - side * FING) * 16;
  const float a0 = attn[side * 2], a1 = attn[side * 2 + 1];
  for (int idx = t; idx < 16 * (HID / 2); idx += 256) {   // 2048 u32 pairs
    int r = idx & 15, cw = idx >> 4;
    u32 v0 = *(const u32*)&z0[(size_t)(base + r) * HID + cw * 2];
    u32 v1 = *(const u32*)&z1[(size_t)(base + r) * HID + cw * 2];
    zT[(2 * cw) * 16 + r]     = a0 * bf2f(v0 & 0xffffu) + a1 * bf2f(v1 & 0xffffu);
    zT[(2 * cw + 1) * 16 + r] = a0 * bf2f(v0 >> 16) + a1 * bf2f(v1 >> 16);
  }
  __syncthreads();
  const int ig = t >> 6;
  const int cc = t & 63;
  float acc[4] = {};
  for (int k = 0; k < HID; ++k) {
    float w = Wl[k * OUTD + cc];
    f4 xv = *(const f4*)&zT[k * 16 + ig * 4];
    acc[0] = fmaf(xv.x, w, acc[0]);
    acc[1] = fmaf(xv.y, w, acc[1]);
    acc[2] = fmaf(xv.z, w, acc[2]);
    acc[3] = fmaf(xv.w, w, acc[3]);
  }
  float bb = bl[cc];
#pragma unroll
  for (int i = 0; i < 4; ++i)
    op[(size_t)(base + ig * 4 + i) * OUTD + cc] = acc[i] + bb;
}

// ---------------------------------------------------------------------------
extern "C" void kernel_launch(void* const* d_in, const int* in_sizes, int n_in,
                              void* d_out, int out_size, void* d_ws, size_t ws_size,
                              hipStream_t stream)
{
  const float* x_user = (const float*)d_in[0];
  const float* x_item = (const float*)d_in[1];
  const int*   e_ui   = (const int*)d_in[2];
  const int*   e_iu   = (const int*)d_in[3];
  const int*   e_uu   = (const int*)d_in[4];
  const int*   e_ii   = (const int*)d_in[5];
  const float* Wp_u   = (const float*)d_in[6];
  const float* bp_u   = (const float*)d_in[7];
  const float* Wp_i   = (const float*)d_in[8];
  const float* bp_i   = (const float*)d_in[9];
  const float* as_ui  = (const float*)d_in[10];
  const float* ad_ui  = (const float*)d_in[11];
  const float* as_iu  = (const float*)d_in[12];
  const float* ad_iu  = (const float*)d_in[13];
  const float* as_uu  = (const float*)d_in[14];
  const float* ad_uu  = (const float*)d_in[15];
  const float* as_ii  = (const float*)d_in[16];
  const float* ad_ii  = (const float*)d_in[17];
  const float* Wk     = (const float*)d_in[18];
  const float* bk     = (const float*)d_in[19];
  const float* q      = (const float*)d_in[20];
  const float* Wl     = (const float*)d_in[21];
  const float* bl     = (const float*)d_in[22];

  const size_t NH = (size_t)N * HID;
  size_t need = (8 * (size_t)N8 + 8) * 4                     // su,si,sc (f32)
              + (6 * NH + (size_t)HID * HID) * 2             // 4x z, hub, hib, wkT (bf16)
              + ((size_t)8 * N + 4 * (size_t)E + 3 * NBT + 128 + 64) * 4;
  if (ws_size < need) {
    hipMemsetAsync(d_out, 0x7f, (size_t)out_size * sizeof(float), stream);
    return;
  }
  float* su = (float*)d_ws;
  float* si = su + 4 * (size_t)N8;
  float* sc = si + 4 * (size_t)N8;
  ush* zbu0 = (ush*)(sc + 8);
  ush* zbu1 = zbu0 + NH;
  ush* zbi0 = zbu1 + NH;
  ush* zbi1 = zbi0 + NH;
  ush* hub  = zbi1 + NH;
  ush* hib  = hub + NH;
  ush* wkT  = hib + NH;
  int* count  = (int*)(wkT + (size_t)HID * HID);
  int* bcnt   = count + NTOT;
  int* start  = bcnt + NBT;
  int* bstart = start + NTOT;
  int* bcur   = bstart + NBT;
  int* bsum   = bcur + NBT;
  int* csr    = bsum + 128;
  u32* bstage = (u32*)zbu0;     // aliases zbu0 (dead until first conv)

  wkt_kernel<<<HID * HID / 256, 256, 0, stream>>>(Wk, wkT);

  proj_kernel<<<N / 16, 256, 0, stream>>>(x_user, Wp_u, bp_u,
                                          ad_iu, as_uu, ad_uu, as_ui, hub, su);
  proj_kernel<<<N / 16, 256, 0, stream>>>(x_item, Wp_i, bp_i,
                                          as_iu, ad_ui, as_ii, ad_ii, hib, si);

  // batched CSR build via per-block multisplit: rel 0=iu, 1=uu, 2=ui, 3=ii
  hipMemsetAsync(bcnt, 0, NBT * sizeof(int), stream);
  histb_kernel<<<4 * NB1, 256, 0, stream>>>(e_iu + E, e_uu + E, e_ui + E, e_ii + E, bcnt);
  bscan_kernel<<<1, 256, 0, stream>>>(bcnt, bstart, bcur);
  scat2_kernel<<<4 * NB1, 256, 0, stream>>>(e_iu, e_iu + E, e_uu, e_uu + E,
                                            e_ui, e_ui + E, e_ii, e_ii + E,
                                            bcur, bstage);
  cntb_kernel<<<NBT, 256, 0, stream>>>(bstage, bstart, bcnt, count);
  scanA_kernel<<<SC_NB, SC_TPB, 0, stream>>>(count, bsum);
  scanB_kernel<<<1, 128, 0, stream>>>(bsum);
  scanC_kernel<<<SC_NB, SC_TPB, 0, stream>>>(count, bsum, start);
  fillb_kernel<<<NBT, 256, 0, stream>>>(bstage, bstart, bcnt, start, csr);

  // all 4 relation convs (independent; back-to-back for full-device fill)
  conv_kernel<<<N / 4, 256, 0, stream>>>(hib, si, su, csr, start, count, zbu0);
  conv_kernel<<<N / 4, 256, 0, stream>>>(hub, su + N8, su + 2 * (size_t)N8, csr,
                                         start + N, count + N, zbu1);
  conv_kernel<<<N / 4, 256, 0, stream>>>(hub, su + 3 * (size_t)N8, si + N8, csr,
                                         start + 2 * N, count + 2 * N, zbi0);
  conv_kernel<<<N / 4, 256, 0, stream>>>(hib, si + 2 * (size_t)N8, si + 3 * (size_t)N8, csr,
                                         start + 3 * N, count + 3 * N, zbi1);

  // semantic attention: both sides in one launch
  hipMemsetAsync(sc, 0, 4 * sizeof(float), stream);
  semscore_kernel<<<2 * SEMG, 256, 0, stream>>>(zbu0, zbu1, zbi0, zbi1, wkT, bk, q, sc);
  attn2_kernel<<<1, 1, 0, stream>>>(sc, 1.0f / (float)N);

  // final linear: both sides in one launch
  final_kernel<<<2 * FING, 256, 0, stream>>>(zbu0, zbu1, zbi0, zbi1, sc + 4, Wl, bl,
                                             (float*)d_out);
}

// Round 8
// 929.506 us; speedup vs baseline: 2.1561x; 1.0106x over previous
//
#include <hip/hip_runtime.h>
#include <math.h>

#define N     50000
#define F_IN  128
#define HID   256
#define E     800000
#define OUTD  64
#define NEG   0.2f
#define N8    (N * 8)
#define NTOT  (4 * N)
#define SEMG  ((N + 63) / 64)        // 782
#define FING  (N / 16)               // 3125

// hierarchical scan geometry
#define SC_TPB   256
#define SC_PERB  2048
#define SC_NB    ((NTOT + SC_PERB - 1) / SC_PERB)   // 98

// bucket sort geometry
#define BSH   7                      // bucket = dst >> 7 (128 dsts/bucket)
#define NBUK  ((N + 127) / 128)      // 391
#define NBT   (4 * NBUK)             // 1564
#define EPB1  8192
#define NB1   ((E + EPB1 - 1) / EPB1) // 98

typedef float4 f4;
typedef unsigned int u32;
typedef unsigned short ush;
typedef float f32x4 __attribute__((ext_vector_type(4)));
typedef short bf16x8 __attribute__((ext_vector_type(8)));

static __device__ __forceinline__ float lrelu(float x) { return x >= 0.f ? x : NEG * x; }
static __device__ __forceinline__ u32 bfr(float x) {
  u32 u = __float_as_uint(x);
  return (u + 0x7fffu + ((u >> 16) & 1u)) >> 16;
}
static __device__ __forceinline__ float bf2f(u32 us) { return __uint_as_float(us << 16); }
// tanh(x) = 1 - 2/(exp(2x)+1)
static __device__ __forceinline__ float tanh_fast(float x) {
  float e = __expf(2.f * x);
  return fmaf(-2.f, __builtin_amdgcn_rcpf(e + 1.f), 1.f);
}

// ---------------------------------------------------------------------------
// Projection + fused per-node attention scores.
// ---------------------------------------------------------------------------
__global__ __launch_bounds__(256) void proj_kernel(
    const float* __restrict__ x, const float* __restrict__ W, const float* __restrict__ b,
    const float* __restrict__ a0, const float* __restrict__ a1,
    const float* __restrict__ a2, const float* __restrict__ a3,
    ush* __restrict__ hb, float* __restrict__ sdst)
{
  __shared__ float xT[F_IN * 16];   // [k][i]
  const int t = threadIdx.x;
  const int base = blockIdx.x * 16;
  for (int idx = t; idx < 16 * F_IN; idx += 256) {
    int r = idx & 15, c = idx >> 4;
    xT[c * 16 + r] = x[(size_t)(base + r) * F_IN + c];
  }
  __syncthreads();
  const int ig = t >> 6;
  const int lane = t & 63;
  const int j0 = lane * 4;
  float acc[4][4] = {};
  for (int k = 0; k < F_IN; ++k) {
    f4 w  = *(const f4*)&W[k * HID + j0];
    f4 xv = *(const f4*)&xT[k * 16 + ig * 4];
    const float wa[4] = {w.x, w.y, w.z, w.w};
    const float xa[4] = {xv.x, xv.y, xv.z, xv.w};
#pragma unroll
    for (int i = 0; i < 4; ++i)
#pragma unroll
      for (int j = 0; j < 4; ++j) acc[i][j] = fmaf(xa[i], wa[j], acc[i][j]);
  }
  f4 bv = *(const f4*)&b[j0];
  const float ba[4] = {bv.x, bv.y, bv.z, bv.w};
#pragma unroll
  for (int i = 0; i < 4; ++i) {
#pragma unroll
    for (int j = 0; j < 4; ++j) acc[i][j] += ba[j];
    ushort4 o;
    o.x = (ush)bfr(acc[i][0]); o.y = (ush)bfr(acc[i][1]);
    o.z = (ush)bfr(acc[i][2]); o.w = (ush)bfr(acc[i][3]);
    *(ushort4*)&hb[(size_t)(base + ig * 4 + i) * HID + j0] = o;
  }
  const int head = lane >> 3;
  const float* av[4] = {a0, a1, a2, a3};
#pragma unroll
  for (int k = 0; k < 4; ++k) {
    f4 a = *(const f4*)&av[k][j0];
#pragma unroll
    for (int i = 0; i < 4; ++i) {
      float p = acc[i][0] * a.x + acc[i][1] * a.y + acc[i][2] * a.z + acc[i][3] * a.w;
      p += __shfl_xor(p, 1);
      p += __shfl_xor(p, 2);
      p += __shfl_xor(p, 4);
      if ((lane & 7) == 0)
        sdst[(size_t)k * N8 + (size_t)(base + ig * 4 + i) * 8 + head] = p;
    }
  }
}

// ---------------------------------------------------------------------------
__global__ void wkt_kernel(const float* __restrict__ Wk, ush* __restrict__ wkT)
{
  int idx = blockIdx.x * 256 + threadIdx.x;
  int n = idx >> 8, k = idx & 255;
  wkT[idx] = (ush)bfr(Wk[k * HID + n]);
}

// ---------------------------------------------------------------------------
// CSR build, per-block multisplit (unchanged — off the critical list)
// ---------------------------------------------------------------------------
__global__ __launch_bounds__(256) void histb_kernel(
    const int* __restrict__ d0, const int* __restrict__ d1,
    const int* __restrict__ d2, const int* __restrict__ d3,
    int* __restrict__ bcnt)
{
  __shared__ int lh[NBUK];
  const int rel = blockIdx.x / NB1;
  const int blk = blockIdx.x % NB1;
  for (int j = threadIdx.x; j < NBUK; j += 256) lh[j] = 0;
  __syncthreads();
  const int* dp = rel == 0 ? d0 : rel == 1 ? d1 : rel == 2 ? d2 : d3;
  const int base = blk * EPB1;
#pragma unroll 4
  for (int k = 0; k < EPB1 / 256; ++k) {
    int i = base + k * 256 + threadIdx.x;
    if (i < E) atomicAdd(&lh[dp[i] >> BSH], 1);
  }
  __syncthreads();
  for (int j = threadIdx.x; j < NBUK; j += 256)
    if (lh[j]) atomicAdd(&bcnt[rel * NBUK + j], lh[j]);
}

__global__ __launch_bounds__(256) void bscan_kernel(
    const int* __restrict__ bcnt, int* __restrict__ bstart, int* __restrict__ bcur)
{
  __shared__ int part[256];
  const int t = threadIdx.x;
  const int chunk = (NBT + 255) / 256;   // 7
  const int b = t * chunk;
  const int e = min(NBT, b + chunk);
  int s = 0;
  for (int i = b; i < e; ++i) s += bcnt[i];
  part[t] = s;
  __syncthreads();
  for (int off = 1; off < 256; off <<= 1) {
    int u = (t >= off) ? part[t - off] : 0;
    __syncthreads();
    part[t] += u;
    __syncthreads();
  }
  int run = part[t] - s;
  for (int i = b; i < e; ++i) {
    bstart[i] = run;
    bcur[i] = run;
    run += bcnt[i];
  }
}

__global__ __launch_bounds__(256) void scat2_kernel(
    const int* __restrict__ s0, const int* __restrict__ d0,
    const int* __restrict__ s1, const int* __restrict__ d1,
    const int* __restrict__ s2, const int* __restrict__ d2,
    const int* __restrict__ s3, const int* __restrict__ d3,
    int* __restrict__ bcur, u32* __restrict__ bstage)
{
  __shared__ int lh[NBUK];
  const int rel = blockIdx.x / NB1;
  const int blk = blockIdx.x % NB1;
  const int* sp = rel == 0 ? s0 : rel == 1 ? s1 : rel == 2 ? s2 : s3;
  const int* dp = rel == 0 ? d0 : rel == 1 ? d1 : rel == 2 ? d2 : d3;
  for (int j = threadIdx.x; j < NBUK; j += 256) lh[j] = 0;
  __syncthreads();
  const int base = blk * EPB1;
#pragma unroll 4
  for (int k = 0; k < EPB1 / 256; ++k) {
    int i = base + k * 256 + threadIdx.x;
    if (i < E) atomicAdd(&lh[dp[i] >> BSH], 1);
  }
  __syncthreads();
  for (int j = threadIdx.x; j < NBUK; j += 256) {
    int c = lh[j];
    lh[j] = c ? atomicAdd(&bcur[rel * NBUK + j], c) : 0;
  }
  __syncthreads();
#pragma unroll 4
  for (int k = 0; k < EPB1 / 256; ++k) {
    int i = base + k * 256 + threadIdx.x;
    if (i < E) {
      int dst = dp[i], src = sp[i];
      int pos = atomicAdd(&lh[dst >> BSH], 1);   // LDS atomic (fast)
      bstage[pos] = ((u32)dst << 16) | (u32)src;
    }
  }
}

__global__ __launch_bounds__(256) void cntb_kernel(
    const u32* __restrict__ bstage, const int* __restrict__ bstart,
    const int* __restrict__ bcnt, int* __restrict__ count)
{
  __shared__ int lcnt[128];
  const int bb = blockIdx.x;
  const int rel = bb / NBUK, b = bb % NBUK;
  if (threadIdx.x < 128) lcnt[threadIdx.x] = 0;
  __syncthreads();
  const int rb = bstart[bb];
  const int cnt = bcnt[bb];
  for (int k = threadIdx.x; k < cnt; k += 256)
    atomicAdd(&lcnt[(bstage[rb + k] >> 16) & 127], 1);
  __syncthreads();
  const int fb = rel * N + b * 128;
  const int lim = min(128, N - b * 128);
  if (threadIdx.x < lim) count[fb + threadIdx.x] = lcnt[threadIdx.x];
}

__global__ __launch_bounds__(SC_TPB) void scanA_kernel(
    const int* __restrict__ count, int* __restrict__ bsum)
{
  __shared__ int red[4];
  const int t = threadIdx.x;
  const int base = blockIdx.x * SC_PERB + t * 8;
  int s = 0;
  if (base + 8 <= NTOT) {
    int4 a = *(const int4*)&count[base];
    int4 b = *(const int4*)&count[base + 4];
    s = a.x + a.y + a.z + a.w + b.x + b.y + b.z + b.w;
  } else {
    for (int i = 0; i < 8; ++i) { int idx = base + i; if (idx < NTOT) s += count[idx]; }
  }
#pragma unroll
  for (int off = 1; off < 64; off <<= 1) s += __shfl_xor(s, off);
  if ((t & 63) == 0) red[t >> 6] = s;
  __syncthreads();
  if (t == 0) bsum[blockIdx.x] = red[0] + red[1] + red[2] + red[3];
}

__global__ __launch_bounds__(128) void scanB_kernel(int* __restrict__ bsum)
{
  __shared__ int tmp[128];
  const int t = threadIdx.x;
  int v = (t < SC_NB) ? bsum[t] : 0;
  tmp[t] = v;
  __syncthreads();
  for (int off = 1; off < 128; off <<= 1) {
    int u = (t >= off) ? tmp[t - off] : 0;
    __syncthreads();
    tmp[t] += u;
    __syncthreads();
  }
  if (t < SC_NB) bsum[t] = tmp[t] - v;  // exclusive
}

__global__ __launch_bounds__(SC_TPB) void scanC_kernel(
    const int* __restrict__ count, const int* __restrict__ bsum,
    int* __restrict__ start)
{
  __shared__ int ts[SC_TPB];
  const int t = threadIdx.x;
  const int base = blockIdx.x * SC_PERB + t * 8;
  int c[8];
  int s = 0;
#pragma unroll
  for (int i = 0; i < 8; ++i) {
    int idx = base + i;
    c[i] = (idx < NTOT) ? count[idx] : 0;
    s += c[i];
  }
  ts[t] = s;
  __syncthreads();
  for (int off = 1; off < SC_TPB; off <<= 1) {
    int u = (t >= off) ? ts[t - off] : 0;
    __syncthreads();
    ts[t] += u;
    __syncthreads();
  }
  int run = ts[t] - s + bsum[blockIdx.x];
#pragma unroll
  for (int i = 0; i < 8; ++i) {
    int idx = base + i;
    if (idx < NTOT) {
      start[idx] = run;
      run += c[i];
    }
  }
}

__global__ __launch_bounds__(256) void fillb_kernel(
    const u32* __restrict__ bstage, const int* __restrict__ bstart,
    const int* __restrict__ bcnt, const int* __restrict__ start,
    int* __restrict__ csr)
{
  __shared__ int lcur[128];
  const int bb = blockIdx.x;           // rel*NBUK + b
  const int rel = bb / NBUK, b = bb % NBUK;
  const int fb = rel * N + b * 128;
  const int lim = min(128, N - b * 128);
  if (threadIdx.x < lim) lcur[threadIdx.x] = start[fb + threadIdx.x];
  __syncthreads();
  const int rb = bstart[bb];
  const int cnt = bcnt[bb];
  for (int k = threadIdx.x; k < cnt; k += 256) {
    u32 pk = bstage[rb + k];
    int ldst = (pk >> 16) & 127;
    int pos = atomicAdd(&lcur[ldst], 1);
    csr[pos] = (int)(pk & 0xffffu);
  }
}

// ---------------------------------------------------------------------------
// Relation conv, bf16 row gathers, fp32 accumulate, bf16 z output.
// ---------------------------------------------------------------------------
__global__ __launch_bounds__(256) void conv_kernel(
    const ush* __restrict__ xsb, const float* __restrict__ ss,
    const float* __restrict__ sd, const int* __restrict__ csr,
    const int* __restrict__ start, const int* __restrict__ count,
    ush* __restrict__ z)
{
  const int dst = blockIdx.x * 4 + (threadIdx.x >> 6);
  const int lane = threadIdx.x & 63;
  const int e0 = start[dst];
  const int ne = count[dst];

  const int h1 = lane & 7;
  const float sdv1 = sd[dst * 8 + h1];
  float den = 0.f;
  for (int j = lane >> 3; j < ne; j += 8)
    den += __expf(lrelu(ss[csr[e0 + j] * 8 + h1] + sdv1));
  den += __shfl_xor(den, 8);
  den += __shfl_xor(den, 16);
  den += __shfl_xor(den, 32);
  const int h2 = lane >> 3;
  const float inv_den = 1.f / (__shfl(den, h2) + 1e-16f);
  const float sdv2 = sd[dst * 8 + h2];

  float a0 = 0.f, a1 = 0.f, a2 = 0.f, a3 = 0.f;
  int j = 0;
  for (; j + 4 <= ne; j += 4) {
    int sA = csr[e0 + j], sB = csr[e0 + j + 1];
    int sC = csr[e0 + j + 2], sD = csr[e0 + j + 3];
    float lA = ss[sA * 8 + h2], lB = ss[sB * 8 + h2];
    float lC = ss[sC * 8 + h2], lD = ss[sD * 8 + h2];
    ushort4 vA = *(const ushort4*)&xsb[(size_t)sA * HID + lane * 4];
    ushort4 vB = *(const ushort4*)&xsb[(size_t)sB * HID + lane * 4];
    ushort4 vC = *(const ushort4*)&xsb[(size_t)sC * HID + lane * 4];
    ushort4 vD = *(const ushort4*)&xsb[(size_t)sD * HID + lane * 4];
    float alA = __expf(lrelu(lA + sdv2)) * inv_den;
    float alB = __expf(lrelu(lB + sdv2)) * inv_den;
    float alC = __expf(lrelu(lC + sdv2)) * inv_den;
    float alD = __expf(lrelu(lD + sdv2)) * inv_den;
    a0 = fmaf(alA, bf2f(vA.x), a0); a1 = fmaf(alA, bf2f(vA.y), a1);
    a2 = fmaf(alA, bf2f(vA.z), a2); a3 = fmaf(alA, bf2f(vA.w), a3);
    a0 = fmaf(alB, bf2f(vB.x), a0); a1 = fmaf(alB, bf2f(vB.y), a1);
    a2 = fmaf(alB, bf2f(vB.z), a2); a3 = fmaf(alB, bf2f(vB.w), a3);
    a0 = fmaf(alC, bf2f(vC.x), a0); a1 = fmaf(alC, bf2f(vC.y), a1);
    a2 = fmaf(alC, bf2f(vC.z), a2); a3 = fmaf(alC, bf2f(vC.w), a3);
    a0 = fmaf(alD, bf2f(vD.x), a0); a1 = fmaf(alD, bf2f(vD.y), a1);
    a2 = fmaf(alD, bf2f(vD.z), a2); a3 = fmaf(alD, bf2f(vD.w), a3);
  }
  for (; j < ne; ++j) {
    int sA = csr[e0 + j];
    float alA = __expf(lrelu(ss[sA * 8 + h2] + sdv2)) * inv_den;
    ushort4 vA = *(const ushort4*)&xsb[(size_t)sA * HID + lane * 4];
    a0 = fmaf(alA, bf2f(vA.x), a0); a1 = fmaf(alA, bf2f(vA.y), a1);
    a2 = fmaf(alA, bf2f(vA.z), a2); a3 = fmaf(alA, bf2f(vA.w), a3);
  }
  ushort4 o;
  o.x = (ush)bfr(fmaxf(a0, 0.f));
  o.y = (ush)bfr(fmaxf(a1, 0.f));
  o.z = (ush)bfr(fmaxf(a2, 0.f));
  o.w = (ush)bfr(fmaxf(a3, 0.f));
  *(ushort4*)&z[(size_t)dst * HID + lane * 4] = o;
}

// ---------------------------------------------------------------------------
// Semantic scores, register-resident MFMA. __launch_bounds__(256,4) raises
// the VGPR budget to 128 so the 64-VGPR A-fragment set stays RESIDENT
// (R6/R7: compiler targeted 8 waves/SIMD -> 48 VGPR -> A reloaded every nt
// from HBM-latency z; that chain was the whole 254us).
// ---------------------------------------------------------------------------
__global__ __launch_bounds__(256, 4) void semscore_kernel(
    const ush* __restrict__ zbu0, const ush* __restrict__ zbu1,
    const ush* __restrict__ zbi0, const ush* __restrict__ zbi1,
    const ush* __restrict__ wkT, const float* __restrict__ bk,
    const float* __restrict__ q, float* __restrict__ score)
{
  const int bid = blockIdx.x;
  const int side = bid >= SEMG;
  const ush* zA = side ? zbi0 : zbu0;
  const ush* zB = side ? zbi1 : zbu1;
  const int t = threadIdx.x;
  const int w = t >> 6;
  const int l = t & 63;
  const int lrow = l & 15;
  const int kgrp = l >> 4;
  const int rbase = (bid - side * SEMG) * 64 + w * 16;
  int arow = rbase + lrow;
  if (arow >= N) arow = N - 1;   // dup row; masked in epilogue

  bf16x8 A0[8], A1[8];
  const ush* pa0 = &zA[(size_t)arow * HID + kgrp * 8];
  const ush* pa1 = &zB[(size_t)arow * HID + kgrp * 8];
#pragma unroll
  for (int ks = 0; ks < 8; ++ks) {
    A0[ks] = *(const bf16x8*)(pa0 + ks * 32);
    A1[ks] = *(const bf16x8*)(pa1 + ks * 32);
  }

  float s0 = 0.f, s1 = 0.f;
#pragma unroll 1
  for (int nt = 0; nt < 16; ++nt) {
    const ush* pb = &wkT[(size_t)(nt * 16 + lrow) * HID + kgrp * 8];
    bf16x8 B[8];
#pragma unroll
    for (int ks = 0; ks < 8; ++ks) B[ks] = *(const bf16x8*)(pb + ks * 32);
    f32x4 acc0 = {0.f, 0.f, 0.f, 0.f};
    f32x4 acc1 = {0.f, 0.f, 0.f, 0.f};
#pragma unroll
    for (int ks = 0; ks < 8; ++ks) {
      acc0 = __builtin_amdgcn_mfma_f32_16x16x32_bf16(A0[ks], B[ks], acc0, 0, 0, 0);
      acc1 = __builtin_amdgcn_mfma_f32_16x16x32_bf16(A1[ks], B[ks], acc1, 0, 0, 0);
    }
    const int col = nt * 16 + lrow;
    const float bkv = bk[col], qv = q[col];
#pragma unroll
    for (int i = 0; i < 4; ++i) {
      int gr = rbase + kgrp * 4 + i;     // D row for this lane/reg
      if (gr < N) {
        s0 += tanh_fast(acc0[i] + bkv) * qv;
        s1 += tanh_fast(acc1[i] + bkv) * qv;
      }
    }
  }
#pragma unroll
  for (int off = 1; off < 64; off <<= 1) {
    s0 += __shfl_xor(s0, off);
    s1 += __shfl_xor(s1, off);
  }
  if (l == 0) {
    atomicAdd(&score[side * 2], s0);
    atomicAdd(&score[side * 2 + 1], s1);
  }
}

__global__ void attn2_kernel(float* __restrict__ score, float inv_n)
{
#pragma unroll
  for (int s = 0; s < 2; ++s) {
    float s0 = score[2 * s] * inv_n, s1 = score[2 * s + 1] * inv_n;
    float m = fmaxf(s0, s1);
    float e0 = __expf(s0 - m), e1 = __expf(s1 - m);
    float d = e0 + e1;
    score[4 + 2 * s] = e0 / d;
    score[5 + 2 * s] = e1 / d;
  }
}

// ---------------------------------------------------------------------------
// Final: out[n,64] = (a0*z0[n]+a1*z1[n]) @ Wl + bl, both sides one launch.
// ---------------------------------------------------------------------------
__global__ __launch_bounds__(256) void final_kernel(
    const ush* __restrict__ zbu0, const ush* __restrict__ zbu1,
    const ush* __restrict__ zbi0, const ush* __restrict__ zbi1,
    const float* __restrict__ attn, const float* __restrict__ Wl,
    const float* __restrict__ bl, float* __restrict__ out)
{
  __shared__ float zT[HID * 16];
  const int bid = blockIdx.x;
  const int side = bid >= FING;
  const ush* z0 = side ? zbi0 : zbu0;
  const ush* z1 = side ? zbi1 : zbu1;
  float* op = out + (size_t)side * N * OUTD;
  const int t = threadIdx.x;
  const int base = (bid - side * FING) * 16;
  const float a0 = attn[side * 2], a1 = attn[side * 2 + 1];
  for (int idx = t; idx < 16 * (HID / 2); idx += 256) {   // 2048 u32 pairs
    int r = idx & 15, cw = idx >> 4;
    u32 v0 = *(const u32*)&z0[(size_t)(base + r) * HID + cw * 2];
    u32 v1 = *(const u32*)&z1[(size_t)(base + r) * HID + cw * 2];
    zT[(2 * cw) * 16 + r]     = a0 * bf2f(v0 & 0xffffu) + a1 * bf2f(v1 & 0xffffu);
    zT[(2 * cw + 1) * 16 + r] = a0 * bf2f(v0 >> 16) + a1 * bf2f(v1 >> 16);
  }
  __syncthreads();
  const int ig = t >> 6;
  const int cc = t & 63;
  float acc[4] = {};
  for (int k = 0; k < HID; ++k) {
    float w = Wl[k * OUTD + cc];
    f4 xv = *(const f4*)&zT[k * 16 + ig * 4];
    acc[0] = fmaf(xv.x, w, acc[0]);
    acc[1] = fmaf(xv.y, w, acc[1]);
    acc[2] = fmaf(xv.z, w, acc[2]);
    acc[3] = fmaf(xv.w, w, acc[3]);
  }
  float bb = bl[cc];
#pragma unroll
  for (int i = 0; i < 4; ++i)
    op[(size_t)(base + ig * 4 + i) * OUTD + cc] = acc[i] + bb;
}

// ---------------------------------------------------------------------------
extern "C" void kernel_launch(void* const* d_in, const int* in_sizes, int n_in,
                              void* d_out, int out_size, void* d_ws, size_t ws_size,
                              hipStream_t stream)
{
  const float* x_user = (const float*)d_in[0];
  const float* x_item = (const float*)d_in[1];
  const int*   e_ui   = (const int*)d_in[2];
  const int*   e_iu   = (const int*)d_in[3];
  const int*   e_uu   = (const int*)d_in[4];
  const int*   e_ii   = (const int*)d_in[5];
  const float* Wp_u   = (const float*)d_in[6];
  const float* bp_u   = (const float*)d_in[7];
  const float* Wp_i   = (const float*)d_in[8];
  const float* bp_i   = (const float*)d_in[9];
  const float* as_ui  = (const float*)d_in[10];
  const float* ad_ui  = (const float*)d_in[11];
  const float* as_iu  = (const float*)d_in[12];
  const float* ad_iu  = (const float*)d_in[13];
  const float* as_uu  = (const float*)d_in[14];
  const float* ad_uu  = (const float*)d_in[15];
  const float* as_ii  = (const float*)d_in[16];
  const float* ad_ii  = (const float*)d_in[17];
  const float* Wk     = (const float*)d_in[18];
  const float* bk     = (const float*)d_in[19];
  const float* q      = (const float*)d_in[20];
  const float* Wl     = (const float*)d_in[21];
  const float* bl     = (const float*)d_in[22];

  const size_t NH = (size_t)N * HID;
  size_t need = (8 * (size_t)N8 + 8) * 4                     // su,si,sc (f32)
              + (6 * NH + (size_t)HID * HID) * 2             // 4x z, hub, hib, wkT (bf16)
              + ((size_t)8 * N + 4 * (size_t)E + 3 * NBT + 128 + 64) * 4;
  if (ws_size < need) {
    hipMemsetAsync(d_out, 0x7f, (size_t)out_size * sizeof(float), stream);
    return;
  }
  float* su = (float*)d_ws;
  float* si = su + 4 * (size_t)N8;
  float* sc = si + 4 * (size_t)N8;
  ush* zbu0 = (ush*)(sc + 8);
  ush* zbu1 = zbu0 + NH;
  ush* zbi0 = zbu1 + NH;
  ush* zbi1 = zbi0 + NH;
  ush* hub  = zbi1 + NH;
  ush* hib  = hub + NH;
  ush* wkT  = hib + NH;
  int* count  = (int*)(wkT + (size_t)HID * HID);
  int* bcnt   = count + NTOT;
  int* start  = bcnt + NBT;
  int* bstart = start + NTOT;
  int* bcur   = bstart + NBT;
  int* bsum   = bcur + NBT;
  int* csr    = bsum + 128;
  u32* bstage = (u32*)zbu0;     // aliases zbu0 (dead until first conv)

  wkt_kernel<<<HID * HID / 256, 256, 0, stream>>>(Wk, wkT);

  proj_kernel<<<N / 16, 256, 0, stream>>>(x_user, Wp_u, bp_u,
                                          ad_iu, as_uu, ad_uu, as_ui, hub, su);
  proj_kernel<<<N / 16, 256, 0, stream>>>(x_item, Wp_i, bp_i,
                                          as_iu, ad_ui, as_ii, ad_ii, hib, si);

  // batched CSR build via per-block multisplit: rel 0=iu, 1=uu, 2=ui, 3=ii
  hipMemsetAsync(bcnt, 0, NBT * sizeof(int), stream);
  histb_kernel<<<4 * NB1, 256, 0, stream>>>(e_iu + E, e_uu + E, e_ui + E, e_ii + E, bcnt);
  bscan_kernel<<<1, 256, 0, stream>>>(bcnt, bstart, bcur);
  scat2_kernel<<<4 * NB1, 256, 0, stream>>>(e_iu, e_iu + E, e_uu, e_uu + E,
                                            e_ui, e_ui + E, e_ii, e_ii + E,
                                            bcur, bstage);
  cntb_kernel<<<NBT, 256, 0, stream>>>(bstage, bstart, bcnt, count);
  scanA_kernel<<<SC_NB, SC_TPB, 0, stream>>>(count, bsum);
  scanB_kernel<<<1, 128, 0, stream>>>(bsum);
  scanC_kernel<<<SC_NB, SC_TPB, 0, stream>>>(count, bsum, start);
  fillb_kernel<<<NBT, 256, 0, stream>>>(bstage, bstart, bcnt, start, csr);

  // all 4 relation convs
  conv_kernel<<<N / 4, 256, 0, stream>>>(hib, si, su, csr, start, count, zbu0);
  conv_kernel<<<N / 4, 256, 0, stream>>>(hub, su + N8, su + 2 * (size_t)N8, csr,
                                         start + N, count + N, zbu1);
  conv_kernel<<<N / 4, 256, 0, stream>>>(hub, su + 3 * (size_t)N8, si + N8, csr,
                                         start + 2 * N, count + 2 * N, zbi0);
  conv_kernel<<<N / 4, 256, 0, stream>>>(hib, si + 2 * (size_t)N8, si + 3 * (size_t)N8, csr,
                                         start + 3 * N, count + 3 * N, zbi1);

  // semantic attention: both sides in one launch
  hipMemsetAsync(sc, 0, 4 * sizeof(float), stream);
  semscore_kernel<<<2 * SEMG, 256, 0, stream>>>(zbu0, zbu1, zbi0, zbi1, wkT, bk, q, sc);
  attn2_kernel<<<1, 1, 0, stream>>>(sc, 1.0f / (float)N);

  // final linear: both sides in one launch
  final_kernel<<<2 * FING, 256, 0, stream>>>(zbu0, zbu1, zbi0, zbi1, sc + 4, Wl, bl,
                                             (float*)d_out);
}

// Round 9
// 873.110 us; speedup vs baseline: 2.2954x; 1.0646x over previous
//
#include <hip/hip_runtime.h>
#include <math.h>

#define N     50000
#define F_IN  128
#define HID   256
#define E     800000
#define OUTD  64
#define NEG   0.2f
#define N8    (N * 8)
#define NTOT  (4 * N)
#define FING  (N / 16)               // 3125

// semscore GEMM geometry (m97 structure)
#define SMT    ((N + 127) / 128)     // 391 M-tiles
#define SEMBLK (SMT * 2)             // blocks per matrix (2 N-tiles)

// hierarchical scan geometry
#define SC_TPB   256
#define SC_PERB  2048
#define SC_NB    ((NTOT + SC_PERB - 1) / SC_PERB)   // 98

// bucket sort geometry
#define BSH   7                      // bucket = dst >> 7 (128 dsts/bucket)
#define NBUK  ((N + 127) / 128)      // 391
#define NBT   (4 * NBUK)             // 1564
#define EPB1  8192
#define NB1   ((E + EPB1 - 1) / EPB1) // 98

typedef float4 f4;
typedef unsigned int u32;
typedef unsigned short ush;
typedef float f32x4 __attribute__((ext_vector_type(4)));
typedef short bf16x8 __attribute__((ext_vector_type(8)));

static __device__ __forceinline__ float lrelu(float x) { return x >= 0.f ? x : NEG * x; }
static __device__ __forceinline__ u32 bfr(float x) {
  u32 u = __float_as_uint(x);
  return (u + 0x7fffu + ((u >> 16) & 1u)) >> 16;
}
static __device__ __forceinline__ float bf2f(u32 us) { return __uint_as_float(us << 16); }
// tanh(x) = 1 - 2/(exp(2x)+1)
static __device__ __forceinline__ float tanh_fast(float x) {
  float e = __expf(2.f * x);
  return fmaf(-2.f, __builtin_amdgcn_rcpf(e + 1.f), 1.f);
}

// async global->LDS, 16B per lane; LDS dest = ldsbase + lane*16 (wave-uniform base)
typedef const __attribute__((address_space(1))) unsigned int gu32;
typedef __attribute__((address_space(3))) unsigned int lu32;
static __device__ __forceinline__ void gll16(const void* g, void* l) {
  __builtin_amdgcn_global_load_lds((gu32*)g, (lu32*)l, 16, 0, 0);
}

// ---------------------------------------------------------------------------
// Projection + fused per-node attention scores.
// ---------------------------------------------------------------------------
__global__ __launch_bounds__(256) void proj_kernel(
    const float* __restrict__ x, const float* __restrict__ W, const float* __restrict__ b,
    const float* __restrict__ a0, const float* __restrict__ a1,
    const float* __restrict__ a2, const float* __restrict__ a3,
    ush* __restrict__ hb, float* __restrict__ sdst)
{
  __shared__ float xT[F_IN * 16];   // [k][i]
  const int t = threadIdx.x;
  const int base = blockIdx.x * 16;
  for (int idx = t; idx < 16 * F_IN; idx += 256) {
    int r = idx & 15, c = idx >> 4;
    xT[c * 16 + r] = x[(size_t)(base + r) * F_IN + c];
  }
  __syncthreads();
  const int ig = t >> 6;
  const int lane = t & 63;
  const int j0 = lane * 4;
  float acc[4][4] = {};
  for (int k = 0; k < F_IN; ++k) {
    f4 w  = *(const f4*)&W[k * HID + j0];
    f4 xv = *(const f4*)&xT[k * 16 + ig * 4];
    const float wa[4] = {w.x, w.y, w.z, w.w};
    const float xa[4] = {xv.x, xv.y, xv.z, xv.w};
#pragma unroll
    for (int i = 0; i < 4; ++i)
#pragma unroll
      for (int j = 0; j < 4; ++j) acc[i][j] = fmaf(xa[i], wa[j], acc[i][j]);
  }
  f4 bv = *(const f4*)&b[j0];
  const float ba[4] = {bv.x, bv.y, bv.z, bv.w};
#pragma unroll
  for (int i = 0; i < 4; ++i) {
#pragma unroll
    for (int j = 0; j < 4; ++j) acc[i][j] += ba[j];
    ushort4 o;
    o.x = (ush)bfr(acc[i][0]); o.y = (ush)bfr(acc[i][1]);
    o.z = (ush)bfr(acc[i][2]); o.w = (ush)bfr(acc[i][3]);
    *(ushort4*)&hb[(size_t)(base + ig * 4 + i) * HID + j0] = o;
  }
  const int head = lane >> 3;
  const float* av[4] = {a0, a1, a2, a3};
#pragma unroll
  for (int k = 0; k < 4; ++k) {
    f4 a = *(const f4*)&av[k][j0];
#pragma unroll
    for (int i = 0; i < 4; ++i) {
      float p = acc[i][0] * a.x + acc[i][1] * a.y + acc[i][2] * a.z + acc[i][3] * a.w;
      p += __shfl_xor(p, 1);
      p += __shfl_xor(p, 2);
      p += __shfl_xor(p, 4);
      if ((lane & 7) == 0)
        sdst[(size_t)k * N8 + (size_t)(base + ig * 4 + i) * 8 + head] = p;
    }
  }
}

// ---------------------------------------------------------------------------
__global__ void wkt_kernel(const float* __restrict__ Wk, ush* __restrict__ wkT)
{
  int idx = blockIdx.x * 256 + threadIdx.x;
  int n = idx >> 8, k = idx & 255;
  wkT[idx] = (ush)bfr(Wk[k * HID + n]);
}

// ---------------------------------------------------------------------------
// CSR build, per-block multisplit (unchanged — off the critical list)
// ---------------------------------------------------------------------------
__global__ __launch_bounds__(256) void histb_kernel(
    const int* __restrict__ d0, const int* __restrict__ d1,
    const int* __restrict__ d2, const int* __restrict__ d3,
    int* __restrict__ bcnt)
{
  __shared__ int lh[NBUK];
  const int rel = blockIdx.x / NB1;
  const int blk = blockIdx.x % NB1;
  for (int j = threadIdx.x; j < NBUK; j += 256) lh[j] = 0;
  __syncthreads();
  const int* dp = rel == 0 ? d0 : rel == 1 ? d1 : rel == 2 ? d2 : d3;
  const int base = blk * EPB1;
#pragma unroll 4
  for (int k = 0; k < EPB1 / 256; ++k) {
    int i = base + k * 256 + threadIdx.x;
    if (i < E) atomicAdd(&lh[dp[i] >> BSH], 1);
  }
  __syncthreads();
  for (int j = threadIdx.x; j < NBUK; j += 256)
    if (lh[j]) atomicAdd(&bcnt[rel * NBUK + j], lh[j]);
}

__global__ __launch_bounds__(256) void bscan_kernel(
    const int* __restrict__ bcnt, int* __restrict__ bstart, int* __restrict__ bcur)
{
  __shared__ int part[256];
  const int t = threadIdx.x;
  const int chunk = (NBT + 255) / 256;   // 7
  const int b = t * chunk;
  const int e = min(NBT, b + chunk);
  int s = 0;
  for (int i = b; i < e; ++i) s += bcnt[i];
  part[t] = s;
  __syncthreads();
  for (int off = 1; off < 256; off <<= 1) {
    int u = (t >= off) ? part[t - off] : 0;
    __syncthreads();
    part[t] += u;
    __syncthreads();
  }
  int run = part[t] - s;
  for (int i = b; i < e; ++i) {
    bstart[i] = run;
    bcur[i] = run;
    run += bcnt[i];
  }
}

__global__ __launch_bounds__(256) void scat2_kernel(
    const int* __restrict__ s0, const int* __restrict__ d0,
    const int* __restrict__ s1, const int* __restrict__ d1,
    const int* __restrict__ s2, const int* __restrict__ d2,
    const int* __restrict__ s3, const int* __restrict__ d3,
    int* __restrict__ bcur, u32* __restrict__ bstage)
{
  __shared__ int lh[NBUK];
  const int rel = blockIdx.x / NB1;
  const int blk = blockIdx.x % NB1;
  const int* sp = rel == 0 ? s0 : rel == 1 ? s1 : rel == 2 ? s2 : s3;
  const int* dp = rel == 0 ? d0 : rel == 1 ? d1 : rel == 2 ? d2 : d3;
  for (int j = threadIdx.x; j < NBUK; j += 256) lh[j] = 0;
  __syncthreads();
  const int base = blk * EPB1;
#pragma unroll 4
  for (int k = 0; k < EPB1 / 256; ++k) {
    int i = base + k * 256 + threadIdx.x;
    if (i < E) atomicAdd(&lh[dp[i] >> BSH], 1);
  }
  __syncthreads();
  for (int j = threadIdx.x; j < NBUK; j += 256) {
    int c = lh[j];
    lh[j] = c ? atomicAdd(&bcur[rel * NBUK + j], c) : 0;
  }
  __syncthreads();
#pragma unroll 4
  for (int k = 0; k < EPB1 / 256; ++k) {
    int i = base + k * 256 + threadIdx.x;
    if (i < E) {
      int dst = dp[i], src = sp[i];
      int pos = atomicAdd(&lh[dst >> BSH], 1);   // LDS atomic (fast)
      bstage[pos] = ((u32)dst << 16) | (u32)src;
    }
  }
}

__global__ __launch_bounds__(256) void cntb_kernel(
    const u32* __restrict__ bstage, const int* __restrict__ bstart,
    const int* __restrict__ bcnt, int* __restrict__ count)
{
  __shared__ int lcnt[128];
  const int bb = blockIdx.x;
  const int rel = bb / NBUK, b = bb % NBUK;
  if (threadIdx.x < 128) lcnt[threadIdx.x] = 0;
  __syncthreads();
  const int rb = bstart[bb];
  const int cnt = bcnt[bb];
  for (int k = threadIdx.x; k < cnt; k += 256)
    atomicAdd(&lcnt[(bstage[rb + k] >> 16) & 127], 1);
  __syncthreads();
  const int fb = rel * N + b * 128;
  const int lim = min(128, N - b * 128);
  if (threadIdx.x < lim) count[fb + threadIdx.x] = lcnt[threadIdx.x];
}

__global__ __launch_bounds__(SC_TPB) void scanA_kernel(
    const int* __restrict__ count, int* __restrict__ bsum)
{
  __shared__ int red[4];
  const int t = threadIdx.x;
  const int base = blockIdx.x * SC_PERB + t * 8;
  int s = 0;
  if (base + 8 <= NTOT) {
    int4 a = *(const int4*)&count[base];
    int4 b = *(const int4*)&count[base + 4];
    s = a.x + a.y + a.z + a.w + b.x + b.y + b.z + b.w;
  } else {
    for (int i = 0; i < 8; ++i) { int idx = base + i; if (idx < NTOT) s += count[idx]; }
  }
#pragma unroll
  for (int off = 1; off < 64; off <<= 1) s += __shfl_xor(s, off);
  if ((t & 63) == 0) red[t >> 6] = s;
  __syncthreads();
  if (t == 0) bsum[blockIdx.x] = red[0] + red[1] + red[2] + red[3];
}

__global__ __launch_bounds__(128) void scanB_kernel(int* __restrict__ bsum)
{
  __shared__ int tmp[128];
  const int t = threadIdx.x;
  int v = (t < SC_NB) ? bsum[t] : 0;
  tmp[t] = v;
  __syncthreads();
  for (int off = 1; off < 128; off <<= 1) {
    int u = (t >= off) ? tmp[t - off] : 0;
    __syncthreads();
    tmp[t] += u;
    __syncthreads();
  }
  if (t < SC_NB) bsum[t] = tmp[t] - v;  // exclusive
}

__global__ __launch_bounds__(SC_TPB) void scanC_kernel(
    const int* __restrict__ count, const int* __restrict__ bsum,
    int* __restrict__ start)
{
  __shared__ int ts[SC_TPB];
  const int t = threadIdx.x;
  const int base = blockIdx.x * SC_PERB + t * 8;
  int c[8];
  int s = 0;
#pragma unroll
  for (int i = 0; i < 8; ++i) {
    int idx = base + i;
    c[i] = (idx < NTOT) ? count[idx] : 0;
    s += c[i];
  }
  ts[t] = s;
  __syncthreads();
  for (int off = 1; off < SC_TPB; off <<= 1) {
    int u = (t >= off) ? ts[t - off] : 0;
    __syncthreads();
    ts[t] += u;
    __syncthreads();
  }
  int run = ts[t] - s + bsum[blockIdx.x];
#pragma unroll
  for (int i = 0; i < 8; ++i) {
    int idx = base + i;
    if (idx < NTOT) {
      start[idx] = run;
      run += c[i];
    }
  }
}

__global__ __launch_bounds__(256) void fillb_kernel(
    const u32* __restrict__ bstage, const int* __restrict__ bstart,
    const int* __restrict__ bcnt, const int* __restrict__ start,
    int* __restrict__ csr)
{
  __shared__ int lcur[128];
  const int bb = blockIdx.x;           // rel*NBUK + b
  const int rel = bb / NBUK, b = bb % NBUK;
  const int fb = rel * N + b * 128;
  const int lim = min(128, N - b * 128);
  if (threadIdx.x < lim) lcur[threadIdx.x] = start[fb + threadIdx.x];
  __syncthreads();
  const int rb = bstart[bb];
  const int cnt = bcnt[bb];
  for (int k = threadIdx.x; k < cnt; k += 256) {
    u32 pk = bstage[rb + k];
    int ldst = (pk >> 16) & 127;
    int pos = atomicAdd(&lcur[ldst], 1);
    csr[pos] = (int)(pk & 0xffffu);
  }
}

// ---------------------------------------------------------------------------
// Relation conv, bf16 row gathers, fp32 accumulate, bf16 z output.
// ---------------------------------------------------------------------------
__global__ __launch_bounds__(256) void conv_kernel(
    const ush* __restrict__ xsb, const float* __restrict__ ss,
    const float* __restrict__ sd, const int* __restrict__ csr,
    const int* __restrict__ start, const int* __restrict__ count,
    ush* __restrict__ z)
{
  const int dst = blockIdx.x * 4 + (threadIdx.x >> 6);
  const int lane = threadIdx.x & 63;
  const int e0 = start[dst];
  const int ne = count[dst];

  const int h1 = lane & 7;
  const float sdv1 = sd[dst * 8 + h1];
  float den = 0.f;
  for (int j = lane >> 3; j < ne; j += 8)
    den += __expf(lrelu(ss[csr[e0 + j] * 8 + h1] + sdv1));
  den += __shfl_xor(den, 8);
  den += __shfl_xor(den, 16);
  den += __shfl_xor(den, 32);
  const int h2 = lane >> 3;
  const float inv_den = 1.f / (__shfl(den, h2) + 1e-16f);
  const float sdv2 = sd[dst * 8 + h2];

  float a0 = 0.f, a1 = 0.f, a2 = 0.f, a3 = 0.f;
  int j = 0;
  for (; j + 4 <= ne; j += 4) {
    int sA = csr[e0 + j], sB = csr[e0 + j + 1];
    int sC = csr[e0 + j + 2], sD = csr[e0 + j + 3];
    float lA = ss[sA * 8 + h2], lB = ss[sB * 8 + h2];
    float lC = ss[sC * 8 + h2], lD = ss[sD * 8 + h2];
    ushort4 vA = *(const ushort4*)&xsb[(size_t)sA * HID + lane * 4];
    ushort4 vB = *(const ushort4*)&xsb[(size_t)sB * HID + lane * 4];
    ushort4 vC = *(const ushort4*)&xsb[(size_t)sC * HID + lane * 4];
    ushort4 vD = *(const ushort4*)&xsb[(size_t)sD * HID + lane * 4];
    float alA = __expf(lrelu(lA + sdv2)) * inv_den;
    float alB = __expf(lrelu(lB + sdv2)) * inv_den;
    float alC = __expf(lrelu(lC + sdv2)) * inv_den;
    float alD = __expf(lrelu(lD + sdv2)) * inv_den;
    a0 = fmaf(alA, bf2f(vA.x), a0); a1 = fmaf(alA, bf2f(vA.y), a1);
    a2 = fmaf(alA, bf2f(vA.z), a2); a3 = fmaf(alA, bf2f(vA.w), a3);
    a0 = fmaf(alB, bf2f(vB.x), a0); a1 = fmaf(alB, bf2f(vB.y), a1);
    a2 = fmaf(alB, bf2f(vB.z), a2); a3 = fmaf(alB, bf2f(vB.w), a3);
    a0 = fmaf(alC, bf2f(vC.x), a0); a1 = fmaf(alC, bf2f(vC.y), a1);
    a2 = fmaf(alC, bf2f(vC.z), a2); a3 = fmaf(alC, bf2f(vC.w), a3);
    a0 = fmaf(alD, bf2f(vD.x), a0); a1 = fmaf(alD, bf2f(vD.y), a1);
    a2 = fmaf(alD, bf2f(vD.z), a2); a3 = fmaf(alD, bf2f(vD.w), a3);
  }
  for (; j < ne; ++j) {
    int sA = csr[e0 + j];
    float alA = __expf(lrelu(ss[sA * 8 + h2] + sdv2)) * inv_den;
    ushort4 vA = *(const ushort4*)&xsb[(size_t)sA * HID + lane * 4];
    a0 = fmaf(alA, bf2f(vA.x), a0); a1 = fmaf(alA, bf2f(vA.y), a1);
    a2 = fmaf(alA, bf2f(vA.z), a2); a3 = fmaf(alA, bf2f(vA.w), a3);
  }
  ushort4 o;
  o.x = (ush)bfr(fmaxf(a0, 0.f));
  o.y = (ush)bfr(fmaxf(a1, 0.f));
  o.z = (ush)bfr(fmaxf(a2, 0.f));
  o.w = (ush)bfr(fmaxf(a3, 0.f));
  *(ushort4*)&z[(size_t)dst * HID + lane * 4] = o;
}

// ---------------------------------------------------------------------------
// Semantic scores as an m97-structure GEMM (128x128 tile, BK=64, dbuf LDS via
// global_load_lds w=16, XOR-swizzled source+read) with fused tanh*q epilogue.
// R6-R8 register-streaming versions were load-serialized (VGPR 48 -> 1 load
// in flight, ~800cyc each -> 257us). This uses async staging for MLP.
// Grid: 4 matrices x 391 M-tiles x 2 N-tiles = 3128 blocks.
// ---------------------------------------------------------------------------
__global__ __launch_bounds__(256, 2) void semscore_kernel(
    const ush* __restrict__ zbu0, const ush* __restrict__ zbu1,
    const ush* __restrict__ zbi0, const ush* __restrict__ zbi1,
    const ush* __restrict__ wkT, const float* __restrict__ bk,
    const float* __restrict__ q, float* __restrict__ score)
{
  __shared__ ush Als[2][128 * 64];   // 32 KB: [buf][row*64 + col], swizzled 16B chunks
  __shared__ ush Bls[2][128 * 64];   // 32 KB
  const int bid = blockIdx.x;
  const int mat = bid / SEMBLK;
  const int rem = bid % SEMBLK;
  const int mt = rem >> 1, ntile = rem & 1;
  const ush* zsrc = mat == 0 ? zbu0 : mat == 1 ? zbu1 : mat == 2 ? zbi0 : zbi1;
  const int Mbase = mt * 128, Nbase = ntile * 128;
  const int t = threadIdx.x;
  const int w = t >> 6, l = t & 63;
  const int lrow = l & 15, kgrp = l >> 4;
  const int wr = w >> 1, wc = w & 1;

  f32x4 acc[4][4];
  const f32x4 zz = {0.f, 0.f, 0.f, 0.f};
#pragma unroll
  for (int m = 0; m < 4; ++m)
#pragma unroll
    for (int n = 0; n < 4; ++n) acc[m][n] = zz;

  // stage K-step kc into buffer buf: 1024 16B-chunks each for A and B.
  // LDS chunk q holds global row r=q>>3, col-chunk c=(q&7)^(r&7) (st-swizzle).
  auto stage = [&](int buf, int kc) {
#pragma unroll
    for (int i = 0; i < 4; ++i) {
      int q16 = i * 256 + t;
      int r = q16 >> 3;
      int c = (q16 & 7) ^ (r & 7);
      int gr = Mbase + r; if (gr >= N) gr = N - 1;
      gll16(&zsrc[(size_t)gr * HID + kc * 64 + c * 8],
            &Als[buf][(i * 256 + w * 64) * 8]);
      gll16(&wkT[(size_t)(Nbase + r) * HID + kc * 64 + c * 8],
            &Bls[buf][(i * 256 + w * 64) * 8]);
    }
  };

  auto compute = [&](int buf) {
#pragma unroll
    for (int m = 0; m < 4; ++m) {
      const int mrow = wr * 64 + m * 16 + lrow;
      bf16x8 Af[2];
#pragma unroll
      for (int ks = 0; ks < 2; ++ks) {
        int ch = (ks * 4 + kgrp) ^ (mrow & 7);
        Af[ks] = *(const bf16x8*)&Als[buf][mrow * 64 + ch * 8];
      }
#pragma unroll
      for (int n = 0; n < 4; ++n) {
        const int nrow = wc * 64 + n * 16 + lrow;
#pragma unroll
        for (int ks = 0; ks < 2; ++ks) {
          int ch = (ks * 4 + kgrp) ^ (nrow & 7);
          bf16x8 Bf = *(const bf16x8*)&Bls[buf][nrow * 64 + ch * 8];
          acc[m][n] = __builtin_amdgcn_mfma_f32_16x16x32_bf16(Af[ks], Bf, acc[m][n], 0, 0, 0);
        }
      }
    }
  };

  stage(0, 0);
  __syncthreads();          // drains vmcnt -> buf0 ready
  int cur = 0;
#pragma unroll
  for (int kc = 0; kc < 4; ++kc) {
    if (kc < 3) stage(cur ^ 1, kc + 1);
    compute(cur);
    __syncthreads();        // staged buf ready + all reads of cur done
    cur ^= 1;
  }

  // epilogue: D row = Mbase + wr*64 + m*16 + kgrp*4 + i, col = Nbase + wc*64 + n*16 + lrow
  float s = 0.f;
#pragma unroll
  for (int m = 0; m < 4; ++m) {
    const int gr0 = Mbase + wr * 64 + m * 16 + kgrp * 4;
#pragma unroll
    for (int n = 0; n < 4; ++n) {
      const int col = Nbase + wc * 64 + n * 16 + lrow;
      const float bkv = bk[col], qv = q[col];
#pragma unroll
      for (int i = 0; i < 4; ++i)
        if (gr0 + i < N) s += tanh_fast(acc[m][n][i] + bkv) * qv;
    }
  }
#pragma unroll
  for (int off = 1; off < 64; off <<= 1) s += __shfl_xor(s, off);
  if (l == 0) atomicAdd(&score[mat], s);
}

__global__ void attn2_kernel(float* __restrict__ score, float inv_n)
{
#pragma unroll
  for (int s = 0; s < 2; ++s) {
    float s0 = score[2 * s] * inv_n, s1 = score[2 * s + 1] * inv_n;
    float m = fmaxf(s0, s1);
    float e0 = __expf(s0 - m), e1 = __expf(s1 - m);
    float d = e0 + e1;
    score[4 + 2 * s] = e0 / d;
    score[5 + 2 * s] = e1 / d;
  }
}

// ---------------------------------------------------------------------------
// Final: out[n,64] = (a0*z0[n]+a1*z1[n]) @ Wl + bl, both sides one launch.
// ---------------------------------------------------------------------------
__global__ __launch_bounds__(256) void final_kernel(
    const ush* __restrict__ zbu0, const ush* __restrict__ zbu1,
    const ush* __restrict__ zbi0, const ush* __restrict__ zbi1,
    const float* __restrict__ attn, const float* __restrict__ Wl,
    const float* __restrict__ bl, float* __restrict__ out)
{
  __shared__ float zT[HID * 16];
  const int bid = blockIdx.x;
  const int side = bid >= FING;
  const ush* z0 = side ? zbi0 : zbu0;
  const ush* z1 = side ? zbi1 : zbu1;
  float* op = out + (size_t)side * N * OUTD;
  const int t = threadIdx.x;
  const int base = (bid - side * FING) * 16;
  const float a0 = attn[side * 2], a1 = attn[side * 2 + 1];
  for (int idx = t; idx < 16 * (HID / 2); idx += 256) {   // 2048 u32 pairs
    int r = idx & 15, cw = idx >> 4;
    u32 v0 = *(const u32*)&z0[(size_t)(base + r) * HID + cw * 2];
    u32 v1 = *(const u32*)&z1[(size_t)(base + r) * HID + cw * 2];
    zT[(2 * cw) * 16 + r]     = a0 * bf2f(v0 & 0xffffu) + a1 * bf2f(v1 & 0xffffu);
    zT[(2 * cw + 1) * 16 + r] = a0 * bf2f(v0 >> 16) + a1 * bf2f(v1 >> 16);
  }
  __syncthreads();
  const int ig = t >> 6;
  const int cc = t & 63;
  float acc[4] = {};
  for (int k = 0; k < HID; ++k) {
    float w = Wl[k * OUTD + cc];
    f4 xv = *(const f4*)&zT[k * 16 + ig * 4];
    acc[0] = fmaf(xv.x, w, acc[0]);
    acc[1] = fmaf(xv.y, w, acc[1]);
    acc[2] = fmaf(xv.z, w, acc[2]);
    acc[3] = fmaf(xv.w, w, acc[3]);
  }
  float bb = bl[cc];
#pragma unroll
  for (int i = 0; i < 4; ++i)
    op[(size_t)(base + ig * 4 + i) * OUTD + cc] = acc[i] + bb;
}

// ---------------------------------------------------------------------------
extern "C" void kernel_launch(void* const* d_in, const int* in_sizes, int n_in,
                              void* d_out, int out_size, void* d_ws, size_t ws_size,
                              hipStream_t stream)
{
  const float* x_user = (const float*)d_in[0];
  const float* x_item = (const float*)d_in[1];
  const int*   e_ui   = (const int*)d_in[2];
  const int*   e_iu   = (const int*)d_in[3];
  const int*   e_uu   = (const int*)d_in[4];
  const int*   e_ii   = (const int*)d_in[5];
  const float* Wp_u   = (const float*)d_in[6];
  const float* bp_u   = (const float*)d_in[7];
  const float* Wp_i   = (const float*)d_in[8];
  const float* bp_i   = (const float*)d_in[9];
  const float* as_ui  = (const float*)d_in[10];
  const float* ad_ui  = (const float*)d_in[11];
  const float* as_iu  = (const float*)d_in[12];
  const float* ad_iu  = (const float*)d_in[13];
  const float* as_uu  = (const float*)d_in[14];
  const float* ad_uu  = (const float*)d_in[15];
  const float* as_ii  = (const float*)d_in[16];
  const float* ad_ii  = (const float*)d_in[17];
  const float* Wk     = (const float*)d_in[18];
  const float* bk     = (const float*)d_in[19];
  const float* q      = (const float*)d_in[20];
  const float* Wl     = (const float*)d_in[21];
  const float* bl     = (const float*)d_in[22];

  const size_t NH = (size_t)N * HID;
  size_t need = (8 * (size_t)N8 + 8) * 4                     // su,si,sc (f32)
              + (6 * NH + (size_t)HID * HID) * 2             // 4x z, hub, hib, wkT (bf16)
              + ((size_t)8 * N + 4 * (size_t)E + 3 * NBT + 128 + 64) * 4;
  if (ws_size < need) {
    hipMemsetAsync(d_out, 0x7f, (size_t)out_size * sizeof(float), stream);
    return;
  }
  float* su = (float*)d_ws;
  float* si = su + 4 * (size_t)N8;
  float* sc = si + 4 * (size_t)N8;
  ush* zbu0 = (ush*)(sc + 8);
  ush* zbu1 = zbu0 + NH;
  ush* zbi0 = zbu1 + NH;
  ush* zbi1 = zbi0 + NH;
  ush* hub  = zbi1 + NH;
  ush* hib  = hub + NH;
  ush* wkT  = hib + NH;
  int* count  = (int*)(wkT + (size_t)HID * HID);
  int* bcnt   = count + NTOT;
  int* start  = bcnt + NBT;
  int* bstart = start + NTOT;
  int* bcur   = bstart + NBT;
  int* bsum   = bcur + NBT;
  int* csr    = bsum + 128;
  u32* bstage = (u32*)zbu0;     // aliases zbu0 (dead until first conv)

  wkt_kernel<<<HID * HID / 256, 256, 0, stream>>>(Wk, wkT);

  proj_kernel<<<N / 16, 256, 0, stream>>>(x_user, Wp_u, bp_u,
                                          ad_iu, as_uu, ad_uu, as_ui, hub, su);
  proj_kernel<<<N / 16, 256, 0, stream>>>(x_item, Wp_i, bp_i,
                                          as_iu, ad_ui, as_ii, ad_ii, hib, si);

  // batched CSR build via per-block multisplit: rel 0=iu, 1=uu, 2=ui, 3=ii
  hipMemsetAsync(bcnt, 0, NBT * sizeof(int), stream);
  histb_kernel<<<4 * NB1, 256, 0, stream>>>(e_iu + E, e_uu + E, e_ui + E, e_ii + E, bcnt);
  bscan_kernel<<<1, 256, 0, stream>>>(bcnt, bstart, bcur);
  scat2_kernel<<<4 * NB1, 256, 0, stream>>>(e_iu, e_iu + E, e_uu, e_uu + E,
                                            e_ui, e_ui + E, e_ii, e_ii + E,
                                            bcur, bstage);
  cntb_kernel<<<NBT, 256, 0, stream>>>(bstage, bstart, bcnt, count);
  scanA_kernel<<<SC_NB, SC_TPB, 0, stream>>>(count, bsum);
  scanB_kernel<<<1, 128, 0, stream>>>(bsum);
  scanC_kernel<<<SC_NB, SC_TPB, 0, stream>>>(count, bsum, start);
  fillb_kernel<<<NBT, 256, 0, stream>>>(bstage, bstart, bcnt, start, csr);

  // all 4 relation convs
  conv_kernel<<<N / 4, 256, 0, stream>>>(hib, si, su, csr, start, count, zbu0);
  conv_kernel<<<N / 4, 256, 0, stream>>>(hub, su + N8, su + 2 * (size_t)N8, csr,
                                         start + N, count + N, zbu1);
  conv_kernel<<<N / 4, 256, 0, stream>>>(hub, su + 3 * (size_t)N8, si + N8, csr,
                                         start + 2 * N, count + 2 * N, zbi0);
  conv_kernel<<<N / 4, 256, 0, stream>>>(hib, si + 2 * (size_t)N8, si + 3 * (size_t)N8, csr,
                                         start + 3 * N, count + 3 * N, zbi1);

  // semantic attention: all 4 matrices in one GEMM-structured launch
  hipMemsetAsync(sc, 0, 4 * sizeof(float), stream);
  semscore_kernel<<<4 * SEMBLK, 256, 0, stream>>>(zbu0, zbu1, zbi0, zbi1, wkT, bk, q, sc);
  attn2_kernel<<<1, 1, 0, stream>>>(sc, 1.0f / (float)N);

  // final linear: both sides in one launch
  final_kernel<<<2 * FING, 256, 0, stream>>>(zbu0, zbu1, zbi0, zbi1, sc + 4, Wl, bl,
                                             (float*)d_out);
}

// Round 10
// 868.335 us; speedup vs baseline: 2.3080x; 1.0055x over previous
//
#include <hip/hip_runtime.h>
#include <math.h>

#define N     50000
#define F_IN  128
#define HID   256
#define E     800000
#define OUTD  64
#define NEG   0.2f
#define N8    (N * 8)
#define NTOT  (4 * N)
#define FING  (N / 16)               // 3125
#define SMT   ((N + 127) / 128)      // 391 M-tiles per matrix

// hierarchical scan geometry
#define SC_TPB   256
#define SC_PERB  2048
#define SC_NB    ((NTOT + SC_PERB - 1) / SC_PERB)   // 98

// bucket sort geometry
#define BSH   7                      // bucket = dst >> 7 (128 dsts/bucket)
#define NBUK  ((N + 127) / 128)      // 391
#define NBT   (4 * NBUK)             // 1564
#define EPB1  8192
#define NB1   ((E + EPB1 - 1) / EPB1) // 98

typedef float4 f4;
typedef unsigned int u32;
typedef unsigned short ush;
typedef float f32x4 __attribute__((ext_vector_type(4)));
typedef short bf16x8 __attribute__((ext_vector_type(8)));

static __device__ __forceinline__ float lrelu(float x) { return x >= 0.f ? x : NEG * x; }
static __device__ __forceinline__ u32 bfr(float x) {
  u32 u = __float_as_uint(x);
  return (u + 0x7fffu + ((u >> 16) & 1u)) >> 16;
}
static __device__ __forceinline__ float bf2f(u32 us) { return __uint_as_float(us << 16); }
// tanh(x) = 1 - 2/(exp(2x)+1)
static __device__ __forceinline__ float tanh_fast(float x) {
  float e = __expf(2.f * x);
  return fmaf(-2.f, __builtin_amdgcn_rcpf(e + 1.f), 1.f);
}

// async global->LDS, 16B per lane; LDS dest = wave-uniform base + lane*16
typedef const __attribute__((address_space(1))) unsigned int gu32;
typedef __attribute__((address_space(3))) unsigned int lu32;
static __device__ __forceinline__ void gll16(const void* g, void* l) {
  __builtin_amdgcn_global_load_lds((gu32*)g, (lu32*)l, 16, 0, 0);
}

// counted-vmcnt barrier: wait own wave's oldest staging loads, then sync.
// memory-clobber asms pin LDS reads on the correct side of the barrier.
#define WAITK(nstr)                                          \
  asm volatile("s_waitcnt vmcnt(" nstr ")" ::: "memory");    \
  __builtin_amdgcn_s_barrier();                              \
  asm volatile("" ::: "memory");

// ---------------------------------------------------------------------------
// Projection + fused per-node attention scores.
// ---------------------------------------------------------------------------
__global__ __launch_bounds__(256) void proj_kernel(
    const float* __restrict__ x, const float* __restrict__ W, const float* __restrict__ b,
    const float* __restrict__ a0, const float* __restrict__ a1,
    const float* __restrict__ a2, const float* __restrict__ a3,
    ush* __restrict__ hb, float* __restrict__ sdst)
{
  __shared__ float xT[F_IN * 16];   // [k][i]
  const int t = threadIdx.x;
  const int base = blockIdx.x * 16;
  for (int idx = t; idx < 16 * F_IN; idx += 256) {
    int r = idx & 15, c = idx >> 4;
    xT[c * 16 + r] = x[(size_t)(base + r) * F_IN + c];
  }
  __syncthreads();
  const int ig = t >> 6;
  const int lane = t & 63;
  const int j0 = lane * 4;
  float acc[4][4] = {};
  for (int k = 0; k < F_IN; ++k) {
    f4 w  = *(const f4*)&W[k * HID + j0];
    f4 xv = *(const f4*)&xT[k * 16 + ig * 4];
    const float wa[4] = {w.x, w.y, w.z, w.w};
    const float xa[4] = {xv.x, xv.y, xv.z, xv.w};
#pragma unroll
    for (int i = 0; i < 4; ++i)
#pragma unroll
      for (int j = 0; j < 4; ++j) acc[i][j] = fmaf(xa[i], wa[j], acc[i][j]);
  }
  f4 bv = *(const f4*)&b[j0];
  const float ba[4] = {bv.x, bv.y, bv.z, bv.w};
#pragma unroll
  for (int i = 0; i < 4; ++i) {
#pragma unroll
    for (int j = 0; j < 4; ++j) acc[i][j] += ba[j];
    ushort4 o;
    o.x = (ush)bfr(acc[i][0]); o.y = (ush)bfr(acc[i][1]);
    o.z = (ush)bfr(acc[i][2]); o.w = (ush)bfr(acc[i][3]);
    *(ushort4*)&hb[(size_t)(base + ig * 4 + i) * HID + j0] = o;
  }
  const int head = lane >> 3;
  const float* av[4] = {a0, a1, a2, a3};
#pragma unroll
  for (int k = 0; k < 4; ++k) {
    f4 a = *(const f4*)&av[k][j0];
#pragma unroll
    for (int i = 0; i < 4; ++i) {
      float p = acc[i][0] * a.x + acc[i][1] * a.y + acc[i][2] * a.z + acc[i][3] * a.w;
      p += __shfl_xor(p, 1);
      p += __shfl_xor(p, 2);
      p += __shfl_xor(p, 4);
      if ((lane & 7) == 0)
        sdst[(size_t)k * N8 + (size_t)(base + ig * 4 + i) * 8 + head] = p;
    }
  }
}

// ---------------------------------------------------------------------------
__global__ void wkt_kernel(const float* __restrict__ Wk, ush* __restrict__ wkT)
{
  int idx = blockIdx.x * 256 + threadIdx.x;
  int n = idx >> 8, k = idx & 255;
  wkT[idx] = (ush)bfr(Wk[k * HID + n]);
}

// ---------------------------------------------------------------------------
// CSR build, per-block multisplit (unchanged — off the critical list)
// ---------------------------------------------------------------------------
__global__ __launch_bounds__(256) void histb_kernel(
    const int* __restrict__ d0, const int* __restrict__ d1,
    const int* __restrict__ d2, const int* __restrict__ d3,
    int* __restrict__ bcnt)
{
  __shared__ int lh[NBUK];
  const int rel = blockIdx.x / NB1;
  const int blk = blockIdx.x % NB1;
  for (int j = threadIdx.x; j < NBUK; j += 256) lh[j] = 0;
  __syncthreads();
  const int* dp = rel == 0 ? d0 : rel == 1 ? d1 : rel == 2 ? d2 : d3;
  const int base = blk * EPB1;
#pragma unroll 4
  for (int k = 0; k < EPB1 / 256; ++k) {
    int i = base + k * 256 + threadIdx.x;
    if (i < E) atomicAdd(&lh[dp[i] >> BSH], 1);
  }
  __syncthreads();
  for (int j = threadIdx.x; j < NBUK; j += 256)
    if (lh[j]) atomicAdd(&bcnt[rel * NBUK + j], lh[j]);
}

__global__ __launch_bounds__(256) void bscan_kernel(
    const int* __restrict__ bcnt, int* __restrict__ bstart, int* __restrict__ bcur)
{
  __shared__ int part[256];
  const int t = threadIdx.x;
  const int chunk = (NBT + 255) / 256;   // 7
  const int b = t * chunk;
  const int e = min(NBT, b + chunk);
  int s = 0;
  for (int i = b; i < e; ++i) s += bcnt[i];
  part[t] = s;
  __syncthreads();
  for (int off = 1; off < 256; off <<= 1) {
    int u = (t >= off) ? part[t - off] : 0;
    __syncthreads();
    part[t] += u;
    __syncthreads();
  }
  int run = part[t] - s;
  for (int i = b; i < e; ++i) {
    bstart[i] = run;
    bcur[i] = run;
    run += bcnt[i];
  }
}

__global__ __launch_bounds__(256) void scat2_kernel(
    const int* __restrict__ s0, const int* __restrict__ d0,
    const int* __restrict__ s1, const int* __restrict__ d1,
    const int* __restrict__ s2, const int* __restrict__ d2,
    const int* __restrict__ s3, const int* __restrict__ d3,
    int* __restrict__ bcur, u32* __restrict__ bstage)
{
  __shared__ int lh[NBUK];
  const int rel = blockIdx.x / NB1;
  const int blk = blockIdx.x % NB1;
  const int* sp = rel == 0 ? s0 : rel == 1 ? s1 : rel == 2 ? s2 : s3;
  const int* dp = rel == 0 ? d0 : rel == 1 ? d1 : rel == 2 ? d2 : d3;
  for (int j = threadIdx.x; j < NBUK; j += 256) lh[j] = 0;
  __syncthreads();
  const int base = blk * EPB1;
#pragma unroll 4
  for (int k = 0; k < EPB1 / 256; ++k) {
    int i = base + k * 256 + threadIdx.x;
    if (i < E) atomicAdd(&lh[dp[i] >> BSH], 1);
  }
  __syncthreads();
  for (int j = threadIdx.x; j < NBUK; j += 256) {
    int c = lh[j];
    lh[j] = c ? atomicAdd(&bcur[rel * NBUK + j], c) : 0;
  }
  __syncthreads();
#pragma unroll 4
  for (int k = 0; k < EPB1 / 256; ++k) {
    int i = base + k * 256 + threadIdx.x;
    if (i < E) {
      int dst = dp[i], src = sp[i];
      int pos = atomicAdd(&lh[dst >> BSH], 1);   // LDS atomic (fast)
      bstage[pos] = ((u32)dst << 16) | (u32)src;
    }
  }
}

__global__ __launch_bounds__(256) void cntb_kernel(
    const u32* __restrict__ bstage, const int* __restrict__ bstart,
    const int* __restrict__ bcnt, int* __restrict__ count)
{
  __shared__ int lcnt[128];
  const int bb = blockIdx.x;
  const int rel = bb / NBUK, b = bb % NBUK;
  if (threadIdx.x < 128) lcnt[threadIdx.x] = 0;
  __syncthreads();
  const int rb = bstart[bb];
  const int cnt = bcnt[bb];
  for (int k = threadIdx.x; k < cnt; k += 256)
    atomicAdd(&lcnt[(bstage[rb + k] >> 16) & 127], 1);
  __syncthreads();
  const int fb = rel * N + b * 128;
  const int lim = min(128, N - b * 128);
  if (threadIdx.x < lim) count[fb + threadIdx.x] = lcnt[threadIdx.x];
}

__global__ __launch_bounds__(SC_TPB) void scanA_kernel(
    const int* __restrict__ count, int* __restrict__ bsum)
{
  __shared__ int red[4];
  const int t = threadIdx.x;
  const int base = blockIdx.x * SC_PERB + t * 8;
  int s = 0;
  if (base + 8 <= NTOT) {
    int4 a = *(const int4*)&count[base];
    int4 b = *(const int4*)&count[base + 4];
    s = a.x + a.y + a.z + a.w + b.x + b.y + b.z + b.w;
  } else {
    for (int i = 0; i < 8; ++i) { int idx = base + i; if (idx < NTOT) s += count[idx]; }
  }
#pragma unroll
  for (int off = 1; off < 64; off <<= 1) s += __shfl_xor(s, off);
  if ((t & 63) == 0) red[t >> 6] = s;
  __syncthreads();
  if (t == 0) bsum[blockIdx.x] = red[0] + red[1] + red[2] + red[3];
}

__global__ __launch_bounds__(128) void scanB_kernel(int* __restrict__ bsum)
{
  __shared__ int tmp[128];
  const int t = threadIdx.x;
  int v = (t < SC_NB) ? bsum[t] : 0;
  tmp[t] = v;
  __syncthreads();
  for (int off = 1; off < 128; off <<= 1) {
    int u = (t >= off) ? tmp[t - off] : 0;
    __syncthreads();
    tmp[t] += u;
    __syncthreads();
  }
  if (t < SC_NB) bsum[t] = tmp[t] - v;  // exclusive
}

__global__ __launch_bounds__(SC_TPB) void scanC_kernel(
    const int* __restrict__ count, const int* __restrict__ bsum,
    int* __restrict__ start)
{
  __shared__ int ts[SC_TPB];
  const int t = threadIdx.x;
  const int base = blockIdx.x * SC_PERB + t * 8;
  int c[8];
  int s = 0;
#pragma unroll
  for (int i = 0; i < 8; ++i) {
    int idx = base + i;
    c[i] = (idx < NTOT) ? count[idx] : 0;
    s += c[i];
  }
  ts[t] = s;
  __syncthreads();
  for (int off = 1; off < SC_TPB; off <<= 1) {
    int u = (t >= off) ? ts[t - off] : 0;
    __syncthreads();
    ts[t] += u;
    __syncthreads();
  }
  int run = ts[t] - s + bsum[blockIdx.x];
#pragma unroll
  for (int i = 0; i < 8; ++i) {
    int idx = base + i;
    if (idx < NTOT) {
      start[idx] = run;
      run += c[i];
    }
  }
}

__global__ __launch_bounds__(256) void fillb_kernel(
    const u32* __restrict__ bstage, const int* __restrict__ bstart,
    const int* __restrict__ bcnt, const int* __restrict__ start,
    int* __restrict__ csr)
{
  __shared__ int lcur[128];
  const int bb = blockIdx.x;           // rel*NBUK + b
  const int rel = bb / NBUK, b = bb % NBUK;
  const int fb = rel * N + b * 128;
  const int lim = min(128, N - b * 128);
  if (threadIdx.x < lim) lcur[threadIdx.x] = start[fb + threadIdx.x];
  __syncthreads();
  const int rb = bstart[bb];
  const int cnt = bcnt[bb];
  for (int k = threadIdx.x; k < cnt; k += 256) {
    u32 pk = bstage[rb + k];
    int ldst = (pk >> 16) & 127;
    int pos = atomicAdd(&lcur[ldst], 1);
    csr[pos] = (int)(pk & 0xffffu);
  }
}

// ---------------------------------------------------------------------------
// Relation conv, ALL 4 relations in one launch (rel = blockIdx/12500).
// bf16 row gathers, fp32 accumulate, bf16 z output. zall rows: rel*N + dst.
// ---------------------------------------------------------------------------
__global__ __launch_bounds__(256) void conv_kernel(
    const ush* __restrict__ hub, const ush* __restrict__ hib,
    const float* __restrict__ su, const float* __restrict__ si,
    const int* __restrict__ csr,
    const int* __restrict__ start, const int* __restrict__ count,
    ush* __restrict__ zall)
{
  const int rel = blockIdx.x / (N / 4);
  const int lb  = blockIdx.x % (N / 4);
  const int dst = lb * 4 + (threadIdx.x >> 6);
  const int lane = threadIdx.x & 63;
  // rel 0=iu(xs=hib), 1=uu(xs=hub), 2=ui(xs=hub), 3=ii(xs=hib)
  const ush* xsb = (rel == 0 || rel == 3) ? hib : hub;
  const float* ss = rel == 0 ? si : rel == 1 ? su + N8 :
                    rel == 2 ? su + 3 * (size_t)N8 : si + 2 * (size_t)N8;
  const float* sd = rel == 0 ? su : rel == 1 ? su + 2 * (size_t)N8 :
                    rel == 2 ? si + N8 : si + 3 * (size_t)N8;
  const int grow = rel * N + dst;
  const int e0 = start[grow];
  const int ne = count[grow];

  const int h1 = lane & 7;
  const float sdv1 = sd[dst * 8 + h1];
  float den = 0.f;
  for (int j = lane >> 3; j < ne; j += 8)
    den += __expf(lrelu(ss[csr[e0 + j] * 8 + h1] + sdv1));
  den += __shfl_xor(den, 8);
  den += __shfl_xor(den, 16);
  den += __shfl_xor(den, 32);
  const int h2 = lane >> 3;
  const float inv_den = 1.f / (__shfl(den, h2) + 1e-16f);
  const float sdv2 = sd[dst * 8 + h2];

  float a0 = 0.f, a1 = 0.f, a2 = 0.f, a3 = 0.f;
  int j = 0;
  for (; j + 4 <= ne; j += 4) {
    int sA = csr[e0 + j], sB = csr[e0 + j + 1];
    int sC = csr[e0 + j + 2], sD = csr[e0 + j + 3];
    float lA = ss[sA * 8 + h2], lB = ss[sB * 8 + h2];
    float lC = ss[sC * 8 + h2], lD = ss[sD * 8 + h2];
    ushort4 vA = *(const ushort4*)&xsb[(size_t)sA * HID + lane * 4];
    ushort4 vB = *(const ushort4*)&xsb[(size_t)sB * HID + lane * 4];
    ushort4 vC = *(const ushort4*)&xsb[(size_t)sC * HID + lane * 4];
    ushort4 vD = *(const ushort4*)&xsb[(size_t)sD * HID + lane * 4];
    float alA = __expf(lrelu(lA + sdv2)) * inv_den;
    float alB = __expf(lrelu(lB + sdv2)) * inv_den;
    float alC = __expf(lrelu(lC + sdv2)) * inv_den;
    float alD = __expf(lrelu(lD + sdv2)) * inv_den;
    a0 = fmaf(alA, bf2f(vA.x), a0); a1 = fmaf(alA, bf2f(vA.y), a1);
    a2 = fmaf(alA, bf2f(vA.z), a2); a3 = fmaf(alA, bf2f(vA.w), a3);
    a0 = fmaf(alB, bf2f(vB.x), a0); a1 = fmaf(alB, bf2f(vB.y), a1);
    a2 = fmaf(alB, bf2f(vB.z), a2); a3 = fmaf(alB, bf2f(vB.w), a3);
    a0 = fmaf(alC, bf2f(vC.x), a0); a1 = fmaf(alC, bf2f(vC.y), a1);
    a2 = fmaf(alC, bf2f(vC.z), a2); a3 = fmaf(alC, bf2f(vC.w), a3);
    a0 = fmaf(alD, bf2f(vD.x), a0); a1 = fmaf(alD, bf2f(vD.y), a1);
    a2 = fmaf(alD, bf2f(vD.z), a2); a3 = fmaf(alD, bf2f(vD.w), a3);
  }
  for (; j < ne; ++j) {
    int sA = csr[e0 + j];
    float alA = __expf(lrelu(ss[sA * 8 + h2] + sdv2)) * inv_den;
    ushort4 vA = *(const ushort4*)&xsb[(size_t)sA * HID + lane * 4];
    a0 = fmaf(alA, bf2f(vA.x), a0); a1 = fmaf(alA, bf2f(vA.y), a1);
    a2 = fmaf(alA, bf2f(vA.z), a2); a3 = fmaf(alA, bf2f(vA.w), a3);
  }
  ushort4 o;
  o.x = (ush)bfr(fmaxf(a0, 0.f));
  o.y = (ush)bfr(fmaxf(a1, 0.f));
  o.z = (ush)bfr(fmaxf(a2, 0.f));
  o.w = (ush)bfr(fmaxf(a3, 0.f));
  *(ushort4*)&zall[(size_t)grow * HID + lane * 4] = o;
}

// ---------------------------------------------------------------------------
// Semantic scores v5: 128x256 tile (z read ONCE), K=256 in 4 steps.
// A staged to a 4-deep WRITE-ONCE LDS ring (64KB) via global_load_lds upfront;
// per-step counted s_waitcnt vmcnt(6/4/2/0) + raw s_barrier keeps the other
// stages in flight across barriers (no drain-to-0 — the R9 killer).
// B (wkT 128KB, L2-hot) read as register fragments. 512 thr = 8 waves (2m x 4n).
// ---------------------------------------------------------------------------
__global__ __launch_bounds__(512, 2) void semscore_kernel(
    const ush* __restrict__ zbu0, const ush* __restrict__ zbu1,
    const ush* __restrict__ zbi0, const ush* __restrict__ zbi1,
    const ush* __restrict__ wkT, const float* __restrict__ bk,
    const float* __restrict__ q, float* __restrict__ score)
{
  __shared__ ush As[4][128 * 64];   // 64 KB ring: [kc][row*64 + pos*8], swizzled
  const int bid = blockIdx.x;
  const int mat = bid / SMT;
  const int mt  = bid % SMT;
  const ush* zsrc = mat == 0 ? zbu0 : mat == 1 ? zbu1 : mat == 2 ? zbi0 : zbi1;
  const int Mbase = mt * 128;
  const int t = threadIdx.x;
  const int w = t >> 6, l = t & 63;
  const int lrow = l & 15, kgrp = l >> 4;
  const int wr = w >> 2, wc = w & 3;    // 2 m-spans x 4 n-spans of 64

  // stage kc: 1024 16B-chunks; chunk q16 -> row r=q16>>3, data-col c=(q16&7)^(r&7)
  auto stage = [&](int kc) {
#pragma unroll
    for (int i = 0; i < 2; ++i) {
      int q16 = i * 512 + t;
      int r = q16 >> 3;
      int c = (q16 & 7) ^ (r & 7);
      int gr = Mbase + r; if (gr >= N) gr = N - 1;
      gll16(&zsrc[(size_t)gr * HID + kc * 64 + c * 8],
            &As[kc][(i * 512 + w * 64) * 8]);
    }
  };

  f32x4 acc[4][4];
  const f32x4 zz = {0.f, 0.f, 0.f, 0.f};
#pragma unroll
  for (int m = 0; m < 4; ++m)
#pragma unroll
    for (int n = 0; n < 4; ++n) acc[m][n] = zz;

  stage(0); stage(1); stage(2); stage(3);   // 8 vmem insts/wave outstanding

  auto compute = [&](int kc) {
    // B fragments once per step: wave's 64-col slice x 64-k
    bf16x8 Bf[4][2];
#pragma unroll
    for (int n = 0; n < 4; ++n)
#pragma unroll
      for (int ks = 0; ks < 2; ++ks)
        Bf[n][ks] = *(const bf16x8*)&wkT[(size_t)(wc * 64 + n * 16 + lrow) * HID
                                         + kc * 64 + ks * 32 + kgrp * 8];
#pragma unroll
    for (int m = 0; m < 4; ++m) {
      const int mrow = wr * 64 + m * 16 + lrow;
      bf16x8 Af[2];
#pragma unroll
      for (int ks = 0; ks < 2; ++ks) {
        int ch = (ks * 4 + kgrp) ^ (mrow & 7);
        Af[ks] = *(const bf16x8*)&As[kc][mrow * 64 + ch * 8];
      }
#pragma unroll
      for (int n = 0; n < 4; ++n)
#pragma unroll
        for (int ks = 0; ks < 2; ++ks)
          acc[m][n] = __builtin_amdgcn_mfma_f32_16x16x32_bf16(Af[ks], Bf[n][ks],
                                                              acc[m][n], 0, 0, 0);
    }
  };

  WAITK("6"); compute(0);     // buf0's 2 loads retired; 6 still in flight
  WAITK("4"); compute(1);
  WAITK("2"); compute(2);
  WAITK("0"); compute(3);

  // epilogue: D row = Mbase + wr*64 + m*16 + kgrp*4 + i; col = wc*64 + n*16 + lrow
  float s = 0.f;
#pragma unroll
  for (int m = 0; m < 4; ++m) {
    const int gr0 = Mbase + wr * 64 + m * 16 + kgrp * 4;
#pragma unroll
    for (int n = 0; n < 4; ++n) {
      const int col = wc * 64 + n * 16 + lrow;
      const float bkv = bk[col], qv = q[col];
#pragma unroll
      for (int i = 0; i < 4; ++i)
        if (gr0 + i < N) s += tanh_fast(acc[m][n][i] + bkv) * qv;
    }
  }
#pragma unroll
  for (int off = 1; off < 64; off <<= 1) s += __shfl_xor(s, off);
  if (l == 0) atomicAdd(&score[mat], s);
}

__global__ void attn2_kernel(float* __restrict__ score, float inv_n)
{
#pragma unroll
  for (int s = 0; s < 2; ++s) {
    float s0 = score[2 * s] * inv_n, s1 = score[2 * s + 1] * inv_n;
    float m = fmaxf(s0, s1);
    float e0 = __expf(s0 - m), e1 = __expf(s1 - m);
    float d = e0 + e1;
    score[4 + 2 * s] = e0 / d;
    score[5 + 2 * s] = e1 / d;
  }
}

// ---------------------------------------------------------------------------
// Final: out[n,64] = (a0*z0[n]+a1*z1[n]) @ Wl + bl, both sides one launch.
// ---------------------------------------------------------------------------
__global__ __launch_bounds__(256) void final_kernel(
    const ush* __restrict__ zbu0, const ush* __restrict__ zbu1,
    const ush* __restrict__ zbi0, const ush* __restrict__ zbi1,
    const float* __restrict__ attn, const float* __restrict__ Wl,
    const float* __restrict__ bl, float* __restrict__ out)
{
  __shared__ float zT[HID * 16];
  const int bid = blockIdx.x;
  const int side = bid >= FING;
  const ush* z0 = side ? zbi0 : zbu0;
  const ush* z1 = side ? zbi1 : zbu1;
  float* op = out + (size_t)side * N * OUTD;
  const int t = threadIdx.x;
  const int base = (bid - side * FING) * 16;
  const float a0 = attn[side * 2], a1 = attn[side * 2 + 1];
  for (int idx = t; idx < 16 * (HID / 2); idx += 256) {   // 2048 u32 pairs
    int r = idx & 15, cw = idx >> 4;
    u32 v0 = *(const u32*)&z0[(size_t)(base + r) * HID + cw * 2];
    u32 v1 = *(const u32*)&z1[(size_t)(base + r) * HID + cw * 2];
    zT[(2 * cw) * 16 + r]     = a0 * bf2f(v0 & 0xffffu) + a1 * bf2f(v1 & 0xffffu);
    zT[(2 * cw + 1) * 16 + r] = a0 * bf2f(v0 >> 16) + a1 * bf2f(v1 >> 16);
  }
  __syncthreads();
  const int ig = t >> 6;
  const int cc = t & 63;
  float acc[4] = {};
  for (int k = 0; k < HID; ++k) {
    float w = Wl[k * OUTD + cc];
    f4 xv = *(const f4*)&zT[k * 16 + ig * 4];
    acc[0] = fmaf(xv.x, w, acc[0]);
    acc[1] = fmaf(xv.y, w, acc[1]);
    acc[2] = fmaf(xv.z, w, acc[2]);
    acc[3] = fmaf(xv.w, w, acc[3]);
  }
  float bb = bl[cc];
#pragma unroll
  for (int i = 0; i < 4; ++i)
    op[(size_t)(base + ig * 4 + i) * OUTD + cc] = acc[i] + bb;
}

// ---------------------------------------------------------------------------
extern "C" void kernel_launch(void* const* d_in, const int* in_sizes, int n_in,
                              void* d_out, int out_size, void* d_ws, size_t ws_size,
                              hipStream_t stream)
{
  const float* x_user = (const float*)d_in[0];
  const float* x_item = (const float*)d_in[1];
  const int*   e_ui   = (const int*)d_in[2];
  const int*   e_iu   = (const int*)d_in[3];
  const int*   e_uu   = (const int*)d_in[4];
  const int*   e_ii   = (const int*)d_in[5];
  const float* Wp_u   = (const float*)d_in[6];
  const float* bp_u   = (const float*)d_in[7];
  const float* Wp_i   = (const float*)d_in[8];
  const float* bp_i   = (const float*)d_in[9];
  const float* as_ui  = (const float*)d_in[10];
  const float* ad_ui  = (const float*)d_in[11];
  const float* as_iu  = (const float*)d_in[12];
  const float* ad_iu  = (const float*)d_in[13];
  const float* as_uu  = (const float*)d_in[14];
  const float* ad_uu  = (const float*)d_in[15];
  const float* as_ii  = (const float*)d_in[16];
  const float* ad_ii  = (const float*)d_in[17];
  const float* Wk     = (const float*)d_in[18];
  const float* bk     = (const float*)d_in[19];
  const float* q      = (const float*)d_in[20];
  const float* Wl     = (const float*)d_in[21];
  const float* bl     = (const float*)d_in[22];

  const size_t NH = (size_t)N * HID;
  size_t need = (8 * (size_t)N8 + 8) * 4                     // su,si,sc (f32)
              + (6 * NH + (size_t)HID * HID) * 2             // 4x z, hub, hib, wkT (bf16)
              + ((size_t)8 * N + 4 * (size_t)E + 3 * NBT + 128 + 64) * 4;
  if (ws_size < need) {
    hipMemsetAsync(d_out, 0x7f, (size_t)out_size * sizeof(float), stream);
    return;
  }
  float* su = (float*)d_ws;
  float* si = su + 4 * (size_t)N8;
  float* sc = si + 4 * (size_t)N8;
  ush* zbu0 = (ush*)(sc + 8);
  ush* zbu1 = zbu0 + NH;
  ush* zbi0 = zbu1 + NH;
  ush* zbi1 = zbi0 + NH;
  ush* hub  = zbi1 + NH;
  ush* hib  = hub + NH;
  ush* wkT  = hib + NH;
  int* count  = (int*)(wkT + (size_t)HID * HID);
  int* bcnt   = count + NTOT;
  int* start  = bcnt + NBT;
  int* bstart = start + NTOT;
  int* bcur   = bstart + NBT;
  int* bsum   = bcur + NBT;
  int* csr    = bsum + 128;
  u32* bstage = (u32*)zbu0;     // aliases zbu0 (dead until conv)

  wkt_kernel<<<HID * HID / 256, 256, 0, stream>>>(Wk, wkT);

  proj_kernel<<<N / 16, 256, 0, stream>>>(x_user, Wp_u, bp_u,
                                          ad_iu, as_uu, ad_uu, as_ui, hub, su);
  proj_kernel<<<N / 16, 256, 0, stream>>>(x_item, Wp_i, bp_i,
                                          as_iu, ad_ui, as_ii, ad_ii, hib, si);

  // batched CSR build via per-block multisplit: rel 0=iu, 1=uu, 2=ui, 3=ii
  hipMemsetAsync(bcnt, 0, NBT * sizeof(int), stream);
  histb_kernel<<<4 * NB1, 256, 0, stream>>>(e_iu + E, e_uu + E, e_ui + E, e_ii + E, bcnt);
  bscan_kernel<<<1, 256, 0, stream>>>(bcnt, bstart, bcur);
  scat2_kernel<<<4 * NB1, 256, 0, stream>>>(e_iu, e_iu + E, e_uu, e_uu + E,
                                            e_ui, e_ui + E, e_ii, e_ii + E,
                                            bcur, bstage);
  cntb_kernel<<<NBT, 256, 0, stream>>>(bstage, bstart, bcnt, count);
  scanA_kernel<<<SC_NB, SC_TPB, 0, stream>>>(count, bsum);
  scanB_kernel<<<1, 128, 0, stream>>>(bsum);
  scanC_kernel<<<SC_NB, SC_TPB, 0, stream>>>(count, bsum, start);
  fillb_kernel<<<NBT, 256, 0, stream>>>(bstage, bstart, bcnt, start, csr);

  // all 4 relation convs in ONE launch (z rows: rel*N + dst -> zbu0 base)
  conv_kernel<<<NTOT / 4, 256, 0, stream>>>(hub, hib, su, si, csr, start, count, zbu0);

  // semantic attention: 4 matrices x 391 M-tiles, z read once
  hipMemsetAsync(sc, 0, 4 * sizeof(float), stream);
  semscore_kernel<<<4 * SMT, 512, 0, stream>>>(zbu0, zbu1, zbi0, zbi1, wkT, bk, q, sc);
  attn2_kernel<<<1, 1, 0, stream>>>(sc, 1.0f / (float)N);

  // final linear: both sides in one launch
  final_kernel<<<2 * FING, 256, 0, stream>>>(zbu0, zbu1, zbi0, zbi1, sc + 4, Wl, bl,
                                             (float*)d_out);
}

// Round 11
// 853.766 us; speedup vs baseline: 2.3474x; 1.0171x over previous
//
#include <hip/hip_runtime.h>
#include <math.h>

#define N     50000
#define F_IN  128
#define HID   256
#define E     800000
#define OUTD  64
#define NEG   0.2f
#define N8    (N * 8)
#define NTOT  (4 * N)
#define FING  (N / 16)               // 3125
#define SMT   ((N + 127) / 128)      // 391 M-tiles per matrix

// hierarchical scan geometry
#define SC_TPB   256
#define SC_PERB  2048
#define SC_NB    ((NTOT + SC_PERB - 1) / SC_PERB)   // 98

// bucket sort geometry
#define BSH   7                      // bucket = dst >> 7 (128 dsts/bucket)
#define NBUK  ((N + 127) / 128)      // 391
#define NBT   (4 * NBUK)             // 1564
#define EPB1  8192
#define NB1   ((E + EPB1 - 1) / EPB1) // 98

typedef float4 f4;
typedef unsigned int u32;
typedef unsigned short ush;
typedef float f32x4 __attribute__((ext_vector_type(4)));
typedef short bf16x8 __attribute__((ext_vector_type(8)));

static __device__ __forceinline__ float lrelu(float x) { return x >= 0.f ? x : NEG * x; }
static __device__ __forceinline__ u32 bfr(float x) {
  u32 u = __float_as_uint(x);
  return (u + 0x7fffu + ((u >> 16) & 1u)) >> 16;
}
static __device__ __forceinline__ float bf2f(u32 us) { return __uint_as_float(us << 16); }
// tanh(x) = 1 - 2/(exp(2x)+1)
static __device__ __forceinline__ float tanh_fast(float x) {
  float e = __expf(2.f * x);
  return fmaf(-2.f, __builtin_amdgcn_rcpf(e + 1.f), 1.f);
}

// async global->LDS, 16B per lane; LDS dest = wave-uniform base + lane*16
typedef const __attribute__((address_space(1))) unsigned int gu32;
typedef __attribute__((address_space(3))) unsigned int lu32;
static __device__ __forceinline__ void gll16(const void* g, void* l) {
  __builtin_amdgcn_global_load_lds((gu32*)g, (lu32*)l, 16, 0, 0);
}

// counted-vmcnt barrier
#define WAITK(nstr)                                          \
  asm volatile("s_waitcnt vmcnt(" nstr ")" ::: "memory");    \
  __builtin_amdgcn_s_barrier();                              \
  asm volatile("" ::: "memory");

// ---------------------------------------------------------------------------
// Projection + fused per-node attention scores.
// ---------------------------------------------------------------------------
__global__ __launch_bounds__(256) void proj_kernel(
    const float* __restrict__ x, const float* __restrict__ W, const float* __restrict__ b,
    const float* __restrict__ a0, const float* __restrict__ a1,
    const float* __restrict__ a2, const float* __restrict__ a3,
    ush* __restrict__ hb, float* __restrict__ sdst)
{
  __shared__ float xT[F_IN * 16];   // [k][i]
  const int t = threadIdx.x;
  const int base = blockIdx.x * 16;
  for (int idx = t; idx < 16 * F_IN; idx += 256) {
    int r = idx & 15, c = idx >> 4;
    xT[c * 16 + r] = x[(size_t)(base + r) * F_IN + c];
  }
  __syncthreads();
  const int ig = t >> 6;
  const int lane = t & 63;
  const int j0 = lane * 4;
  float acc[4][4] = {};
  for (int k = 0; k < F_IN; ++k) {
    f4 w  = *(const f4*)&W[k * HID + j0];
    f4 xv = *(const f4*)&xT[k * 16 + ig * 4];
    const float wa[4] = {w.x, w.y, w.z, w.w};
    const float xa[4] = {xv.x, xv.y, xv.z, xv.w};
#pragma unroll
    for (int i = 0; i < 4; ++i)
#pragma unroll
      for (int j = 0; j < 4; ++j) acc[i][j] = fmaf(xa[i], wa[j], acc[i][j]);
  }
  f4 bv = *(const f4*)&b[j0];
  const float ba[4] = {bv.x, bv.y, bv.z, bv.w};
#pragma unroll
  for (int i = 0; i < 4; ++i) {
#pragma unroll
    for (int j = 0; j < 4; ++j) acc[i][j] += ba[j];
    ushort4 o;
    o.x = (ush)bfr(acc[i][0]); o.y = (ush)bfr(acc[i][1]);
    o.z = (ush)bfr(acc[i][2]); o.w = (ush)bfr(acc[i][3]);
    *(ushort4*)&hb[(size_t)(base + ig * 4 + i) * HID + j0] = o;
  }
  const int head = lane >> 3;
  const float* av[4] = {a0, a1, a2, a3};
#pragma unroll
  for (int k = 0; k < 4; ++k) {
    f4 a = *(const f4*)&av[k][j0];
#pragma unroll
    for (int i = 0; i < 4; ++i) {
      float p = acc[i][0] * a.x + acc[i][1] * a.y + acc[i][2] * a.z + acc[i][3] * a.w;
      p += __shfl_xor(p, 1);
      p += __shfl_xor(p, 2);
      p += __shfl_xor(p, 4);
      if ((lane & 7) == 0)
        sdst[(size_t)k * N8 + (size_t)(base + ig * 4 + i) * 8 + head] = p;
    }
  }
}

// ---------------------------------------------------------------------------
__global__ void wkt_kernel(const float* __restrict__ Wk, ush* __restrict__ wkT)
{
  int idx = blockIdx.x * 256 + threadIdx.x;
  int n = idx >> 8, k = idx & 255;
  wkT[idx] = (ush)bfr(Wk[k * HID + n]);
}

// ---------------------------------------------------------------------------
// CSR build, per-block multisplit (unchanged — off the critical list)
// ---------------------------------------------------------------------------
__global__ __launch_bounds__(256) void histb_kernel(
    const int* __restrict__ d0, const int* __restrict__ d1,
    const int* __restrict__ d2, const int* __restrict__ d3,
    int* __restrict__ bcnt)
{
  __shared__ int lh[NBUK];
  const int rel = blockIdx.x / NB1;
  const int blk = blockIdx.x % NB1;
  for (int j = threadIdx.x; j < NBUK; j += 256) lh[j] = 0;
  __syncthreads();
  const int* dp = rel == 0 ? d0 : rel == 1 ? d1 : rel == 2 ? d2 : d3;
  const int base = blk * EPB1;
#pragma unroll 4
  for (int k = 0; k < EPB1 / 256; ++k) {
    int i = base + k * 256 + threadIdx.x;
    if (i < E) atomicAdd(&lh[dp[i] >> BSH], 1);
  }
  __syncthreads();
  for (int j = threadIdx.x; j < NBUK; j += 256)
    if (lh[j]) atomicAdd(&bcnt[rel * NBUK + j], lh[j]);
}

__global__ __launch_bounds__(256) void bscan_kernel(
    const int* __restrict__ bcnt, int* __restrict__ bstart, int* __restrict__ bcur)
{
  __shared__ int part[256];
  const int t = threadIdx.x;
  const int chunk = (NBT + 255) / 256;   // 7
  const int b = t * chunk;
  const int e = min(NBT, b + chunk);
  int s = 0;
  for (int i = b; i < e; ++i) s += bcnt[i];
  part[t] = s;
  __syncthreads();
  for (int off = 1; off < 256; off <<= 1) {
    int u = (t >= off) ? part[t - off] : 0;
    __syncthreads();
    part[t] += u;
    __syncthreads();
  }
  int run = part[t] - s;
  for (int i = b; i < e; ++i) {
    bstart[i] = run;
    bcur[i] = run;
    run += bcnt[i];
  }
}

__global__ __launch_bounds__(256) void scat2_kernel(
    const int* __restrict__ s0, const int* __restrict__ d0,
    const int* __restrict__ s1, const int* __restrict__ d1,
    const int* __restrict__ s2, const int* __restrict__ d2,
    const int* __restrict__ s3, const int* __restrict__ d3,
    int* __restrict__ bcur, u32* __restrict__ bstage)
{
  __shared__ int lh[NBUK];
  const int rel = blockIdx.x / NB1;
  const int blk = blockIdx.x % NB1;
  const int* sp = rel == 0 ? s0 : rel == 1 ? s1 : rel == 2 ? s2 : s3;
  const int* dp = rel == 0 ? d0 : rel == 1 ? d1 : rel == 2 ? d2 : d3;
  for (int j = threadIdx.x; j < NBUK; j += 256) lh[j] = 0;
  __syncthreads();
  const int base = blk * EPB1;
#pragma unroll 4
  for (int k = 0; k < EPB1 / 256; ++k) {
    int i = base + k * 256 + threadIdx.x;
    if (i < E) atomicAdd(&lh[dp[i] >> BSH], 1);
  }
  __syncthreads();
  for (int j = threadIdx.x; j < NBUK; j += 256) {
    int c = lh[j];
    lh[j] = c ? atomicAdd(&bcur[rel * NBUK + j], c) : 0;
  }
  __syncthreads();
#pragma unroll 4
  for (int k = 0; k < EPB1 / 256; ++k) {
    int i = base + k * 256 + threadIdx.x;
    if (i < E) {
      int dst = dp[i], src = sp[i];
      int pos = atomicAdd(&lh[dst >> BSH], 1);   // LDS atomic (fast)
      bstage[pos] = ((u32)dst << 16) | (u32)src;
    }
  }
}

__global__ __launch_bounds__(256) void cntb_kernel(
    const u32* __restrict__ bstage, const int* __restrict__ bstart,
    const int* __restrict__ bcnt, int* __restrict__ count)
{
  __shared__ int lcnt[128];
  const int bb = blockIdx.x;
  const int rel = bb / NBUK, b = bb % NBUK;
  if (threadIdx.x < 128) lcnt[threadIdx.x] = 0;
  __syncthreads();
  const int rb = bstart[bb];
  const int cnt = bcnt[bb];
  for (int k = threadIdx.x; k < cnt; k += 256)
    atomicAdd(&lcnt[(bstage[rb + k] >> 16) & 127], 1);
  __syncthreads();
  const int fb = rel * N + b * 128;
  const int lim = min(128, N - b * 128);
  if (threadIdx.x < lim) count[fb + threadIdx.x] = lcnt[threadIdx.x];
}

__global__ __launch_bounds__(SC_TPB) void scanA_kernel(
    const int* __restrict__ count, int* __restrict__ bsum)
{
  __shared__ int red[4];
  const int t = threadIdx.x;
  const int base = blockIdx.x * SC_PERB + t * 8;
  int s = 0;
  if (base + 8 <= NTOT) {
    int4 a = *(const int4*)&count[base];
    int4 b = *(const int4*)&count[base + 4];
    s = a.x + a.y + a.z + a.w + b.x + b.y + b.z + b.w;
  } else {
    for (int i = 0; i < 8; ++i) { int idx = base + i; if (idx < NTOT) s += count[idx]; }
  }
#pragma unroll
  for (int off = 1; off < 64; off <<= 1) s += __shfl_xor(s, off);
  if ((t & 63) == 0) red[t >> 6] = s;
  __syncthreads();
  if (t == 0) bsum[blockIdx.x] = red[0] + red[1] + red[2] + red[3];
}

__global__ __launch_bounds__(128) void scanB_kernel(int* __restrict__ bsum)
{
  __shared__ int tmp[128];
  const int t = threadIdx.x;
  int v = (t < SC_NB) ? bsum[t] : 0;
  tmp[t] = v;
  __syncthreads();
  for (int off = 1; off < 128; off <<= 1) {
    int u = (t >= off) ? tmp[t - off] : 0;
    __syncthreads();
    tmp[t] += u;
    __syncthreads();
  }
  if (t < SC_NB) bsum[t] = tmp[t] - v;  // exclusive
}

__global__ __launch_bounds__(SC_TPB) void scanC_kernel(
    const int* __restrict__ count, const int* __restrict__ bsum,
    int* __restrict__ start)
{
  __shared__ int ts[SC_TPB];
  const int t = threadIdx.x;
  const int base = blockIdx.x * SC_PERB + t * 8;
  int c[8];
  int s = 0;
#pragma unroll
  for (int i = 0; i < 8; ++i) {
    int idx = base + i;
    c[i] = (idx < NTOT) ? count[idx] : 0;
    s += c[i];
  }
  ts[t] = s;
  __syncthreads();
  for (int off = 1; off < SC_TPB; off <<= 1) {
    int u = (t >= off) ? ts[t - off] : 0;
    __syncthreads();
    ts[t] += u;
    __syncthreads();
  }
  int run = ts[t] - s + bsum[blockIdx.x];
#pragma unroll
  for (int i = 0; i < 8; ++i) {
    int idx = base + i;
    if (idx < NTOT) {
      start[idx] = run;
      run += c[i];
    }
  }
}

__global__ __launch_bounds__(256) void fillb_kernel(
    const u32* __restrict__ bstage, const int* __restrict__ bstart,
    const int* __restrict__ bcnt, const int* __restrict__ start,
    int* __restrict__ csr)
{
  __shared__ int lcur[128];
  const int bb = blockIdx.x;           // rel*NBUK + b
  const int rel = bb / NBUK, b = bb % NBUK;
  const int fb = rel * N + b * 128;
  const int lim = min(128, N - b * 128);
  if (threadIdx.x < lim) lcur[threadIdx.x] = start[fb + threadIdx.x];
  __syncthreads();
  const int rb = bstart[bb];
  const int cnt = bcnt[bb];
  for (int k = threadIdx.x; k < cnt; k += 256) {
    u32 pk = bstage[rb + k];
    int ldst = (pk >> 16) & 127;
    int pos = atomicAdd(&lcur[ldst], 1);
    csr[pos] = (int)(pk & 0xffffu);
  }
}

// ---------------------------------------------------------------------------
// Relation conv v2: SINGLE PASS (num and den accumulated together, divide at
// end — algebraically identical to two-pass softmax), 8-edge batches so 8
// row-gathers are in flight (R10: 24 VGPR -> no pipelining, serial 700cy L3
// round trips; VALUBusy 52% from redundant pass-1).
// ---------------------------------------------------------------------------
#define CONV_EDGE(sx)                                                     \
  {                                                                       \
    float al = __expf(lrelu(lg##sx + sdv2)) * 1.0f;                       \
    den += al;                                                            \
    a0 = fmaf(al, bf2f(v##sx.x), a0); a1 = fmaf(al, bf2f(v##sx.y), a1);   \
    a2 = fmaf(al, bf2f(v##sx.z), a2); a3 = fmaf(al, bf2f(v##sx.w), a3);   \
  }

__global__ __launch_bounds__(256) void conv_kernel(
    const ush* __restrict__ hub, const ush* __restrict__ hib,
    const float* __restrict__ su, const float* __restrict__ si,
    const int* __restrict__ csr,
    const int* __restrict__ start, const int* __restrict__ count,
    ush* __restrict__ zall)
{
  const int rel = blockIdx.x / (N / 4);
  const int lb  = blockIdx.x % (N / 4);
  const int dst = lb * 4 + (threadIdx.x >> 6);
  const int lane = threadIdx.x & 63;
  // rel 0=iu(xs=hib), 1=uu(xs=hub), 2=ui(xs=hub), 3=ii(xs=hib)
  const ush* xsb = (rel == 0 || rel == 3) ? hib : hub;
  const float* ss = rel == 0 ? si : rel == 1 ? su + N8 :
                    rel == 2 ? su + 3 * (size_t)N8 : si + 2 * (size_t)N8;
  const float* sd = rel == 0 ? su : rel == 1 ? su + 2 * (size_t)N8 :
                    rel == 2 ? si + N8 : si + 3 * (size_t)N8;
  const int grow = rel * N + dst;
  const int e0 = start[grow];
  const int ne = count[grow];

  const int h2 = lane >> 3;
  const float sdv2 = sd[dst * 8 + h2];

  float den = 0.f;
  float a0 = 0.f, a1 = 0.f, a2 = 0.f, a3 = 0.f;
  int j = 0;
  for (; j + 8 <= ne; j += 8) {
    // 8 independent index loads, then 8 score loads + 8 row gathers in flight
    int s0_ = csr[e0 + j + 0], s1_ = csr[e0 + j + 1];
    int s2_ = csr[e0 + j + 2], s3_ = csr[e0 + j + 3];
    int s4_ = csr[e0 + j + 4], s5_ = csr[e0 + j + 5];
    int s6_ = csr[e0 + j + 6], s7_ = csr[e0 + j + 7];
    float lg0 = ss[s0_ * 8 + h2], lg1 = ss[s1_ * 8 + h2];
    float lg2 = ss[s2_ * 8 + h2], lg3 = ss[s3_ * 8 + h2];
    float lg4 = ss[s4_ * 8 + h2], lg5 = ss[s5_ * 8 + h2];
    float lg6 = ss[s6_ * 8 + h2], lg7 = ss[s7_ * 8 + h2];
    ushort4 v0 = *(const ushort4*)&xsb[(size_t)s0_ * HID + lane * 4];
    ushort4 v1 = *(const ushort4*)&xsb[(size_t)s1_ * HID + lane * 4];
    ushort4 v2 = *(const ushort4*)&xsb[(size_t)s2_ * HID + lane * 4];
    ushort4 v3 = *(const ushort4*)&xsb[(size_t)s3_ * HID + lane * 4];
    ushort4 v4 = *(const ushort4*)&xsb[(size_t)s4_ * HID + lane * 4];
    ushort4 v5 = *(const ushort4*)&xsb[(size_t)s5_ * HID + lane * 4];
    ushort4 v6 = *(const ushort4*)&xsb[(size_t)s6_ * HID + lane * 4];
    ushort4 v7 = *(const ushort4*)&xsb[(size_t)s7_ * HID + lane * 4];
    CONV_EDGE(0) CONV_EDGE(1) CONV_EDGE(2) CONV_EDGE(3)
    CONV_EDGE(4) CONV_EDGE(5) CONV_EDGE(6) CONV_EDGE(7)
  }
  for (; j + 2 <= ne; j += 2) {
    int s0_ = csr[e0 + j + 0], s1_ = csr[e0 + j + 1];
    float lg0 = ss[s0_ * 8 + h2], lg1 = ss[s1_ * 8 + h2];
    ushort4 v0 = *(const ushort4*)&xsb[(size_t)s0_ * HID + lane * 4];
    ushort4 v1 = *(const ushort4*)&xsb[(size_t)s1_ * HID + lane * 4];
    CONV_EDGE(0) CONV_EDGE(1)
  }
  if (j < ne) {
    int s0_ = csr[e0 + j];
    float lg0 = ss[s0_ * 8 + h2];
    ushort4 v0 = *(const ushort4*)&xsb[(size_t)s0_ * HID + lane * 4];
    CONV_EDGE(0)
  }
  const float inv = 1.f / (den + 1e-16f);
  ushort4 o;
  o.x = (ush)bfr(fmaxf(a0 * inv, 0.f));
  o.y = (ush)bfr(fmaxf(a1 * inv, 0.f));
  o.z = (ush)bfr(fmaxf(a2 * inv, 0.f));
  o.w = (ush)bfr(fmaxf(a3 * inv, 0.f));
  *(ushort4*)&zall[(size_t)grow * HID + lane * 4] = o;
}

// ---------------------------------------------------------------------------
// Semantic scores v5 (R10, unchanged): 128x256 tile, 4-deep write-once LDS
// ring via global_load_lds, counted vmcnt barriers, B from L2 as registers.
// ---------------------------------------------------------------------------
__global__ __launch_bounds__(512, 2) void semscore_kernel(
    const ush* __restrict__ zbu0, const ush* __restrict__ zbu1,
    const ush* __restrict__ zbi0, const ush* __restrict__ zbi1,
    const ush* __restrict__ wkT, const float* __restrict__ bk,
    const float* __restrict__ q, float* __restrict__ score)
{
  __shared__ ush As[4][128 * 64];   // 64 KB ring: [kc][row*64 + pos*8], swizzled
  const int bid = blockIdx.x;
  const int mat = bid / SMT;
  const int mt  = bid % SMT;
  const ush* zsrc = mat == 0 ? zbu0 : mat == 1 ? zbu1 : mat == 2 ? zbi0 : zbi1;
  const int Mbase = mt * 128;
  const int t = threadIdx.x;
  const int w = t >> 6, l = t & 63;
  const int lrow = l & 15, kgrp = l >> 4;
  const int wr = w >> 2, wc = w & 3;    // 2 m-spans x 4 n-spans of 64

  auto stage = [&](int kc) {
#pragma unroll
    for (int i = 0; i < 2; ++i) {
      int q16 = i * 512 + t;
      int r = q16 >> 3;
      int c = (q16 & 7) ^ (r & 7);
      int gr = Mbase + r; if (gr >= N) gr = N - 1;
      gll16(&zsrc[(size_t)gr * HID + kc * 64 + c * 8],
            &As[kc][(i * 512 + w * 64) * 8]);
    }
  };

  f32x4 acc[4][4];
  const f32x4 zz = {0.f, 0.f, 0.f, 0.f};
#pragma unroll
  for (int m = 0; m < 4; ++m)
#pragma unroll
    for (int n = 0; n < 4; ++n) acc[m][n] = zz;

  stage(0); stage(1); stage(2); stage(3);   // 8 vmem insts/wave outstanding

  auto compute = [&](int kc) {
    bf16x8 Bf[4][2];
#pragma unroll
    for (int n = 0; n < 4; ++n)
#pragma unroll
      for (int ks = 0; ks < 2; ++ks)
        Bf[n][ks] = *(const bf16x8*)&wkT[(size_t)(wc * 64 + n * 16 + lrow) * HID
                                         + kc * 64 + ks * 32 + kgrp * 8];
#pragma unroll
    for (int m = 0; m < 4; ++m) {
      const int mrow = wr * 64 + m * 16 + lrow;
      bf16x8 Af[2];
#pragma unroll
      for (int ks = 0; ks < 2; ++ks) {
        int ch = (ks * 4 + kgrp) ^ (mrow & 7);
        Af[ks] = *(const bf16x8*)&As[kc][mrow * 64 + ch * 8];
      }
#pragma unroll
      for (int n = 0; n < 4; ++n)
#pragma unroll
        for (int ks = 0; ks < 2; ++ks)
          acc[m][n] = __builtin_amdgcn_mfma_f32_16x16x32_bf16(Af[ks], Bf[n][ks],
                                                              acc[m][n], 0, 0, 0);
    }
  };

  WAITK("6"); compute(0);
  WAITK("4"); compute(1);
  WAITK("2"); compute(2);
  WAITK("0"); compute(3);

  float s = 0.f;
#pragma unroll
  for (int m = 0; m < 4; ++m) {
    const int gr0 = Mbase + wr * 64 + m * 16 + kgrp * 4;
#pragma unroll
    for (int n = 0; n < 4; ++n) {
      const int col = wc * 64 + n * 16 + lrow;
      const float bkv = bk[col], qv = q[col];
#pragma unroll
      for (int i = 0; i < 4; ++i)
        if (gr0 + i < N) s += tanh_fast(acc[m][n][i] + bkv) * qv;
    }
  }
#pragma unroll
  for (int off = 1; off < 64; off <<= 1) s += __shfl_xor(s, off);
  if (l == 0) atomicAdd(&score[mat], s);
}

__global__ void attn2_kernel(float* __restrict__ score, float inv_n)
{
#pragma unroll
  for (int s = 0; s < 2; ++s) {
    float s0 = score[2 * s] * inv_n, s1 = score[2 * s + 1] * inv_n;
    float m = fmaxf(s0, s1);
    float e0 = __expf(s0 - m), e1 = __expf(s1 - m);
    float d = e0 + e1;
    score[4 + 2 * s] = e0 / d;
    score[5 + 2 * s] = e1 / d;
  }
}

// ---------------------------------------------------------------------------
// Final: out[n,64] = (a0*z0[n]+a1*z1[n]) @ Wl + bl, both sides one launch.
// ---------------------------------------------------------------------------
__global__ __launch_bounds__(256) void final_kernel(
    const ush* __restrict__ zbu0, const ush* __restrict__ zbu1,
    const ush* __restrict__ zbi0, const ush* __restrict__ zbi1,
    const float* __restrict__ attn, const float* __restrict__ Wl,
    const float* __restrict__ bl, float* __restrict__ out)
{
  __shared__ float zT[HID * 16];
  const int bid = blockIdx.x;
  const int side = bid >= FING;
  const ush* z0 = side ? zbi0 : zbu0;
  const ush* z1 = side ? zbi1 : zbu1;
  float* op = out + (size_t)side * N * OUTD;
  const int t = threadIdx.x;
  const int base = (bid - side * FING) * 16;
  const float a0 = attn[side * 2], a1 = attn[side * 2 + 1];
  for (int idx = t; idx < 16 * (HID / 2); idx += 256) {   // 2048 u32 pairs
    int r = idx & 15, cw = idx >> 4;
    u32 v0 = *(const u32*)&z0[(size_t)(base + r) * HID + cw * 2];
    u32 v1 = *(const u32*)&z1[(size_t)(base + r) * HID + cw * 2];
    zT[(2 * cw) * 16 + r]     = a0 * bf2f(v0 & 0xffffu) + a1 * bf2f(v1 & 0xffffu);
    zT[(2 * cw + 1) * 16 + r] = a0 * bf2f(v0 >> 16) + a1 * bf2f(v1 >> 16);
  }
  __syncthreads();
  const int ig = t >> 6;
  const int cc = t & 63;
  float acc[4] = {};
  for (int k = 0; k < HID; ++k) {
    float w = Wl[k * OUTD + cc];
    f4 xv = *(const f4*)&zT[k * 16 + ig * 4];
    acc[0] = fmaf(xv.x, w, acc[0]);
    acc[1] = fmaf(xv.y, w, acc[1]);
    acc[2] = fmaf(xv.z, w, acc[2]);
    acc[3] = fmaf(xv.w, w, acc[3]);
  }
  float bb = bl[cc];
#pragma unroll
  for (int i = 0; i < 4; ++i)
    op[(size_t)(base + ig * 4 + i) * OUTD + cc] = acc[i] + bb;
}

// ---------------------------------------------------------------------------
extern "C" void kernel_launch(void* const* d_in, const int* in_sizes, int n_in,
                              void* d_out, int out_size, void* d_ws, size_t ws_size,
                              hipStream_t stream)
{
  const float* x_user = (const float*)d_in[0];
  const float* x_item = (const float*)d_in[1];
  const int*   e_ui   = (const int*)d_in[2];
  const int*   e_iu   = (const int*)d_in[3];
  const int*   e_uu   = (const int*)d_in[4];
  const int*   e_ii   = (const int*)d_in[5];
  const float* Wp_u   = (const float*)d_in[6];
  const float* bp_u   = (const float*)d_in[7];
  const float* Wp_i   = (const float*)d_in[8];
  const float* bp_i   = (const float*)d_in[9];
  const float* as_ui  = (const float*)d_in[10];
  const float* ad_ui  = (const float*)d_in[11];
  const float* as_iu  = (const float*)d_in[12];
  const float* ad_iu  = (const float*)d_in[13];
  const float* as_uu  = (const float*)d_in[14];
  const float* ad_uu  = (const float*)d_in[15];
  const float* as_ii  = (const float*)d_in[16];
  const float* ad_ii  = (const float*)d_in[17];
  const float* Wk     = (const float*)d_in[18];
  const float* bk     = (const float*)d_in[19];
  const float* q      = (const float*)d_in[20];
  const float* Wl     = (const float*)d_in[21];
  const float* bl     = (const float*)d_in[22];

  const size_t NH = (size_t)N * HID;
  size_t need = (8 * (size_t)N8 + 8) * 4                     // su,si,sc (f32)
              + (6 * NH + (size_t)HID * HID) * 2             // 4x z, hub, hib, wkT (bf16)
              + ((size_t)8 * N + 4 * (size_t)E + 3 * NBT + 128 + 64) * 4;
  if (ws_size < need) {
    hipMemsetAsync(d_out, 0x7f, (size_t)out_size * sizeof(float), stream);
    return;
  }
  float* su = (float*)d_ws;
  float* si = su + 4 * (size_t)N8;
  float* sc = si + 4 * (size_t)N8;
  ush* zbu0 = (ush*)(sc + 8);
  ush* zbu1 = zbu0 + NH;
  ush* zbi0 = zbu1 + NH;
  ush* zbi1 = zbi0 + NH;
  ush* hub  = zbi1 + NH;
  ush* hib  = hub + NH;
  ush* wkT  = hib + NH;
  int* count  = (int*)(wkT + (size_t)HID * HID);
  int* bcnt   = count + NTOT;
  int* start  = bcnt + NBT;
  int* bstart = start + NTOT;
  int* bcur   = bstart + NBT;
  int* bsum   = bcur + NBT;
  int* csr    = bsum + 128;
  u32* bstage = (u32*)zbu0;     // aliases zbu0 (dead until conv)

  wkt_kernel<<<HID * HID / 256, 256, 0, stream>>>(Wk, wkT);

  proj_kernel<<<N / 16, 256, 0, stream>>>(x_user, Wp_u, bp_u,
                                          ad_iu, as_uu, ad_uu, as_ui, hub, su);
  proj_kernel<<<N / 16, 256, 0, stream>>>(x_item, Wp_i, bp_i,
                                          as_iu, ad_ui, as_ii, ad_ii, hib, si);

  // batched CSR build via per-block multisplit: rel 0=iu, 1=uu, 2=ui, 3=ii
  hipMemsetAsync(bcnt, 0, NBT * sizeof(int), stream);
  histb_kernel<<<4 * NB1, 256, 0, stream>>>(e_iu + E, e_uu + E, e_ui + E, e_ii + E, bcnt);
  bscan_kernel<<<1, 256, 0, stream>>>(bcnt, bstart, bcur);
  scat2_kernel<<<4 * NB1, 256, 0, stream>>>(e_iu, e_iu + E, e_uu, e_uu + E,
                                            e_ui, e_ui + E, e_ii, e_ii + E,
                                            bcur, bstage);
  cntb_kernel<<<NBT, 256, 0, stream>>>(bstage, bstart, bcnt, count);
  scanA_kernel<<<SC_NB, SC_TPB, 0, stream>>>(count, bsum);
  scanB_kernel<<<1, 128, 0, stream>>>(bsum);
  scanC_kernel<<<SC_NB, SC_TPB, 0, stream>>>(count, bsum, start);
  fillb_kernel<<<NBT, 256, 0, stream>>>(bstage, bstart, bcnt, start, csr);

  // all 4 relation convs in ONE launch (z rows: rel*N + dst -> zbu0 base)
  conv_kernel<<<NTOT / 4, 256, 0, stream>>>(hub, hib, su, si, csr, start, count, zbu0);

  // semantic attention: 4 matrices x 391 M-tiles, z read once
  hipMemsetAsync(sc, 0, 4 * sizeof(float), stream);
  semscore_kernel<<<4 * SMT, 512, 0, stream>>>(zbu0, zbu1, zbi0, zbi1, wkT, bk, q, sc);
  attn2_kernel<<<1, 1, 0, stream>>>(sc, 1.0f / (float)N);

  // final linear: both sides in one launch
  final_kernel<<<2 * FING, 256, 0, stream>>>(zbu0, zbu1, zbi0, zbi1, sc + 4, Wl, bl,
                                             (float*)d_out);
}

// Round 12
// 749.181 us; speedup vs baseline: 2.6751x; 1.1396x over previous
//
#include <hip/hip_runtime.h>
#include <math.h>

#define N     50000
#define F_IN  128
#define HID   256
#define E     800000
#define OUTD  64
#define NEG   0.2f
#define N8    (N * 8)
#define NTOT  (4 * N)
#define SMT   ((N + 127) / 128)      // 391 M-tiles per matrix (semscore)
#define FB    ((N + 63) / 64)        // 782 64-row blocks (proj/final)

// hierarchical scan geometry
#define SC_TPB   256
#define SC_PERB  2048
#define SC_NB    ((NTOT + SC_PERB - 1) / SC_PERB)   // 98

// bucket sort geometry
#define BSH   7
#define NBUK  ((N + 127) / 128)      // 391
#define NBT   (4 * NBUK)             // 1564
#define EPB1  8192
#define NB1   ((E + EPB1 - 1) / EPB1) // 98

typedef float4 f4;
typedef unsigned int u32;
typedef unsigned short ush;
typedef float f32x4 __attribute__((ext_vector_type(4)));
typedef short bf16x8 __attribute__((ext_vector_type(8)));

static __device__ __forceinline__ float lrelu(float x) { return x >= 0.f ? x : NEG * x; }
static __device__ __forceinline__ u32 bfr(float x) {
  u32 u = __float_as_uint(x);
  return (u + 0x7fffu + ((u >> 16) & 1u)) >> 16;
}
static __device__ __forceinline__ u32 pk2(float a, float b) { return bfr(a) | (bfr(b) << 16); }
static __device__ __forceinline__ float bf2f(u32 us) { return __uint_as_float(us << 16); }
static __device__ __forceinline__ float tanh_fast(float x) {
  float e = __expf(2.f * x);
  return fmaf(-2.f, __builtin_amdgcn_rcpf(e + 1.f), 1.f);
}

typedef const __attribute__((address_space(1))) unsigned int gu32;
typedef __attribute__((address_space(3))) unsigned int lu32;
static __device__ __forceinline__ void gll16(const void* g, void* l) {
  __builtin_amdgcn_global_load_lds((gu32*)g, (lu32*)l, 16, 0, 0);
}

#define WAITK(nstr)                                          \
  asm volatile("s_waitcnt vmcnt(" nstr ")" ::: "memory");    \
  __builtin_amdgcn_s_barrier();                              \
  asm volatile("" ::: "memory");

// ---------------------------------------------------------------------------
// Weight precompute: bf16 transposes of Wk (256x256), Wp_u/Wp_i (128x256),
// Wl (256x64).  dst[m*K+k] = bf16(src[k*M+m]).
// ---------------------------------------------------------------------------
__global__ void tran_kernel(const float* __restrict__ Wk,
                            const float* __restrict__ Wpu,
                            const float* __restrict__ Wpi,
                            const float* __restrict__ Wl,
                            ush* __restrict__ wkT, ush* __restrict__ wpTu,
                            ush* __restrict__ wpTi, ush* __restrict__ wlT)
{
  int idx = blockIdx.x * 256 + threadIdx.x;
  const float* src; ush* dst; int K, M, li;
  if (idx < 65536)       { src = Wk;  dst = wkT;  K = 256; M = 256; li = idx; }
  else if (idx < 98304)  { src = Wpu; dst = wpTu; K = 128; M = 256; li = idx - 65536; }
  else if (idx < 131072) { src = Wpi; dst = wpTi; K = 128; M = 256; li = idx - 98304; }
  else                   { src = Wl;  dst = wlT;  K = 256; M = 64;  li = idx - 131072; }
  int m = li / K, k = li % K;
  dst[li] = (ush)bfr(src[k * M + m]);
}

// ---------------------------------------------------------------------------
// Projection v2: h = x @ Wp + b via bf16 MFMA.  64 rows/block, 4 waves, each
// wave owns 16 rows x 256 cols (16 n-tiles, K=128 in 4 steps).  A-frags
// loaded from global x (fp32->bf16 pack, 16 VGPR resident), B-frags from
// L2-hot wpT.  D layout: col=lane&15, row=(lane>>4)*4+i (verified mapping).
// ---------------------------------------------------------------------------
__global__ __launch_bounds__(256) void proj_kernel(
    const float* __restrict__ x, const ush* __restrict__ wpT,
    const float* __restrict__ b, ush* __restrict__ hb)
{
  const int t = threadIdx.x;
  const int w = t >> 6, l = t & 63;
  const int lrow = l & 15, kgrp = l >> 4;
  const int base = blockIdx.x * 64;
  int arow = base + w * 16 + lrow;
  if (arow >= N) arow = N - 1;

  bf16x8 Af[4];
#pragma unroll
  for (int ks = 0; ks < 4; ++ks) {
    const float* px = &x[(size_t)arow * F_IN + ks * 32 + kgrp * 8];
    f4 v0 = *(const f4*)px;
    f4 v1 = *(const f4*)(px + 4);
    union { u32 u[4]; bf16x8 v; } c;
    c.u[0] = pk2(v0.x, v0.y); c.u[1] = pk2(v0.z, v0.w);
    c.u[2] = pk2(v1.x, v1.y); c.u[3] = pk2(v1.z, v1.w);
    Af[ks] = c.v;
  }

#pragma unroll
  for (int nt = 0; nt < 16; ++nt) {
    const int col = nt * 16 + lrow;
    f32x4 acc = {0.f, 0.f, 0.f, 0.f};
#pragma unroll
    for (int ks = 0; ks < 4; ++ks) {
      bf16x8 Bf = *(const bf16x8*)&wpT[(size_t)col * F_IN + ks * 32 + kgrp * 8];
      acc = __builtin_amdgcn_mfma_f32_16x16x32_bf16(Af[ks], Bf, acc, 0, 0, 0);
    }
    const float bb = b[col];
#pragma unroll
    for (int i = 0; i < 4; ++i) {
      int gr = base + w * 16 + kgrp * 4 + i;
      if (gr < N) hb[(size_t)gr * HID + col] = (ush)bfr(acc[i] + bb);
    }
  }
}

// ---------------------------------------------------------------------------
// Node scores from bf16 h: s_k[n,h] = sum_d h[n,h*32+d]*a_k[h*32+d].
// One wave per node; 8-lane-group shuffle reduce per head.
// ---------------------------------------------------------------------------
__global__ __launch_bounds__(256) void nodescore_kernel(
    const ush* __restrict__ hb,
    const float* __restrict__ a0, const float* __restrict__ a1,
    const float* __restrict__ a2, const float* __restrict__ a3,
    float* __restrict__ sdst)
{
  const int node = (blockIdx.x * 256 + threadIdx.x) >> 6;
  const int lane = threadIdx.x & 63;
  ushort4 hv = *(const ushort4*)&hb[(size_t)node * HID + lane * 4];
  const float h0 = bf2f(hv.x), h1 = bf2f(hv.y), h2 = bf2f(hv.z), h3 = bf2f(hv.w);
  const int head = lane >> 3;
  const float* av[4] = {a0, a1, a2, a3};
#pragma unroll
  for (int k = 0; k < 4; ++k) {
    f4 a = *(const f4*)&av[k][lane * 4];
    float p = h0 * a.x + h1 * a.y + h2 * a.z + h3 * a.w;
    p += __shfl_xor(p, 1);
    p += __shfl_xor(p, 2);
    p += __shfl_xor(p, 4);
    if ((lane & 7) == 0)
      sdst[(size_t)k * N8 + (size_t)node * 8 + head] = p;
  }
}

// ---------------------------------------------------------------------------
// CSR build, per-block multisplit (unchanged)
// ---------------------------------------------------------------------------
__global__ __launch_bounds__(256) void histb_kernel(
    const int* __restrict__ d0, const int* __restrict__ d1,
    const int* __restrict__ d2, const int* __restrict__ d3,
    int* __restrict__ bcnt)
{
  __shared__ int lh[NBUK];
  const int rel = blockIdx.x / NB1;
  const int blk = blockIdx.x % NB1;
  for (int j = threadIdx.x; j < NBUK; j += 256) lh[j] = 0;
  __syncthreads();
  const int* dp = rel == 0 ? d0 : rel == 1 ? d1 : rel == 2 ? d2 : d3;
  const int base = blk * EPB1;
#pragma unroll 4
  for (int k = 0; k < EPB1 / 256; ++k) {
    int i = base + k * 256 + threadIdx.x;
    if (i < E) atomicAdd(&lh[dp[i] >> BSH], 1);
  }
  __syncthreads();
  for (int j = threadIdx.x; j < NBUK; j += 256)
    if (lh[j]) atomicAdd(&bcnt[rel * NBUK + j], lh[j]);
}

__global__ __launch_bounds__(256) void bscan_kernel(
    const int* __restrict__ bcnt, int* __restrict__ bstart, int* __restrict__ bcur)
{
  __shared__ int part[256];
  const int t = threadIdx.x;
  const int chunk = (NBT + 255) / 256;   // 7
  const int b = t * chunk;
  const int e = min(NBT, b + chunk);
  int s = 0;
  for (int i = b; i < e; ++i) s += bcnt[i];
  part[t] = s;
  __syncthreads();
  for (int off = 1; off < 256; off <<= 1) {
    int u = (t >= off) ? part[t - off] : 0;
    __syncthreads();
    part[t] += u;
    __syncthreads();
  }
  int run = part[t] - s;
  for (int i = b; i < e; ++i) {
    bstart[i] = run;
    bcur[i] = run;
    run += bcnt[i];
  }
}

__global__ __launch_bounds__(256) void scat2_kernel(
    const int* __restrict__ s0, const int* __restrict__ d0,
    const int* __restrict__ s1, const int* __restrict__ d1,
    const int* __restrict__ s2, const int* __restrict__ d2,
    const int* __restrict__ s3, const int* __restrict__ d3,
    int* __restrict__ bcur, u32* __restrict__ bstage)
{
  __shared__ int lh[NBUK];
  const int rel = blockIdx.x / NB1;
  const int blk = blockIdx.x % NB1;
  const int* sp = rel == 0 ? s0 : rel == 1 ? s1 : rel == 2 ? s2 : s3;
  const int* dp = rel == 0 ? d0 : rel == 1 ? d1 : rel == 2 ? d2 : d3;
  for (int j = threadIdx.x; j < NBUK; j += 256) lh[j] = 0;
  __syncthreads();
  const int base = blk * EPB1;
#pragma unroll 4
  for (int k = 0; k < EPB1 / 256; ++k) {
    int i = base + k * 256 + threadIdx.x;
    if (i < E) atomicAdd(&lh[dp[i] >> BSH], 1);
  }
  __syncthreads();
  for (int j = threadIdx.x; j < NBUK; j += 256) {
    int c = lh[j];
    lh[j] = c ? atomicAdd(&bcur[rel * NBUK + j], c) : 0;
  }
  __syncthreads();
#pragma unroll 4
  for (int k = 0; k < EPB1 / 256; ++k) {
    int i = base + k * 256 + threadIdx.x;
    if (i < E) {
      int dst = dp[i], src = sp[i];
      int pos = atomicAdd(&lh[dst >> BSH], 1);   // LDS atomic (fast)
      bstage[pos] = ((u32)dst << 16) | (u32)src;
    }
  }
}

__global__ __launch_bounds__(256) void cntb_kernel(
    const u32* __restrict__ bstage, const int* __restrict__ bstart,
    const int* __restrict__ bcnt, int* __restrict__ count)
{
  __shared__ int lcnt[128];
  const int bb = blockIdx.x;
  const int rel = bb / NBUK, b = bb % NBUK;
  if (threadIdx.x < 128) lcnt[threadIdx.x] = 0;
  __syncthreads();
  const int rb = bstart[bb];
  const int cnt = bcnt[bb];
  for (int k = threadIdx.x; k < cnt; k += 256)
    atomicAdd(&lcnt[(bstage[rb + k] >> 16) & 127], 1);
  __syncthreads();
  const int fb = rel * N + b * 128;
  const int lim = min(128, N - b * 128);
  if (threadIdx.x < lim) count[fb + threadIdx.x] = lcnt[threadIdx.x];
}

__global__ __launch_bounds__(SC_TPB) void scanA_kernel(
    const int* __restrict__ count, int* __restrict__ bsum)
{
  __shared__ int red[4];
  const int t = threadIdx.x;
  const int base = blockIdx.x * SC_PERB + t * 8;
  int s = 0;
  if (base + 8 <= NTOT) {
    int4 a = *(const int4*)&count[base];
    int4 b = *(const int4*)&count[base + 4];
    s = a.x + a.y + a.z + a.w + b.x + b.y + b.z + b.w;
  } else {
    for (int i = 0; i < 8; ++i) { int idx = base + i; if (idx < NTOT) s += count[idx]; }
  }
#pragma unroll
  for (int off = 1; off < 64; off <<= 1) s += __shfl_xor(s, off);
  if ((t & 63) == 0) red[t >> 6] = s;
  __syncthreads();
  if (t == 0) bsum[blockIdx.x] = red[0] + red[1] + red[2] + red[3];
}

__global__ __launch_bounds__(128) void scanB_kernel(int* __restrict__ bsum)
{
  __shared__ int tmp[128];
  const int t = threadIdx.x;
  int v = (t < SC_NB) ? bsum[t] : 0;
  tmp[t] = v;
  __syncthreads();
  for (int off = 1; off < 128; off <<= 1) {
    int u = (t >= off) ? tmp[t - off] : 0;
    __syncthreads();
    tmp[t] += u;
    __syncthreads();
  }
  if (t < SC_NB) bsum[t] = tmp[t] - v;  // exclusive
}

__global__ __launch_bounds__(SC_TPB) void scanC_kernel(
    const int* __restrict__ count, const int* __restrict__ bsum,
    int* __restrict__ start)
{
  __shared__ int ts[SC_TPB];
  const int t = threadIdx.x;
  const int base = blockIdx.x * SC_PERB + t * 8;
  int c[8];
  int s = 0;
#pragma unroll
  for (int i = 0; i < 8; ++i) {
    int idx = base + i;
    c[i] = (idx < NTOT) ? count[idx] : 0;
    s += c[i];
  }
  ts[t] = s;
  __syncthreads();
  for (int off = 1; off < SC_TPB; off <<= 1) {
    int u = (t >= off) ? ts[t - off] : 0;
    __syncthreads();
    ts[t] += u;
    __syncthreads();
  }
  int run = ts[t] - s + bsum[blockIdx.x];
#pragma unroll
  for (int i = 0; i < 8; ++i) {
    int idx = base + i;
    if (idx < NTOT) {
      start[idx] = run;
      run += c[i];
    }
  }
}

__global__ __launch_bounds__(256) void fillb_kernel(
    const u32* __restrict__ bstage, const int* __restrict__ bstart,
    const int* __restrict__ bcnt, const int* __restrict__ start,
    int* __restrict__ csr)
{
  __shared__ int lcur[128];
  const int bb = blockIdx.x;           // rel*NBUK + b
  const int rel = bb / NBUK, b = bb % NBUK;
  const int fb = rel * N + b * 128;
  const int lim = min(128, N - b * 128);
  if (threadIdx.x < lim) lcur[threadIdx.x] = start[fb + threadIdx.x];
  __syncthreads();
  const int rb = bstart[bb];
  const int cnt = bcnt[bb];
  for (int k = threadIdx.x; k < cnt; k += 256) {
    u32 pk = bstage[rb + k];
    int ldst = (pk >> 16) & 127;
    int pos = atomicAdd(&lcur[ldst], 1);
    csr[pos] = (int)(pk & 0xffffu);
  }
}

// ---------------------------------------------------------------------------
// Relation conv (R11 single-pass, 8-edge batches) — near its TCC-BW floor.
// ---------------------------------------------------------------------------
#define CONV_EDGE(sx)                                                     \
  {                                                                       \
    float al = __expf(lrelu(lg##sx + sdv2));                              \
    den += al;                                                            \
    a0 = fmaf(al, bf2f(v##sx.x), a0); a1 = fmaf(al, bf2f(v##sx.y), a1);   \
    a2 = fmaf(al, bf2f(v##sx.z), a2); a3 = fmaf(al, bf2f(v##sx.w), a3);   \
  }

__global__ __launch_bounds__(256) void conv_kernel(
    const ush* __restrict__ hub, const ush* __restrict__ hib,
    const float* __restrict__ su, const float* __restrict__ si,
    const int* __restrict__ csr,
    const int* __restrict__ start, const int* __restrict__ count,
    ush* __restrict__ zall)
{
  const int rel = blockIdx.x / (N / 4);
  const int lb  = blockIdx.x % (N / 4);
  const int dst = lb * 4 + (threadIdx.x >> 6);
  const int lane = threadIdx.x & 63;
  const ush* xsb = (rel == 0 || rel == 3) ? hib : hub;
  const float* ss = rel == 0 ? si : rel == 1 ? su + N8 :
                    rel == 2 ? su + 3 * (size_t)N8 : si + 2 * (size_t)N8;
  const float* sd = rel == 0 ? su : rel == 1 ? su + 2 * (size_t)N8 :
                    rel == 2 ? si + N8 : si + 3 * (size_t)N8;
  const int grow = rel * N + dst;
  const int e0 = start[grow];
  const int ne = count[grow];

  const int h2 = lane >> 3;
  const float sdv2 = sd[dst * 8 + h2];

  float den = 0.f;
  float a0 = 0.f, a1 = 0.f, a2 = 0.f, a3 = 0.f;
  int j = 0;
  for (; j + 8 <= ne; j += 8) {
    int s0_ = csr[e0 + j + 0], s1_ = csr[e0 + j + 1];
    int s2_ = csr[e0 + j + 2], s3_ = csr[e0 + j + 3];
    int s4_ = csr[e0 + j + 4], s5_ = csr[e0 + j + 5];
    int s6_ = csr[e0 + j + 6], s7_ = csr[e0 + j + 7];
    float lg0 = ss[s0_ * 8 + h2], lg1 = ss[s1_ * 8 + h2];
    float lg2 = ss[s2_ * 8 + h2], lg3 = ss[s3_ * 8 + h2];
    float lg4 = ss[s4_ * 8 + h2], lg5 = ss[s5_ * 8 + h2];
    float lg6 = ss[s6_ * 8 + h2], lg7 = ss[s7_ * 8 + h2];
    ushort4 v0 = *(const ushort4*)&xsb[(size_t)s0_ * HID + lane * 4];
    ushort4 v1 = *(const ushort4*)&xsb[(size_t)s1_ * HID + lane * 4];
    ushort4 v2 = *(const ushort4*)&xsb[(size_t)s2_ * HID + lane * 4];
    ushort4 v3 = *(const ushort4*)&xsb[(size_t)s3_ * HID + lane * 4];
    ushort4 v4 = *(const ushort4*)&xsb[(size_t)s4_ * HID + lane * 4];
    ushort4 v5 = *(const ushort4*)&xsb[(size_t)s5_ * HID + lane * 4];
    ushort4 v6 = *(const ushort4*)&xsb[(size_t)s6_ * HID + lane * 4];
    ushort4 v7 = *(const ushort4*)&xsb[(size_t)s7_ * HID + lane * 4];
    CONV_EDGE(0) CONV_EDGE(1) CONV_EDGE(2) CONV_EDGE(3)
    CONV_EDGE(4) CONV_EDGE(5) CONV_EDGE(6) CONV_EDGE(7)
  }
  for (; j + 2 <= ne; j += 2) {
    int s0_ = csr[e0 + j + 0], s1_ = csr[e0 + j + 1];
    float lg0 = ss[s0_ * 8 + h2], lg1 = ss[s1_ * 8 + h2];
    ushort4 v0 = *(const ushort4*)&xsb[(size_t)s0_ * HID + lane * 4];
    ushort4 v1 = *(const ushort4*)&xsb[(size_t)s1_ * HID + lane * 4];
    CONV_EDGE(0) CONV_EDGE(1)
  }
  if (j < ne) {
    int s0_ = csr[e0 + j];
    float lg0 = ss[s0_ * 8 + h2];
    ushort4 v0 = *(const ushort4*)&xsb[(size_t)s0_ * HID + lane * 4];
    CONV_EDGE(0)
  }
  const float inv = 1.f / (den + 1e-16f);
  ushort4 o;
  o.x = (ush)bfr(fmaxf(a0 * inv, 0.f));
  o.y = (ush)bfr(fmaxf(a1 * inv, 0.f));
  o.z = (ush)bfr(fmaxf(a2 * inv, 0.f));
  o.w = (ush)bfr(fmaxf(a3 * inv, 0.f));
  *(ushort4*)&zall[(size_t)grow * HID + lane * 4] = o;
}

// ---------------------------------------------------------------------------
// Semantic scores v5 (R10, unchanged)
// ---------------------------------------------------------------------------
__global__ __launch_bounds__(512, 2) void semscore_kernel(
    const ush* __restrict__ zbu0, const ush* __restrict__ zbu1,
    const ush* __restrict__ zbi0, const ush* __restrict__ zbi1,
    const ush* __restrict__ wkT, const float* __restrict__ bk,
    const float* __restrict__ q, float* __restrict__ score)
{
  __shared__ ush As[4][128 * 64];
  const int bid = blockIdx.x;
  const int mat = bid / SMT;
  const int mt  = bid % SMT;
  const ush* zsrc = mat == 0 ? zbu0 : mat == 1 ? zbu1 : mat == 2 ? zbi0 : zbi1;
  const int Mbase = mt * 128;
  const int t = threadIdx.x;
  const int w = t >> 6, l = t & 63;
  const int lrow = l & 15, kgrp = l >> 4;
  const int wr = w >> 2, wc = w & 3;

  auto stage = [&](int kc) {
#pragma unroll
    for (int i = 0; i < 2; ++i) {
      int q16 = i * 512 + t;
      int r = q16 >> 3;
      int c = (q16 & 7) ^ (r & 7);
      int gr = Mbase + r; if (gr >= N) gr = N - 1;
      gll16(&zsrc[(size_t)gr * HID + kc * 64 + c * 8],
            &As[kc][(i * 512 + w * 64) * 8]);
    }
  };

  f32x4 acc[4][4];
  const f32x4 zz = {0.f, 0.f, 0.f, 0.f};
#pragma unroll
  for (int m = 0; m < 4; ++m)
#pragma unroll
    for (int n = 0; n < 4; ++n) acc[m][n] = zz;

  stage(0); stage(1); stage(2); stage(3);

  auto compute = [&](int kc) {
    bf16x8 Bf[4][2];
#pragma unroll
    for (int n = 0; n < 4; ++n)
#pragma unroll
      for (int ks = 0; ks < 2; ++ks)
        Bf[n][ks] = *(const bf16x8*)&wkT[(size_t)(wc * 64 + n * 16 + lrow) * HID
                                         + kc * 64 + ks * 32 + kgrp * 8];
#pragma unroll
    for (int m = 0; m < 4; ++m) {
      const int mrow = wr * 64 + m * 16 + lrow;
      bf16x8 Af[2];
#pragma unroll
      for (int ks = 0; ks < 2; ++ks) {
        int ch = (ks * 4 + kgrp) ^ (mrow & 7);
        Af[ks] = *(const bf16x8*)&As[kc][mrow * 64 + ch * 8];
      }
#pragma unroll
      for (int n = 0; n < 4; ++n)
#pragma unroll
        for (int ks = 0; ks < 2; ++ks)
          acc[m][n] = __builtin_amdgcn_mfma_f32_16x16x32_bf16(Af[ks], Bf[n][ks],
                                                              acc[m][n], 0, 0, 0);
    }
  };

  WAITK("6"); compute(0);
  WAITK("4"); compute(1);
  WAITK("2"); compute(2);
  WAITK("0"); compute(3);

  float s = 0.f;
#pragma unroll
  for (int m = 0; m < 4; ++m) {
    const int gr0 = Mbase + wr * 64 + m * 16 + kgrp * 4;
#pragma unroll
    for (int n = 0; n < 4; ++n) {
      const int col = wc * 64 + n * 16 + lrow;
      const float bkv = bk[col], qv = q[col];
#pragma unroll
      for (int i = 0; i < 4; ++i)
        if (gr0 + i < N) s += tanh_fast(acc[m][n][i] + bkv) * qv;
    }
  }
#pragma unroll
  for (int off = 1; off < 64; off <<= 1) s += __shfl_xor(s, off);
  if (l == 0) atomicAdd(&score[mat], s);
}

__global__ void attn2_kernel(float* __restrict__ score, float inv_n)
{
#pragma unroll
  for (int s = 0; s < 2; ++s) {
    float s0 = score[2 * s] * inv_n, s1 = score[2 * s + 1] * inv_n;
    float m = fmaxf(s0, s1);
    float e0 = __expf(s0 - m), e1 = __expf(s1 - m);
    float d = e0 + e1;
    score[4 + 2 * s] = e0 / d;
    score[5 + 2 * s] = e1 / d;
  }
}

// ---------------------------------------------------------------------------
// Final v2: out = (a0*z0 + a1*z1) @ Wl + bl via bf16 MFMA.  64 rows/block,
// both sides in one launch.  A = zmix packed to bf16 in regs (32 VGPR);
// B from L2-hot wlT.
// ---------------------------------------------------------------------------
__global__ __launch_bounds__(256) void final_kernel(
    const ush* __restrict__ zbu0, const ush* __restrict__ zbu1,
    const ush* __restrict__ zbi0, const ush* __restrict__ zbi1,
    const float* __restrict__ attn, const ush* __restrict__ wlT,
    const float* __restrict__ bl, float* __restrict__ out)
{
  const int bid = blockIdx.x;
  const int side = bid >= FB;
  const ush* z0 = side ? zbi0 : zbu0;
  const ush* z1 = side ? zbi1 : zbu1;
  float* op = out + (size_t)side * N * OUTD;
  const float a0 = attn[side * 2], a1 = attn[side * 2 + 1];
  const int t = threadIdx.x;
  const int w = t >> 6, l = t & 63;
  const int lrow = l & 15, kgrp = l >> 4;
  const int base = (bid - side * FB) * 64;
  int arow = base + w * 16 + lrow;
  if (arow >= N) arow = N - 1;

  bf16x8 Af[8];
#pragma unroll
  for (int ks = 0; ks < 8; ++ks) {
    const ush* p0 = &z0[(size_t)arow * HID + ks * 32 + kgrp * 8];
    const ush* p1 = &z1[(size_t)arow * HID + ks * 32 + kgrp * 8];
    ushort4 u0a = *(const ushort4*)p0, u0b = *(const ushort4*)(p0 + 4);
    ushort4 u1a = *(const ushort4*)p1, u1b = *(const ushort4*)(p1 + 4);
    union { u32 u[4]; bf16x8 v; } c;
    c.u[0] = pk2(a0 * bf2f(u0a.x) + a1 * bf2f(u1a.x),
                 a0 * bf2f(u0a.y) + a1 * bf2f(u1a.y));
    c.u[1] = pk2(a0 * bf2f(u0a.z) + a1 * bf2f(u1a.z),
                 a0 * bf2f(u0a.w) + a1 * bf2f(u1a.w));
    c.u[2] = pk2(a0 * bf2f(u0b.x) + a1 * bf2f(u1b.x),
                 a0 * bf2f(u0b.y) + a1 * bf2f(u1b.y));
    c.u[3] = pk2(a0 * bf2f(u0b.z) + a1 * bf2f(u1b.z),
                 a0 * bf2f(u0b.w) + a1 * bf2f(u1b.w));
    Af[ks] = c.v;
  }

#pragma unroll
  for (int nt = 0; nt < 4; ++nt) {
    const int col = nt * 16 + lrow;
    f32x4 acc = {0.f, 0.f, 0.f, 0.f};
#pragma unroll
    for (int ks = 0; ks < 8; ++ks) {
      bf16x8 Bf = *(const bf16x8*)&wlT[(size_t)col * HID + ks * 32 + kgrp * 8];
      acc = __builtin_amdgcn_mfma_f32_16x16x32_bf16(Af[ks], Bf, acc, 0, 0, 0);
    }
    const float bb = bl[col];
#pragma unroll
    for (int i = 0; i < 4; ++i) {
      int gr = base + w * 16 + kgrp * 4 + i;
      if (gr < N) op[(size_t)gr * OUTD + col] = acc[i] + bb;
    }
  }
}

// ---------------------------------------------------------------------------
extern "C" void kernel_launch(void* const* d_in, const int* in_sizes, int n_in,
                              void* d_out, int out_size, void* d_ws, size_t ws_size,
                              hipStream_t stream)
{
  const float* x_user = (const float*)d_in[0];
  const float* x_item = (const float*)d_in[1];
  const int*   e_ui   = (const int*)d_in[2];
  const int*   e_iu   = (const int*)d_in[3];
  const int*   e_uu   = (const int*)d_in[4];
  const int*   e_ii   = (const int*)d_in[5];
  const float* Wp_u   = (const float*)d_in[6];
  const float* bp_u   = (const float*)d_in[7];
  const float* Wp_i   = (const float*)d_in[8];
  const float* bp_i   = (const float*)d_in[9];
  const float* as_ui  = (const float*)d_in[10];
  const float* ad_ui  = (const float*)d_in[11];
  const float* as_iu  = (const float*)d_in[12];
  const float* ad_iu  = (const float*)d_in[13];
  const float* as_uu  = (const float*)d_in[14];
  const float* ad_uu  = (const float*)d_in[15];
  const float* as_ii  = (const float*)d_in[16];
  const float* ad_ii  = (const float*)d_in[17];
  const float* Wk     = (const float*)d_in[18];
  const float* bk     = (const float*)d_in[19];
  const float* q      = (const float*)d_in[20];
  const float* Wl     = (const float*)d_in[21];
  const float* bl     = (const float*)d_in[22];

  const size_t NH = (size_t)N * HID;
  const size_t WT = 65536 + 2 * 32768 + 16384;   // wkT + wpTu + wpTi + wlT (ush)
  size_t need = (8 * (size_t)N8 + 8) * 4                     // su,si,sc (f32)
              + (6 * NH + WT) * 2                            // 4x z, hub, hib, weights
              + ((size_t)8 * N + 4 * (size_t)E + 3 * NBT + 128 + 64) * 4;
  if (ws_size < need) {
    hipMemsetAsync(d_out, 0x7f, (size_t)out_size * sizeof(float), stream);
    return;
  }
  float* su = (float*)d_ws;
  float* si = su + 4 * (size_t)N8;
  float* sc = si + 4 * (size_t)N8;
  ush* zbu0 = (ush*)(sc + 8);
  ush* zbu1 = zbu0 + NH;
  ush* zbi0 = zbu1 + NH;
  ush* zbi1 = zbi0 + NH;
  ush* hub  = zbi1 + NH;
  ush* hib  = hub + NH;
  ush* wkT  = hib + NH;
  ush* wpTu = wkT + 65536;
  ush* wpTi = wpTu + 32768;
  ush* wlT  = wpTi + 32768;
  int* count  = (int*)(wlT + 16384);
  int* bcnt   = count + NTOT;
  int* start  = bcnt + NBT;
  int* bstart = start + NTOT;
  int* bcur   = bstart + NBT;
  int* bsum   = bcur + NBT;
  int* csr    = bsum + 128;
  u32* bstage = (u32*)zbu0;     // aliases zbu0 (dead until conv)

  // weight transposes (bf16)
  tran_kernel<<<576, 256, 0, stream>>>(Wk, Wp_u, Wp_i, Wl, wkT, wpTu, wpTi, wlT);

  // projections (MFMA) + node scores
  proj_kernel<<<FB, 256, 0, stream>>>(x_user, wpTu, bp_u, hub);
  proj_kernel<<<FB, 256, 0, stream>>>(x_item, wpTi, bp_i, hib);
  nodescore_kernel<<<N / 4, 256, 0, stream>>>(hub, ad_iu, as_uu, ad_uu, as_ui, su);
  nodescore_kernel<<<N / 4, 256, 0, stream>>>(hib, as_iu, ad_ui, as_ii, ad_ii, si);

  // batched CSR build via per-block multisplit: rel 0=iu, 1=uu, 2=ui, 3=ii
  hipMemsetAsync(bcnt, 0, NBT * sizeof(int), stream);
  histb_kernel<<<4 * NB1, 256, 0, stream>>>(e_iu + E, e_uu + E, e_ui + E, e_ii + E, bcnt);
  bscan_kernel<<<1, 256, 0, stream>>>(bcnt, bstart, bcur);
  scat2_kernel<<<4 * NB1, 256, 0, stream>>>(e_iu, e_iu + E, e_uu, e_uu + E,
                                            e_ui, e_ui + E, e_ii, e_ii + E,
                                            bcur, bstage);
  cntb_kernel<<<NBT, 256, 0, stream>>>(bstage, bstart, bcnt, count);
  scanA_kernel<<<SC_NB, SC_TPB, 0, stream>>>(count, bsum);
  scanB_kernel<<<1, 128, 0, stream>>>(bsum);
  scanC_kernel<<<SC_NB, SC_TPB, 0, stream>>>(count, bsum, start);
  fillb_kernel<<<NBT, 256, 0, stream>>>(bstage, bstart, bcnt, start, csr);

  // all 4 relation convs in one launch
  conv_kernel<<<NTOT / 4, 256, 0, stream>>>(hub, hib, su, si, csr, start, count, zbu0);

  // semantic attention
  hipMemsetAsync(sc, 0, 4 * sizeof(float), stream);
  semscore_kernel<<<4 * SMT, 512, 0, stream>>>(zbu0, zbu1, zbi0, zbi1, wkT, bk, q, sc);
  attn2_kernel<<<1, 1, 0, stream>>>(sc, 1.0f / (float)N);

  // final linear (MFMA), both sides
  final_kernel<<<2 * FB, 256, 0, stream>>>(zbu0, zbu1, zbi0, zbi1, sc + 4, wlT, bl,
                                           (float*)d_out);
}

// Round 13
// 711.119 us; speedup vs baseline: 2.8183x; 1.0535x over previous
//
#include <hip/hip_runtime.h>
#include <math.h>

#define N     50000
#define F_IN  128
#define HID   256
#define E     800000
#define OUTD  64
#define NEG   0.2f
#define N8    (N * 8)
#define NTOT  (4 * N)
#define SMT   ((N + 127) / 128)      // 391 M-tiles per matrix (semscore)
#define FB    ((N + 63) / 64)        // 782 64-row blocks (proj/final)

// bucket sort geometry (fixed-capacity buckets: no global scan needed)
#define BSH   7
#define NBUK  ((N + 127) / 128)      // 391
#define NBT   (4 * NBUK)             // 1564
#define BCAP  2560                   // bucket capacity; Poisson(2048), 11 sigma headroom
#define EPB1  8192
#define NB1   ((E + EPB1 - 1) / EPB1) // 98

typedef float4 f4;
typedef unsigned int u32;
typedef unsigned short ush;
typedef float f32x4 __attribute__((ext_vector_type(4)));
typedef short bf16x8 __attribute__((ext_vector_type(8)));

static __device__ __forceinline__ float lrelu(float x) { return x >= 0.f ? x : NEG * x; }
static __device__ __forceinline__ u32 bfr(float x) {
  u32 u = __float_as_uint(x);
  return (u + 0x7fffu + ((u >> 16) & 1u)) >> 16;
}
static __device__ __forceinline__ u32 pk2(float a, float b) { return bfr(a) | (bfr(b) << 16); }
static __device__ __forceinline__ float bf2f(u32 us) { return __uint_as_float(us << 16); }
static __device__ __forceinline__ float tanh_fast(float x) {
  float e = __expf(2.f * x);
  return fmaf(-2.f, __builtin_amdgcn_rcpf(e + 1.f), 1.f);
}

typedef const __attribute__((address_space(1))) unsigned int gu32;
typedef __attribute__((address_space(3))) unsigned int lu32;
static __device__ __forceinline__ void gll16(const void* g, void* l) {
  __builtin_amdgcn_global_load_lds((gu32*)g, (lu32*)l, 16, 0, 0);
}

#define WAITK(nstr)                                          \
  asm volatile("s_waitcnt vmcnt(" nstr ")" ::: "memory");    \
  __builtin_amdgcn_s_barrier();                              \
  asm volatile("" ::: "memory");

// ---------------------------------------------------------------------------
// Weight precompute (bf16 transposes) + zero-init of bcnt and sc (folds two
// hipMemsetAsync and keeps the CSR cursor ready).
// ---------------------------------------------------------------------------
__global__ void tran_kernel(const float* __restrict__ Wk,
                            const float* __restrict__ Wpu,
                            const float* __restrict__ Wpi,
                            const float* __restrict__ Wl,
                            ush* __restrict__ wkT, ush* __restrict__ wpTu,
                            ush* __restrict__ wpTi, ush* __restrict__ wlT,
                            int* __restrict__ bcnt, float* __restrict__ sc)
{
  int idx = blockIdx.x * 256 + threadIdx.x;
  if (idx < NBT) bcnt[idx] = 0;
  if (idx >= NBT && idx < NBT + 8) sc[idx - NBT] = 0.f;
  const float* src; ush* dst; int K, M, li;
  if (idx < 65536)       { src = Wk;  dst = wkT;  K = 256; M = 256; li = idx; }
  else if (idx < 98304)  { src = Wpu; dst = wpTu; K = 128; M = 256; li = idx - 65536; }
  else if (idx < 131072) { src = Wpi; dst = wpTi; K = 128; M = 256; li = idx - 98304; }
  else                   { src = Wl;  dst = wlT;  K = 256; M = 64;  li = idx - 131072; }
  int m = li / K, k = li % K;
  dst[li] = (ush)bfr(src[k * M + m]);
}

// ---------------------------------------------------------------------------
// Projection: h = x @ Wp + b via bf16 MFMA (R12-verified). Both node types
// in one launch (side = bid >= FB).
// ---------------------------------------------------------------------------
__global__ __launch_bounds__(256) void proj_kernel(
    const float* __restrict__ xu, const float* __restrict__ xi,
    const ush* __restrict__ wpTu, const ush* __restrict__ wpTi,
    const float* __restrict__ bu, const float* __restrict__ bi,
    ush* __restrict__ hu, ush* __restrict__ hi)
{
  const int bid = blockIdx.x;
  const int side = bid >= FB;
  const float* x = side ? xi : xu;
  const ush* wpT = side ? wpTi : wpTu;
  const float* b = side ? bi : bu;
  ush* hb = side ? hi : hu;
  const int t = threadIdx.x;
  const int w = t >> 6, l = t & 63;
  const int lrow = l & 15, kgrp = l >> 4;
  const int base = (bid - side * FB) * 64;
  int arow = base + w * 16 + lrow;
  if (arow >= N) arow = N - 1;

  bf16x8 Af[4];
#pragma unroll
  for (int ks = 0; ks < 4; ++ks) {
    const float* px = &x[(size_t)arow * F_IN + ks * 32 + kgrp * 8];
    f4 v0 = *(const f4*)px;
    f4 v1 = *(const f4*)(px + 4);
    union { u32 u[4]; bf16x8 v; } c;
    c.u[0] = pk2(v0.x, v0.y); c.u[1] = pk2(v0.z, v0.w);
    c.u[2] = pk2(v1.x, v1.y); c.u[3] = pk2(v1.z, v1.w);
    Af[ks] = c.v;
  }

#pragma unroll
  for (int nt = 0; nt < 16; ++nt) {
    const int col = nt * 16 + lrow;
    f32x4 acc = {0.f, 0.f, 0.f, 0.f};
#pragma unroll
    for (int ks = 0; ks < 4; ++ks) {
      bf16x8 Bf = *(const bf16x8*)&wpT[(size_t)col * F_IN + ks * 32 + kgrp * 8];
      acc = __builtin_amdgcn_mfma_f32_16x16x32_bf16(Af[ks], Bf, acc, 0, 0, 0);
    }
    const float bb = b[col];
#pragma unroll
    for (int i = 0; i < 4; ++i) {
      int gr = base + w * 16 + kgrp * 4 + i;
      if (gr < N) hb[(size_t)gr * HID + col] = (ush)bfr(acc[i] + bb);
    }
  }
}

// ---------------------------------------------------------------------------
// Node scores from bf16 h, both node types one launch.
// ---------------------------------------------------------------------------
__global__ __launch_bounds__(256) void nodescore_kernel(
    const ush* __restrict__ hu, const ush* __restrict__ hi,
    const float* __restrict__ au0, const float* __restrict__ au1,
    const float* __restrict__ au2, const float* __restrict__ au3,
    const float* __restrict__ ai0, const float* __restrict__ ai1,
    const float* __restrict__ ai2, const float* __restrict__ ai3,
    float* __restrict__ su, float* __restrict__ si)
{
  const int bid = blockIdx.x;
  const int side = bid >= (N / 4);
  const ush* hb = side ? hi : hu;
  float* sdst = side ? si : su;
  const int node = ((bid - side * (N / 4)) * 256 + threadIdx.x) >> 6;
  const int lane = threadIdx.x & 63;
  ushort4 hv = *(const ushort4*)&hb[(size_t)node * HID + lane * 4];
  const float h0 = bf2f(hv.x), h1 = bf2f(hv.y), h2 = bf2f(hv.z), h3 = bf2f(hv.w);
  const int head = lane >> 3;
  const float* av[4];
  if (side) { av[0] = ai0; av[1] = ai1; av[2] = ai2; av[3] = ai3; }
  else      { av[0] = au0; av[1] = au1; av[2] = au2; av[3] = au3; }
#pragma unroll
  for (int k = 0; k < 4; ++k) {
    f4 a = *(const f4*)&av[k][lane * 4];
    float p = h0 * a.x + h1 * a.y + h2 * a.z + h3 * a.w;
    p += __shfl_xor(p, 1);
    p += __shfl_xor(p, 2);
    p += __shfl_xor(p, 4);
    if ((lane & 7) == 0)
      sdst[(size_t)k * N8 + (size_t)node * 8 + head] = p;
  }
}

// ---------------------------------------------------------------------------
// scat2: per-block multisplit into FIXED-CAPACITY buckets. Block-local LDS
// histogram -> one reservation atomic per (block,bucket) on bcnt (doubles as
// the bucket count) -> contiguous packed writes at bucket*BCAP + offset.
// Replaces the old hist + bscan + scat2 trio.
// ---------------------------------------------------------------------------
__global__ __launch_bounds__(256) void scat2_kernel(
    const int* __restrict__ s0, const int* __restrict__ d0,
    const int* __restrict__ s1, const int* __restrict__ d1,
    const int* __restrict__ s2, const int* __restrict__ d2,
    const int* __restrict__ s3, const int* __restrict__ d3,
    int* __restrict__ bcnt, u32* __restrict__ bstage)
{
  __shared__ int lh[NBUK];
  const int rel = blockIdx.x / NB1;
  const int blk = blockIdx.x % NB1;
  const int* sp = rel == 0 ? s0 : rel == 1 ? s1 : rel == 2 ? s2 : s3;
  const int* dp = rel == 0 ? d0 : rel == 1 ? d1 : rel == 2 ? d2 : d3;
  for (int j = threadIdx.x; j < NBUK; j += 256) lh[j] = 0;
  __syncthreads();
  const int base = blk * EPB1;
#pragma unroll 4
  for (int k = 0; k < EPB1 / 256; ++k) {
    int i = base + k * 256 + threadIdx.x;
    if (i < E) atomicAdd(&lh[dp[i] >> BSH], 1);
  }
  __syncthreads();
  for (int j = threadIdx.x; j < NBUK; j += 256) {
    int c = lh[j];
    int gb = rel * NBUK + j;
    lh[j] = c ? gb * BCAP + atomicAdd(&bcnt[gb], c) : 0;
  }
  __syncthreads();
#pragma unroll 4
  for (int k = 0; k < EPB1 / 256; ++k) {
    int i = base + k * 256 + threadIdx.x;
    if (i < E) {
      int dst = dp[i], src = sp[i];
      int pos = atomicAdd(&lh[dst >> BSH], 1);   // LDS atomic (fast)
      bstage[pos] = ((u32)dst << 16) | (u32)src;
    }
  }
}

// ---------------------------------------------------------------------------
// Fused fillb: per bucket, (1) LDS fine-count, (2) LDS exclusive scan ->
// start/count written directly (start = bucket*BCAP + intra-prefix), (3)
// place csr (bucket-strided). Replaces cntb + scanA/B/C + fillb. The ~10KB
// bucket staging is L1/L2-hot on the second pass.
// ---------------------------------------------------------------------------
__global__ __launch_bounds__(256) void fillb_kernel(
    const u32* __restrict__ bstage, const int* __restrict__ bcnt,
    int* __restrict__ start, int* __restrict__ count, int* __restrict__ csr)
{
  __shared__ int lcnt[128];
  __shared__ int lpos[128];
  const int bb = blockIdx.x;
  const int rel = bb / NBUK, b = bb % NBUK;
  const int base = bb * BCAP;
  const int cnt = bcnt[bb];
  const int t = threadIdx.x;
  if (t < 128) lcnt[t] = 0;
  __syncthreads();
  for (int k = t; k < cnt; k += 256)
    atomicAdd(&lcnt[(bstage[base + k] >> 16) & 127], 1);
  __syncthreads();
  if (t < 128) lpos[t] = lcnt[t];
  __syncthreads();
  for (int off = 1; off < 128; off <<= 1) {
    int v = (t < 128 && t >= off) ? lpos[t - off] : 0;
    __syncthreads();
    if (t < 128) lpos[t] += v;
    __syncthreads();
  }
  const int fb = rel * N + b * 128;
  const int lim = min(128, N - b * 128);
  if (t < 128) {
    int ex = base + lpos[t] - lcnt[t];     // exclusive prefix, absolute csr pos
    if (t < lim) {
      start[fb + t] = ex;
      count[fb + t] = lcnt[t];
    }
    lcnt[t] = ex;                          // becomes the cursor
  }
  __syncthreads();
  for (int k = t; k < cnt; k += 256) {
    u32 pk = bstage[base + k];
    int pos = atomicAdd(&lcnt[(pk >> 16) & 127], 1);
    csr[pos] = (int)(pk & 0xffffu);
  }
}

// ---------------------------------------------------------------------------
// Relation conv (R11 single-pass, 8-edge batches) — at its fabric-BW floor.
// ---------------------------------------------------------------------------
#define CONV_EDGE(sx)                                                     \
  {                                                                       \
    float al = __expf(lrelu(lg##sx + sdv2));                              \
    den += al;                                                            \
    a0 = fmaf(al, bf2f(v##sx.x), a0); a1 = fmaf(al, bf2f(v##sx.y), a1);   \
    a2 = fmaf(al, bf2f(v##sx.z), a2); a3 = fmaf(al, bf2f(v##sx.w), a3);   \
  }

__global__ __launch_bounds__(256) void conv_kernel(
    const ush* __restrict__ hub, const ush* __restrict__ hib,
    const float* __restrict__ su, const float* __restrict__ si,
    const int* __restrict__ csr,
    const int* __restrict__ start, const int* __restrict__ count,
    ush* __restrict__ zall)
{
  const int rel = blockIdx.x / (N / 4);
  const int lb  = blockIdx.x % (N / 4);
  const int dst = lb * 4 + (threadIdx.x >> 6);
  const int lane = threadIdx.x & 63;
  const ush* xsb = (rel == 0 || rel == 3) ? hib : hub;
  const float* ss = rel == 0 ? si : rel == 1 ? su + N8 :
                    rel == 2 ? su + 3 * (size_t)N8 : si + 2 * (size_t)N8;
  const float* sd = rel == 0 ? su : rel == 1 ? su + 2 * (size_t)N8 :
                    rel == 2 ? si + N8 : si + 3 * (size_t)N8;
  const int grow = rel * N + dst;
  const int e0 = start[grow];
  const int ne = count[grow];

  const int h2 = lane >> 3;
  const float sdv2 = sd[dst * 8 + h2];

  float den = 0.f;
  float a0 = 0.f, a1 = 0.f, a2 = 0.f, a3 = 0.f;
  int j = 0;
  for (; j + 8 <= ne; j += 8) {
    int s0_ = csr[e0 + j + 0], s1_ = csr[e0 + j + 1];
    int s2_ = csr[e0 + j + 2], s3_ = csr[e0 + j + 3];
    int s4_ = csr[e0 + j + 4], s5_ = csr[e0 + j + 5];
    int s6_ = csr[e0 + j + 6], s7_ = csr[e0 + j + 7];
    float lg0 = ss[s0_ * 8 + h2], lg1 = ss[s1_ * 8 + h2];
    float lg2 = ss[s2_ * 8 + h2], lg3 = ss[s3_ * 8 + h2];
    float lg4 = ss[s4_ * 8 + h2], lg5 = ss[s5_ * 8 + h2];
    float lg6 = ss[s6_ * 8 + h2], lg7 = ss[s7_ * 8 + h2];
    ushort4 v0 = *(const ushort4*)&xsb[(size_t)s0_ * HID + lane * 4];
    ushort4 v1 = *(const ushort4*)&xsb[(size_t)s1_ * HID + lane * 4];
    ushort4 v2 = *(const ushort4*)&xsb[(size_t)s2_ * HID + lane * 4];
    ushort4 v3 = *(const ushort4*)&xsb[(size_t)s3_ * HID + lane * 4];
    ushort4 v4 = *(const ushort4*)&xsb[(size_t)s4_ * HID + lane * 4];
    ushort4 v5 = *(const ushort4*)&xsb[(size_t)s5_ * HID + lane * 4];
    ushort4 v6 = *(const ushort4*)&xsb[(size_t)s6_ * HID + lane * 4];
    ushort4 v7 = *(const ushort4*)&xsb[(size_t)s7_ * HID + lane * 4];
    CONV_EDGE(0) CONV_EDGE(1) CONV_EDGE(2) CONV_EDGE(3)
    CONV_EDGE(4) CONV_EDGE(5) CONV_EDGE(6) CONV_EDGE(7)
  }
  for (; j + 2 <= ne; j += 2) {
    int s0_ = csr[e0 + j + 0], s1_ = csr[e0 + j + 1];
    float lg0 = ss[s0_ * 8 + h2], lg1 = ss[s1_ * 8 + h2];
    ushort4 v0 = *(const ushort4*)&xsb[(size_t)s0_ * HID + lane * 4];
    ushort4 v1 = *(const ushort4*)&xsb[(size_t)s1_ * HID + lane * 4];
    CONV_EDGE(0) CONV_EDGE(1)
  }
  if (j < ne) {
    int s0_ = csr[e0 + j];
    float lg0 = ss[s0_ * 8 + h2];
    ushort4 v0 = *(const ushort4*)&xsb[(size_t)s0_ * HID + lane * 4];
    CONV_EDGE(0)
  }
  const float inv = 1.f / (den + 1e-16f);
  ushort4 o;
  o.x = (ush)bfr(fmaxf(a0 * inv, 0.f));
  o.y = (ush)bfr(fmaxf(a1 * inv, 0.f));
  o.z = (ush)bfr(fmaxf(a2 * inv, 0.f));
  o.w = (ush)bfr(fmaxf(a3 * inv, 0.f));
  *(ushort4*)&zall[(size_t)grow * HID + lane * 4] = o;
}

// ---------------------------------------------------------------------------
// Semantic scores v5 (R10, unchanged)
// ---------------------------------------------------------------------------
__global__ __launch_bounds__(512, 2) void semscore_kernel(
    const ush* __restrict__ zbu0, const ush* __restrict__ zbu1,
    const ush* __restrict__ zbi0, const ush* __restrict__ zbi1,
    const ush* __restrict__ wkT, const float* __restrict__ bk,
    const float* __restrict__ q, float* __restrict__ score)
{
  __shared__ ush As[4][128 * 64];
  const int bid = blockIdx.x;
  const int mat = bid / SMT;
  const int mt  = bid % SMT;
  const ush* zsrc = mat == 0 ? zbu0 : mat == 1 ? zbu1 : mat == 2 ? zbi0 : zbi1;
  const int Mbase = mt * 128;
  const int t = threadIdx.x;
  const int w = t >> 6, l = t & 63;
  const int lrow = l & 15, kgrp = l >> 4;
  const int wr = w >> 2, wc = w & 3;

  auto stage = [&](int kc) {
#pragma unroll
    for (int i = 0; i < 2; ++i) {
      int q16 = i * 512 + t;
      int r = q16 >> 3;
      int c = (q16 & 7) ^ (r & 7);
      int gr = Mbase + r; if (gr >= N) gr = N - 1;
      gll16(&zsrc[(size_t)gr * HID + kc * 64 + c * 8],
            &As[kc][(i * 512 + w * 64) * 8]);
    }
  };

  f32x4 acc[4][4];
  const f32x4 zz = {0.f, 0.f, 0.f, 0.f};
#pragma unroll
  for (int m = 0; m < 4; ++m)
#pragma unroll
    for (int n = 0; n < 4; ++n) acc[m][n] = zz;

  stage(0); stage(1); stage(2); stage(3);

  auto compute = [&](int kc) {
    bf16x8 Bf[4][2];
#pragma unroll
    for (int n = 0; n < 4; ++n)
#pragma unroll
      for (int ks = 0; ks < 2; ++ks)
        Bf[n][ks] = *(const bf16x8*)&wkT[(size_t)(wc * 64 + n * 16 + lrow) * HID
                                         + kc * 64 + ks * 32 + kgrp * 8];
#pragma unroll
    for (int m = 0; m < 4; ++m) {
      const int mrow = wr * 64 + m * 16 + lrow;
      bf16x8 Af[2];
#pragma unroll
      for (int ks = 0; ks < 2; ++ks) {
        int ch = (ks * 4 + kgrp) ^ (mrow & 7);
        Af[ks] = *(const bf16x8*)&As[kc][mrow * 64 + ch * 8];
      }
#pragma unroll
      for (int n = 0; n < 4; ++n)
#pragma unroll
        for (int ks = 0; ks < 2; ++ks)
          acc[m][n] = __builtin_amdgcn_mfma_f32_16x16x32_bf16(Af[ks], Bf[n][ks],
                                                              acc[m][n], 0, 0, 0);
    }
  };

  WAITK("6"); compute(0);
  WAITK("4"); compute(1);
  WAITK("2"); compute(2);
  WAITK("0"); compute(3);

  float s = 0.f;
#pragma unroll
  for (int m = 0; m < 4; ++m) {
    const int gr0 = Mbase + wr * 64 + m * 16 + kgrp * 4;
#pragma unroll
    for (int n = 0; n < 4; ++n) {
      const int col = wc * 64 + n * 16 + lrow;
      const float bkv = bk[col], qv = q[col];
#pragma unroll
      for (int i = 0; i < 4; ++i)
        if (gr0 + i < N) s += tanh_fast(acc[m][n][i] + bkv) * qv;
    }
  }
#pragma unroll
  for (int off = 1; off < 64; off <<= 1) s += __shfl_xor(s, off);
  if (l == 0) atomicAdd(&score[mat], s);
}

// ---------------------------------------------------------------------------
// Final: out = (a0*z0 + a1*z1) @ Wl + bl via bf16 MFMA; semantic softmax
// computed inline from raw scores (replaces attn2 launch).
// ---------------------------------------------------------------------------
__global__ __launch_bounds__(256) void final_kernel(
    const ush* __restrict__ zbu0, const ush* __restrict__ zbu1,
    const ush* __restrict__ zbi0, const ush* __restrict__ zbi1,
    const float* __restrict__ sc, const ush* __restrict__ wlT,
    const float* __restrict__ bl, float* __restrict__ out)
{
  const int bid = blockIdx.x;
  const int side = bid >= FB;
  const ush* z0 = side ? zbi0 : zbu0;
  const ush* z1 = side ? zbi1 : zbu1;
  float* op = out + (size_t)side * N * OUTD;
  // inline 2-way softmax of mean scores
  const float inv_n = 1.f / (float)N;
  float r0 = sc[side * 2] * inv_n, r1 = sc[side * 2 + 1] * inv_n;
  float mm = fmaxf(r0, r1);
  float e0 = __expf(r0 - mm), e1 = __expf(r1 - mm);
  const float a0 = e0 / (e0 + e1), a1 = e1 / (e0 + e1);
  const int t = threadIdx.x;
  const int w = t >> 6, l = t & 63;
  const int lrow = l & 15, kgrp = l >> 4;
  const int base = (bid - side * FB) * 64;
  int arow = base + w * 16 + lrow;
  if (arow >= N) arow = N - 1;

  bf16x8 Af[8];
#pragma unroll
  for (int ks = 0; ks < 8; ++ks) {
    const ush* p0 = &z0[(size_t)arow * HID + ks * 32 + kgrp * 8];
    const ush* p1 = &z1[(size_t)arow * HID + ks * 32 + kgrp * 8];
    ushort4 u0a = *(const ushort4*)p0, u0b = *(const ushort4*)(p0 + 4);
    ushort4 u1a = *(const ushort4*)p1, u1b = *(const ushort4*)(p1 + 4);
    union { u32 u[4]; bf16x8 v; } c;
    c.u[0] = pk2(a0 * bf2f(u0a.x) + a1 * bf2f(u1a.x),
                 a0 * bf2f(u0a.y) + a1 * bf2f(u1a.y));
    c.u[1] = pk2(a0 * bf2f(u0a.z) + a1 * bf2f(u1a.z),
                 a0 * bf2f(u0a.w) + a1 * bf2f(u1a.w));
    c.u[2] = pk2(a0 * bf2f(u0b.x) + a1 * bf2f(u1b.x),
                 a0 * bf2f(u0b.y) + a1 * bf2f(u1b.y));
    c.u[3] = pk2(a0 * bf2f(u0b.z) + a1 * bf2f(u1b.z),
                 a0 * bf2f(u0b.w) + a1 * bf2f(u1b.w));
    Af[ks] = c.v;
  }

#pragma unroll
  for (int nt = 0; nt < 4; ++nt) {
    const int col = nt * 16 + lrow;
    f32x4 acc = {0.f, 0.f, 0.f, 0.f};
#pragma unroll
    for (int ks = 0; ks < 8; ++ks) {
      bf16x8 Bf = *(const bf16x8*)&wlT[(size_t)col * HID + ks * 32 + kgrp * 8];
      acc = __builtin_amdgcn_mfma_f32_16x16x32_bf16(Af[ks], Bf, acc, 0, 0, 0);
    }
    const float bb = bl[col];
#pragma unroll
    for (int i = 0; i < 4; ++i) {
      int gr = base + w * 16 + kgrp * 4 + i;
      if (gr < N) op[(size_t)gr * OUTD + col] = acc[i] + bb;
    }
  }
}

// ---------------------------------------------------------------------------
extern "C" void kernel_launch(void* const* d_in, const int* in_sizes, int n_in,
                              void* d_out, int out_size, void* d_ws, size_t ws_size,
                              hipStream_t stream)
{
  const float* x_user = (const float*)d_in[0];
  const float* x_item = (const float*)d_in[1];
  const int*   e_ui   = (const int*)d_in[2];
  const int*   e_iu   = (const int*)d_in[3];
  const int*   e_uu   = (const int*)d_in[4];
  const int*   e_ii   = (const int*)d_in[5];
  const float* Wp_u   = (const float*)d_in[6];
  const float* bp_u   = (const float*)d_in[7];
  const float* Wp_i   = (const float*)d_in[8];
  const float* bp_i   = (const float*)d_in[9];
  const float* as_ui  = (const float*)d_in[10];
  const float* ad_ui  = (const float*)d_in[11];
  const float* as_iu  = (const float*)d_in[12];
  const float* ad_iu  = (const float*)d_in[13];
  const float* as_uu  = (const float*)d_in[14];
  const float* ad_uu  = (const float*)d_in[15];
  const float* as_ii  = (const float*)d_in[16];
  const float* ad_ii  = (const float*)d_in[17];
  const float* Wk     = (const float*)d_in[18];
  const float* bk     = (const float*)d_in[19];
  const float* q      = (const float*)d_in[20];
  const float* Wl     = (const float*)d_in[21];
  const float* bl     = (const float*)d_in[22];

  const size_t NH = (size_t)N * HID;
  const size_t WT = 65536 + 2 * 32768 + 16384;   // wkT + wpTu + wpTi + wlT (ush)
  size_t need = (8 * (size_t)N8 + 8) * 4                     // su,si,sc (f32)
              + (6 * NH + WT) * 2                            // 4x z, hub, hib, weights
              + ((size_t)8 * N + (size_t)NBT * BCAP + NBT) * 4; // start/count + csr + bcnt
  if (ws_size < need) {
    hipMemsetAsync(d_out, 0x7f, (size_t)out_size * sizeof(float), stream);
    return;
  }
  float* su = (float*)d_ws;
  float* si = su + 4 * (size_t)N8;
  float* sc = si + 4 * (size_t)N8;
  ush* zbu0 = (ush*)(sc + 8);
  ush* zbu1 = zbu0 + NH;
  ush* zbi0 = zbu1 + NH;
  ush* zbi1 = zbi0 + NH;
  ush* hub  = zbi1 + NH;
  ush* hib  = hub + NH;
  ush* wkT  = hib + NH;
  ush* wpTu = wkT + 65536;
  ush* wpTi = wpTu + 32768;
  ush* wlT  = wpTi + 32768;
  int* count  = (int*)(wlT + 16384);
  int* start  = count + NTOT;
  int* bcnt   = start + NTOT;
  int* csr    = bcnt + NBT;
  u32* bstage = (u32*)zbu0;     // NBT*BCAP*4 = 16.0 MB <= 25.6 MB (dead until conv)

  // 1. weight transposes + zero bcnt/sc
  tran_kernel<<<576, 256, 0, stream>>>(Wk, Wp_u, Wp_i, Wl, wkT, wpTu, wpTi, wlT,
                                       bcnt, sc);
  // 2. projections (MFMA, both types)
  proj_kernel<<<2 * FB, 256, 0, stream>>>(x_user, x_item, wpTu, wpTi, bp_u, bp_i,
                                          hub, hib);
  // 3. node scores (both types)
  nodescore_kernel<<<2 * (N / 4), 256, 0, stream>>>(hub, hib,
                                                    ad_iu, as_uu, ad_uu, as_ui,
                                                    as_iu, ad_ui, as_ii, ad_ii,
                                                    su, si);
  // 4. multisplit into fixed-capacity buckets (rel 0=iu, 1=uu, 2=ui, 3=ii)
  scat2_kernel<<<4 * NB1, 256, 0, stream>>>(e_iu, e_iu + E, e_uu, e_uu + E,
                                            e_ui, e_ui + E, e_ii, e_ii + E,
                                            bcnt, bstage);
  // 5. fused fine count + scan + csr fill
  fillb_kernel<<<NBT, 256, 0, stream>>>(bstage, bcnt, start, count, csr);
  // 6. all 4 relation convs
  conv_kernel<<<NTOT / 4, 256, 0, stream>>>(hub, hib, su, si, csr, start, count, zbu0);
  // 7. semantic attention scores
  semscore_kernel<<<4 * SMT, 512, 0, stream>>>(zbu0, zbu1, zbi0, zbi1, wkT, bk, q, sc);
  // 8. final linear (softmax inline)
  final_kernel<<<2 * FB, 256, 0, stream>>>(zbu0, zbu1, zbi0, zbi1, sc, wlT, bl,
                                           (float*)d_out);
}

// Round 14
// 686.227 us; speedup vs baseline: 2.9205x; 1.0363x over previous
//
#include <hip/hip_runtime.h>
#include <math.h>

#define N     50000
#define F_IN  128
#define HID   256
#define E     800000
#define OUTD  64
#define NEG   0.2f
#define N8    (N * 8)
#define NTOT  (4 * N)
#define SMT   ((N + 127) / 128)      // 391 M-tiles per matrix (semscore)
#define FB    ((N + 63) / 64)        // 782 64-row blocks (proj/final)

// bucket sort geometry (fixed-capacity buckets)
#define BSH   7
#define NBUK  ((N + 127) / 128)      // 391
#define NBT   (4 * NBUK)             // 1564
#define BCAP  2560                   // Poisson(2048) + 11 sigma headroom
#define EPB1  8192
#define NB1   ((E + EPB1 - 1) / EPB1) // 98

typedef float4 f4;
typedef unsigned int u32;
typedef unsigned short ush;
typedef float f32x4 __attribute__((ext_vector_type(4)));
typedef short bf16x8 __attribute__((ext_vector_type(8)));

static __device__ __forceinline__ float lrelu(float x) { return x >= 0.f ? x : NEG * x; }
static __device__ __forceinline__ u32 bfr(float x) {
  u32 u = __float_as_uint(x);
  return (u + 0x7fffu + ((u >> 16) & 1u)) >> 16;
}
static __device__ __forceinline__ u32 pk2(float a, float b) { return bfr(a) | (bfr(b) << 16); }
static __device__ __forceinline__ float bf2f(u32 us) { return __uint_as_float(us << 16); }
static __device__ __forceinline__ float tanh_fast(float x) {
  float e = __expf(2.f * x);
  return fmaf(-2.f, __builtin_amdgcn_rcpf(e + 1.f), 1.f);
}

typedef const __attribute__((address_space(1))) unsigned int gu32;
typedef __attribute__((address_space(3))) unsigned int lu32;
static __device__ __forceinline__ void gll16(const void* g, void* l) {
  __builtin_amdgcn_global_load_lds((gu32*)g, (lu32*)l, 16, 0, 0);
}

#define WAITK(nstr)                                          \
  asm volatile("s_waitcnt vmcnt(" nstr ")" ::: "memory");    \
  __builtin_amdgcn_s_barrier();                              \
  asm volatile("" ::: "memory");

// ---------------------------------------------------------------------------
// Weight precompute (bf16 transposes) + zero bcnt/sc.
// ---------------------------------------------------------------------------
__global__ void tran_kernel(const float* __restrict__ Wk,
                            const float* __restrict__ Wpu,
                            const float* __restrict__ Wpi,
                            const float* __restrict__ Wl,
                            ush* __restrict__ wkT, ush* __restrict__ wpTu,
                            ush* __restrict__ wpTi, ush* __restrict__ wlT,
                            int* __restrict__ bcnt, float* __restrict__ sc)
{
  int idx = blockIdx.x * 256 + threadIdx.x;
  if (idx < NBT) bcnt[idx] = 0;
  if (idx >= NBT && idx < NBT + 8) sc[idx - NBT] = 0.f;
  const float* src; ush* dst; int K, M, li;
  if (idx < 65536)       { src = Wk;  dst = wkT;  K = 256; M = 256; li = idx; }
  else if (idx < 98304)  { src = Wpu; dst = wpTu; K = 128; M = 256; li = idx - 65536; }
  else if (idx < 131072) { src = Wpi; dst = wpTi; K = 128; M = 256; li = idx - 98304; }
  else                   { src = Wl;  dst = wlT;  K = 256; M = 64;  li = idx - 131072; }
  int m = li / K, k = li % K;
  dst[li] = (ush)bfr(src[k * M + m]);
}

// ---------------------------------------------------------------------------
// Projection + FUSED node scores.  h = x @ Wp + b via bf16 MFMA; per nt-tile
// accumulate p_k[i] += acc[i]*a_k[col] (scores from PRE-rounding fp32 acc);
// head = nt>>1, so reduce across the 16-lane lrow group every odd nt.
// ---------------------------------------------------------------------------
__global__ __launch_bounds__(256) void proj_kernel(
    const float* __restrict__ xu, const float* __restrict__ xi,
    const ush* __restrict__ wpTu, const ush* __restrict__ wpTi,
    const float* __restrict__ bu, const float* __restrict__ bi,
    const float* __restrict__ au0, const float* __restrict__ au1,
    const float* __restrict__ au2, const float* __restrict__ au3,
    const float* __restrict__ ai0, const float* __restrict__ ai1,
    const float* __restrict__ ai2, const float* __restrict__ ai3,
    ush* __restrict__ hu, ush* __restrict__ hi,
    float* __restrict__ su, float* __restrict__ si)
{
  const int bid = blockIdx.x;
  const int side = bid >= FB;
  const float* x = side ? xi : xu;
  const ush* wpT = side ? wpTi : wpTu;
  const float* b = side ? bi : bu;
  ush* hb = side ? hi : hu;
  float* sdst = side ? si : su;
  const float* a0 = side ? ai0 : au0;
  const float* a1 = side ? ai1 : au1;
  const float* a2 = side ? ai2 : au2;
  const float* a3 = side ? ai3 : au3;
  const int t = threadIdx.x;
  const int w = t >> 6, l = t & 63;
  const int lrow = l & 15, kgrp = l >> 4;
  const int base = (bid - side * FB) * 64;
  int arow = base + w * 16 + lrow;
  if (arow >= N) arow = N - 1;

  bf16x8 Af[4];
#pragma unroll
  for (int ks = 0; ks < 4; ++ks) {
    const float* px = &x[(size_t)arow * F_IN + ks * 32 + kgrp * 8];
    f4 v0 = *(const f4*)px;
    f4 v1 = *(const f4*)(px + 4);
    union { u32 u[4]; bf16x8 v; } c;
    c.u[0] = pk2(v0.x, v0.y); c.u[1] = pk2(v0.z, v0.w);
    c.u[2] = pk2(v1.x, v1.y); c.u[3] = pk2(v1.z, v1.w);
    Af[ks] = c.v;
  }

  float pk[4][4] = {};
#pragma unroll
  for (int nt = 0; nt < 16; ++nt) {
    const int col = nt * 16 + lrow;
    f32x4 acc = {0.f, 0.f, 0.f, 0.f};
#pragma unroll
    for (int ks = 0; ks < 4; ++ks) {
      bf16x8 Bf = *(const bf16x8*)&wpT[(size_t)col * F_IN + ks * 32 + kgrp * 8];
      acc = __builtin_amdgcn_mfma_f32_16x16x32_bf16(Af[ks], Bf, acc, 0, 0, 0);
    }
    const float bb = b[col];
    const float av0 = a0[col], av1 = a1[col], av2 = a2[col], av3 = a3[col];
#pragma unroll
    for (int i = 0; i < 4; ++i) {
      float hv = acc[i] + bb;
      int gr = base + w * 16 + kgrp * 4 + i;
      if (gr < N) hb[(size_t)gr * HID + col] = (ush)bfr(hv);
      pk[0][i] = fmaf(hv, av0, pk[0][i]);
      pk[1][i] = fmaf(hv, av1, pk[1][i]);
      pk[2][i] = fmaf(hv, av2, pk[2][i]);
      pk[3][i] = fmaf(hv, av3, pk[3][i]);
    }
    if (nt & 1) {
      const int head = nt >> 1;
#pragma unroll
      for (int k = 0; k < 4; ++k)
#pragma unroll
        for (int i = 0; i < 4; ++i) {
          float p = pk[k][i];
          p += __shfl_xor(p, 1);
          p += __shfl_xor(p, 2);
          p += __shfl_xor(p, 4);
          p += __shfl_xor(p, 8);
          int gr = base + w * 16 + kgrp * 4 + i;
          if (lrow == 0 && gr < N)
            sdst[(size_t)k * N8 + (size_t)gr * 8 + head] = p;
          pk[k][i] = 0.f;
        }
    }
  }
}

// ---------------------------------------------------------------------------
// scat2 single-pass: block's 8192 edges held in REGISTERS (32/thread) ->
// LDS histogram -> one reservation atomic per (block,bucket) -> packed writes
// at bucket*BCAP + offset.  One global pass over the edge arrays.
// ---------------------------------------------------------------------------
__global__ __launch_bounds__(256) void scat2_kernel(
    const int* __restrict__ s0, const int* __restrict__ d0,
    const int* __restrict__ s1, const int* __restrict__ d1,
    const int* __restrict__ s2, const int* __restrict__ d2,
    const int* __restrict__ s3, const int* __restrict__ d3,
    int* __restrict__ bcnt, u32* __restrict__ bstage)
{
  __shared__ int lh[NBUK];
  const int rel = blockIdx.x / NB1;
  const int blk = blockIdx.x % NB1;
  const int* sp = rel == 0 ? s0 : rel == 1 ? s1 : rel == 2 ? s2 : s3;
  const int* dp = rel == 0 ? d0 : rel == 1 ? d1 : rel == 2 ? d2 : d3;
  for (int j = threadIdx.x; j < NBUK; j += 256) lh[j] = 0;
  __syncthreads();
  const int base = blk * EPB1;
  int sr[32], dr[32];
#pragma unroll
  for (int k = 0; k < 32; ++k) {
    int i = base + k * 256 + threadIdx.x;
    sr[k] = (i < E) ? sp[i] : -1;
    dr[k] = (i < E) ? dp[i] : -1;
  }
#pragma unroll
  for (int k = 0; k < 32; ++k)
    if (dr[k] >= 0) atomicAdd(&lh[dr[k] >> BSH], 1);
  __syncthreads();
  for (int j = threadIdx.x; j < NBUK; j += 256) {
    int c = lh[j];
    int gb = rel * NBUK + j;
    lh[j] = c ? gb * BCAP + atomicAdd(&bcnt[gb], c) : 0;
  }
  __syncthreads();
#pragma unroll
  for (int k = 0; k < 32; ++k)
    if (dr[k] >= 0) {
      int pos = atomicAdd(&lh[dr[k] >> BSH], 1);
      bstage[pos] = ((u32)dr[k] << 16) | (u32)sr[k];
    }
}

// ---------------------------------------------------------------------------
// Fused fillb (R13): per bucket fine-count + LDS scan + csr fill.
// ---------------------------------------------------------------------------
__global__ __launch_bounds__(256) void fillb_kernel(
    const u32* __restrict__ bstage, const int* __restrict__ bcnt,
    int* __restrict__ start, int* __restrict__ count, int* __restrict__ csr)
{
  __shared__ int lcnt[128];
  __shared__ int lpos[128];
  const int bb = blockIdx.x;
  const int rel = bb / NBUK, b = bb % NBUK;
  const int base = bb * BCAP;
  const int cnt = bcnt[bb];
  const int t = threadIdx.x;
  if (t < 128) lcnt[t] = 0;
  __syncthreads();
  for (int k = t; k < cnt; k += 256)
    atomicAdd(&lcnt[(bstage[base + k] >> 16) & 127], 1);
  __syncthreads();
  if (t < 128) lpos[t] = lcnt[t];
  __syncthreads();
  for (int off = 1; off < 128; off <<= 1) {
    int v = (t < 128 && t >= off) ? lpos[t - off] : 0;
    __syncthreads();
    if (t < 128) lpos[t] += v;
    __syncthreads();
  }
  const int fb = rel * N + b * 128;
  const int lim = min(128, N - b * 128);
  if (t < 128) {
    int ex = base + lpos[t] - lcnt[t];
    if (t < lim) {
      start[fb + t] = ex;
      count[fb + t] = lcnt[t];
    }
    lcnt[t] = ex;
  }
  __syncthreads();
  for (int k = t; k < cnt; k += 256) {
    u32 pk = bstage[base + k];
    int pos = atomicAdd(&lcnt[(pk >> 16) & 127], 1);
    csr[pos] = (int)(pk & 0xffffu);
  }
}

// ---------------------------------------------------------------------------
// Relation conv (R11 single-pass, 8-edge batches) — at its gather-BW floor.
// ---------------------------------------------------------------------------
#define CONV_EDGE(sx)                                                     \
  {                                                                       \
    float al = __expf(lrelu(lg##sx + sdv2));                              \
    den += al;                                                            \
    a0 = fmaf(al, bf2f(v##sx.x), a0); a1 = fmaf(al, bf2f(v##sx.y), a1);   \
    a2 = fmaf(al, bf2f(v##sx.z), a2); a3 = fmaf(al, bf2f(v##sx.w), a3);   \
  }

__global__ __launch_bounds__(256) void conv_kernel(
    const ush* __restrict__ hub, const ush* __restrict__ hib,
    const float* __restrict__ su, const float* __restrict__ si,
    const int* __restrict__ csr,
    const int* __restrict__ start, const int* __restrict__ count,
    ush* __restrict__ zall)
{
  const int rel = blockIdx.x / (N / 4);
  const int lb  = blockIdx.x % (N / 4);
  const int dst = lb * 4 + (threadIdx.x >> 6);
  const int lane = threadIdx.x & 63;
  const ush* xsb = (rel == 0 || rel == 3) ? hib : hub;
  const float* ss = rel == 0 ? si : rel == 1 ? su + N8 :
                    rel == 2 ? su + 3 * (size_t)N8 : si + 2 * (size_t)N8;
  const float* sd = rel == 0 ? su : rel == 1 ? su + 2 * (size_t)N8 :
                    rel == 2 ? si + N8 : si + 3 * (size_t)N8;
  const int grow = rel * N + dst;
  const int e0 = start[grow];
  const int ne = count[grow];

  const int h2 = lane >> 3;
  const float sdv2 = sd[dst * 8 + h2];

  float den = 0.f;
  float a0 = 0.f, a1 = 0.f, a2 = 0.f, a3 = 0.f;
  int j = 0;
  for (; j + 8 <= ne; j += 8) {
    int s0_ = csr[e0 + j + 0], s1_ = csr[e0 + j + 1];
    int s2_ = csr[e0 + j + 2], s3_ = csr[e0 + j + 3];
    int s4_ = csr[e0 + j + 4], s5_ = csr[e0 + j + 5];
    int s6_ = csr[e0 + j + 6], s7_ = csr[e0 + j + 7];
    float lg0 = ss[s0_ * 8 + h2], lg1 = ss[s1_ * 8 + h2];
    float lg2 = ss[s2_ * 8 + h2], lg3 = ss[s3_ * 8 + h2];
    float lg4 = ss[s4_ * 8 + h2], lg5 = ss[s5_ * 8 + h2];
    float lg6 = ss[s6_ * 8 + h2], lg7 = ss[s7_ * 8 + h2];
    ushort4 v0 = *(const ushort4*)&xsb[(size_t)s0_ * HID + lane * 4];
    ushort4 v1 = *(const ushort4*)&xsb[(size_t)s1_ * HID + lane * 4];
    ushort4 v2 = *(const ushort4*)&xsb[(size_t)s2_ * HID + lane * 4];
    ushort4 v3 = *(const ushort4*)&xsb[(size_t)s3_ * HID + lane * 4];
    ushort4 v4 = *(const ushort4*)&xsb[(size_t)s4_ * HID + lane * 4];
    ushort4 v5 = *(const ushort4*)&xsb[(size_t)s5_ * HID + lane * 4];
    ushort4 v6 = *(const ushort4*)&xsb[(size_t)s6_ * HID + lane * 4];
    ushort4 v7 = *(const ushort4*)&xsb[(size_t)s7_ * HID + lane * 4];
    CONV_EDGE(0) CONV_EDGE(1) CONV_EDGE(2) CONV_EDGE(3)
    CONV_EDGE(4) CONV_EDGE(5) CONV_EDGE(6) CONV_EDGE(7)
  }
  for (; j + 2 <= ne; j += 2) {
    int s0_ = csr[e0 + j + 0], s1_ = csr[e0 + j + 1];
    float lg0 = ss[s0_ * 8 + h2], lg1 = ss[s1_ * 8 + h2];
    ushort4 v0 = *(const ushort4*)&xsb[(size_t)s0_ * HID + lane * 4];
    ushort4 v1 = *(const ushort4*)&xsb[(size_t)s1_ * HID + lane * 4];
    CONV_EDGE(0) CONV_EDGE(1)
  }
  if (j < ne) {
    int s0_ = csr[e0 + j];
    float lg0 = ss[s0_ * 8 + h2];
    ushort4 v0 = *(const ushort4*)&xsb[(size_t)s0_ * HID + lane * 4];
    CONV_EDGE(0)
  }
  const float inv = 1.f / (den + 1e-16f);
  ushort4 o;
  o.x = (ush)bfr(fmaxf(a0 * inv, 0.f));
  o.y = (ush)bfr(fmaxf(a1 * inv, 0.f));
  o.z = (ush)bfr(fmaxf(a2 * inv, 0.f));
  o.w = (ush)bfr(fmaxf(a3 * inv, 0.f));
  *(ushort4*)&zall[(size_t)grow * HID + lane * 4] = o;
}

// ---------------------------------------------------------------------------
// Semantic scores v5 (R10, unchanged)
// ---------------------------------------------------------------------------
__global__ __launch_bounds__(512, 2) void semscore_kernel(
    const ush* __restrict__ zbu0, const ush* __restrict__ zbu1,
    const ush* __restrict__ zbi0, const ush* __restrict__ zbi1,
    const ush* __restrict__ wkT, const float* __restrict__ bk,
    const float* __restrict__ q, float* __restrict__ score)
{
  __shared__ ush As[4][128 * 64];
  const int bid = blockIdx.x;
  const int mat = bid / SMT;
  const int mt  = bid % SMT;
  const ush* zsrc = mat == 0 ? zbu0 : mat == 1 ? zbu1 : mat == 2 ? zbi0 : zbi1;
  const int Mbase = mt * 128;
  const int t = threadIdx.x;
  const int w = t >> 6, l = t & 63;
  const int lrow = l & 15, kgrp = l >> 4;
  const int wr = w >> 2, wc = w & 3;

  auto stage = [&](int kc) {
#pragma unroll
    for (int i = 0; i < 2; ++i) {
      int q16 = i * 512 + t;
      int r = q16 >> 3;
      int c = (q16 & 7) ^ (r & 7);
      int gr = Mbase + r; if (gr >= N) gr = N - 1;
      gll16(&zsrc[(size_t)gr * HID + kc * 64 + c * 8],
            &As[kc][(i * 512 + w * 64) * 8]);
    }
  };

  f32x4 acc[4][4];
  const f32x4 zz = {0.f, 0.f, 0.f, 0.f};
#pragma unroll
  for (int m = 0; m < 4; ++m)
#pragma unroll
    for (int n = 0; n < 4; ++n) acc[m][n] = zz;

  stage(0); stage(1); stage(2); stage(3);

  auto compute = [&](int kc) {
    bf16x8 Bf[4][2];
#pragma unroll
    for (int n = 0; n < 4; ++n)
#pragma unroll
      for (int ks = 0; ks < 2; ++ks)
        Bf[n][ks] = *(const bf16x8*)&wkT[(size_t)(wc * 64 + n * 16 + lrow) * HID
                                         + kc * 64 + ks * 32 + kgrp * 8];
#pragma unroll
    for (int m = 0; m < 4; ++m) {
      const int mrow = wr * 64 + m * 16 + lrow;
      bf16x8 Af[2];
#pragma unroll
      for (int ks = 0; ks < 2; ++ks) {
        int ch = (ks * 4 + kgrp) ^ (mrow & 7);
        Af[ks] = *(const bf16x8*)&As[kc][mrow * 64 + ch * 8];
      }
#pragma unroll
      for (int n = 0; n < 4; ++n)
#pragma unroll
        for (int ks = 0; ks < 2; ++ks)
          acc[m][n] = __builtin_amdgcn_mfma_f32_16x16x32_bf16(Af[ks], Bf[n][ks],
                                                              acc[m][n], 0, 0, 0);
    }
  };

  WAITK("6"); compute(0);
  WAITK("4"); compute(1);
  WAITK("2"); compute(2);
  WAITK("0"); compute(3);

  float s = 0.f;
#pragma unroll
  for (int m = 0; m < 4; ++m) {
    const int gr0 = Mbase + wr * 64 + m * 16 + kgrp * 4;
#pragma unroll
    for (int n = 0; n < 4; ++n) {
      const int col = wc * 64 + n * 16 + lrow;
      const float bkv = bk[col], qv = q[col];
#pragma unroll
      for (int i = 0; i < 4; ++i)
        if (gr0 + i < N) s += tanh_fast(acc[m][n][i] + bkv) * qv;
    }
  }
#pragma unroll
  for (int off = 1; off < 64; off <<= 1) s += __shfl_xor(s, off);
  if (l == 0) atomicAdd(&score[mat], s);
}

// ---------------------------------------------------------------------------
// Final: out = (a0*z0 + a1*z1) @ Wl + bl via bf16 MFMA; softmax inline.
// ---------------------------------------------------------------------------
__global__ __launch_bounds__(256) void final_kernel(
    const ush* __restrict__ zbu0, const ush* __restrict__ zbu1,
    const ush* __restrict__ zbi0, const ush* __restrict__ zbi1,
    const float* __restrict__ sc, const ush* __restrict__ wlT,
    const float* __restrict__ bl, float* __restrict__ out)
{
  const int bid = blockIdx.x;
  const int side = bid >= FB;
  const ush* z0 = side ? zbi0 : zbu0;
  const ush* z1 = side ? zbi1 : zbu1;
  float* op = out + (size_t)side * N * OUTD;
  const float inv_n = 1.f / (float)N;
  float r0 = sc[side * 2] * inv_n, r1 = sc[side * 2 + 1] * inv_n;
  float mm = fmaxf(r0, r1);
  float e0 = __expf(r0 - mm), e1 = __expf(r1 - mm);
  const float a0 = e0 / (e0 + e1), a1 = e1 / (e0 + e1);
  const int t = threadIdx.x;
  const int w = t >> 6, l = t & 63;
  const int lrow = l & 15, kgrp = l >> 4;
  const int base = (bid - side * FB) * 64;
  int arow = base + w * 16 + lrow;
  if (arow >= N) arow = N - 1;

  bf16x8 Af[8];
#pragma unroll
  for (int ks = 0; ks < 8; ++ks) {
    const ush* p0 = &z0[(size_t)arow * HID + ks * 32 + kgrp * 8];
    const ush* p1 = &z1[(size_t)arow * HID + ks * 32 + kgrp * 8];
    ushort4 u0a = *(const ushort4*)p0, u0b = *(const ushort4*)(p0 + 4);
    ushort4 u1a = *(const ushort4*)p1, u1b = *(const ushort4*)(p1 + 4);
    union { u32 u[4]; bf16x8 v; } c;
    c.u[0] = pk2(a0 * bf2f(u0a.x) + a1 * bf2f(u1a.x),
                 a0 * bf2f(u0a.y) + a1 * bf2f(u1a.y));
    c.u[1] = pk2(a0 * bf2f(u0a.z) + a1 * bf2f(u1a.z),
                 a0 * bf2f(u0a.w) + a1 * bf2f(u1a.w));
    c.u[2] = pk2(a0 * bf2f(u0b.x) + a1 * bf2f(u1b.x),
                 a0 * bf2f(u0b.y) + a1 * bf2f(u1b.y));
    c.u[3] = pk2(a0 * bf2f(u0b.z) + a1 * bf2f(u1b.z),
                 a0 * bf2f(u0b.w) + a1 * bf2f(u1b.w));
    Af[ks] = c.v;
  }

#pragma unroll
  for (int nt = 0; nt < 4; ++nt) {
    const int col = nt * 16 + lrow;
    f32x4 acc = {0.f, 0.f, 0.f, 0.f};
#pragma unroll
    for (int ks = 0; ks < 8; ++ks) {
      bf16x8 Bf = *(const bf16x8*)&wlT[(size_t)col * HID + ks * 32 + kgrp * 8];
      acc = __builtin_amdgcn_mfma_f32_16x16x32_bf16(Af[ks], Bf, acc, 0, 0, 0);
    }
    const float bb = bl[col];
#pragma unroll
    for (int i = 0; i < 4; ++i) {
      int gr = base + w * 16 + kgrp * 4 + i;
      if (gr < N) op[(size_t)gr * OUTD + col] = acc[i] + bb;
    }
  }
}

// ---------------------------------------------------------------------------
extern "C" void kernel_launch(void* const* d_in, const int* in_sizes, int n_in,
                              void* d_out, int out_size, void* d_ws, size_t ws_size,
                              hipStream_t stream)
{
  const float* x_user = (const float*)d_in[0];
  const float* x_item = (const float*)d_in[1];
  const int*   e_ui   = (const int*)d_in[2];
  const int*   e_iu   = (const int*)d_in[3];
  const int*   e_uu   = (const int*)d_in[4];
  const int*   e_ii   = (const int*)d_in[5];
  const float* Wp_u   = (const float*)d_in[6];
  const float* bp_u   = (const float*)d_in[7];
  const float* Wp_i   = (const float*)d_in[8];
  const float* bp_i   = (const float*)d_in[9];
  const float* as_ui  = (const float*)d_in[10];
  const float* ad_ui  = (const float*)d_in[11];
  const float* as_iu  = (const float*)d_in[12];
  const float* ad_iu  = (const float*)d_in[13];
  const float* as_uu  = (const float*)d_in[14];
  const float* ad_uu  = (const float*)d_in[15];
  const float* as_ii  = (const float*)d_in[16];
  const float* ad_ii  = (const float*)d_in[17];
  const float* Wk     = (const float*)d_in[18];
  const float* bk     = (const float*)d_in[19];
  const float* q      = (const float*)d_in[20];
  const float* Wl     = (const float*)d_in[21];
  const float* bl     = (const float*)d_in[22];

  const size_t NH = (size_t)N * HID;
  const size_t WT = 65536 + 2 * 32768 + 16384;
  size_t need = (8 * (size_t)N8 + 8) * 4
              + (6 * NH + WT) * 2
              + ((size_t)8 * N + (size_t)NBT * BCAP + NBT) * 4;
  if (ws_size < need) {
    hipMemsetAsync(d_out, 0x7f, (size_t)out_size * sizeof(float), stream);
    return;
  }
  float* su = (float*)d_ws;
  float* si = su + 4 * (size_t)N8;
  float* sc = si + 4 * (size_t)N8;
  ush* zbu0 = (ush*)(sc + 8);
  ush* zbu1 = zbu0 + NH;
  ush* zbi0 = zbu1 + NH;
  ush* zbi1 = zbi0 + NH;
  ush* hub  = zbi1 + NH;
  ush* hib  = hub + NH;
  ush* wkT  = hib + NH;
  ush* wpTu = wkT + 65536;
  ush* wpTi = wpTu + 32768;
  ush* wlT  = wpTi + 32768;
  int* count  = (int*)(wlT + 16384);
  int* start  = count + NTOT;
  int* bcnt   = start + NTOT;
  int* csr    = bcnt + NBT;
  u32* bstage = (u32*)zbu0;     // 16.0 MB <= 25.6 MB (dead until conv)

  // 1. weight transposes + zero bcnt/sc
  tran_kernel<<<576, 256, 0, stream>>>(Wk, Wp_u, Wp_i, Wl, wkT, wpTu, wpTi, wlT,
                                       bcnt, sc);
  // 2. projections + fused node scores (both types)
  proj_kernel<<<2 * FB, 256, 0, stream>>>(x_user, x_item, wpTu, wpTi, bp_u, bp_i,
                                          ad_iu, as_uu, ad_uu, as_ui,
                                          as_iu, ad_ui, as_ii, ad_ii,
                                          hub, hib, su, si);
  // 3. multisplit into fixed-capacity buckets (single edge pass)
  scat2_kernel<<<4 * NB1, 256, 0, stream>>>(e_iu, e_iu + E, e_uu, e_uu + E,
                                            e_ui, e_ui + E, e_ii, e_ii + E,
                                            bcnt, bstage);
  // 4. fused fine count + scan + csr fill
  fillb_kernel<<<NBT, 256, 0, stream>>>(bstage, bcnt, start, count, csr);
  // 5. all 4 relation convs
  conv_kernel<<<NTOT / 4, 256, 0, stream>>>(hub, hib, su, si, csr, start, count, zbu0);
  // 6. semantic attention scores
  semscore_kernel<<<4 * SMT, 512, 0, stream>>>(zbu0, zbu1, zbi0, zbi1, wkT, bk, q, sc);
  // 7. final linear (softmax inline)
  final_kernel<<<2 * FB, 256, 0, stream>>>(zbu0, zbu1, zbi0, zbi1, sc, wlT, bl,
                                           (float*)d_out);
}

// Round 15
// 674.329 us; speedup vs baseline: 2.9720x; 1.0176x over previous
//
#include <hip/hip_runtime.h>
#include <math.h>

#define N     50000
#define F_IN  128
#define HID   256
#define E     800000
#define OUTD  64
#define NEG   0.2f
#define N8    (N * 8)
#define NTOT  (4 * N)
#define FB    ((N + 63) / 64)        // 782 64-row blocks (proj/semscore/final)

// bucket sort geometry (fixed-capacity buckets)
#define BSH   7
#define NBUK  ((N + 127) / 128)      // 391
#define NBT   (4 * NBUK)             // 1564
#define BCAP  2560                   // Poisson(2048) + 11 sigma headroom
#define EPB1  8192
#define NB1   ((E + EPB1 - 1) / EPB1) // 98

typedef float4 f4;
typedef unsigned int u32;
typedef unsigned short ush;
typedef float f32x4 __attribute__((ext_vector_type(4)));
typedef short bf16x8 __attribute__((ext_vector_type(8)));

static __device__ __forceinline__ float lrelu(float x) { return x >= 0.f ? x : NEG * x; }
static __device__ __forceinline__ u32 bfr(float x) {
  u32 u = __float_as_uint(x);
  return (u + 0x7fffu + ((u >> 16) & 1u)) >> 16;
}
static __device__ __forceinline__ u32 pk2(float a, float b) { return bfr(a) | (bfr(b) << 16); }
static __device__ __forceinline__ float bf2f(u32 us) { return __uint_as_float(us << 16); }
static __device__ __forceinline__ float tanh_fast(float x) {
  float e = __expf(2.f * x);
  return fmaf(-2.f, __builtin_amdgcn_rcpf(e + 1.f), 1.f);
}

// ---------------------------------------------------------------------------
// Weight precompute (bf16 transposes) + zero bcnt.
// ---------------------------------------------------------------------------
__global__ void tran_kernel(const float* __restrict__ Wk,
                            const float* __restrict__ Wpu,
                            const float* __restrict__ Wpi,
                            const float* __restrict__ Wl,
                            ush* __restrict__ wkT, ush* __restrict__ wpTu,
                            ush* __restrict__ wpTi, ush* __restrict__ wlT,
                            int* __restrict__ bcnt)
{
  int idx = blockIdx.x * 256 + threadIdx.x;
  if (idx < NBT) bcnt[idx] = 0;
  const float* src; ush* dst; int K, M, li;
  if (idx < 65536)       { src = Wk;  dst = wkT;  K = 256; M = 256; li = idx; }
  else if (idx < 98304)  { src = Wpu; dst = wpTu; K = 128; M = 256; li = idx - 65536; }
  else if (idx < 131072) { src = Wpi; dst = wpTi; K = 128; M = 256; li = idx - 98304; }
  else                   { src = Wl;  dst = wlT;  K = 256; M = 64;  li = idx - 131072; }
  int m = li / K, k = li % K;
  dst[li] = (ush)bfr(src[k * M + m]);
}

// ---------------------------------------------------------------------------
// Projection + FUSED node scores (R14, unchanged).
// ---------------------------------------------------------------------------
__global__ __launch_bounds__(256) void proj_kernel(
    const float* __restrict__ xu, const float* __restrict__ xi,
    const ush* __restrict__ wpTu, const ush* __restrict__ wpTi,
    const float* __restrict__ bu, const float* __restrict__ bi,
    const float* __restrict__ au0, const float* __restrict__ au1,
    const float* __restrict__ au2, const float* __restrict__ au3,
    const float* __restrict__ ai0, const float* __restrict__ ai1,
    const float* __restrict__ ai2, const float* __restrict__ ai3,
    ush* __restrict__ hu, ush* __restrict__ hi,
    float* __restrict__ su, float* __restrict__ si)
{
  const int bid = blockIdx.x;
  const int side = bid >= FB;
  const float* x = side ? xi : xu;
  const ush* wpT = side ? wpTi : wpTu;
  const float* b = side ? bi : bu;
  ush* hb = side ? hi : hu;
  float* sdst = side ? si : su;
  const float* a0 = side ? ai0 : au0;
  const float* a1 = side ? ai1 : au1;
  const float* a2 = side ? ai2 : au2;
  const float* a3 = side ? ai3 : au3;
  const int t = threadIdx.x;
  const int w = t >> 6, l = t & 63;
  const int lrow = l & 15, kgrp = l >> 4;
  const int base = (bid - side * FB) * 64;
  int arow = base + w * 16 + lrow;
  if (arow >= N) arow = N - 1;

  bf16x8 Af[4];
#pragma unroll
  for (int ks = 0; ks < 4; ++ks) {
    const float* px = &x[(size_t)arow * F_IN + ks * 32 + kgrp * 8];
    f4 v0 = *(const f4*)px;
    f4 v1 = *(const f4*)(px + 4);
    union { u32 u[4]; bf16x8 v; } c;
    c.u[0] = pk2(v0.x, v0.y); c.u[1] = pk2(v0.z, v0.w);
    c.u[2] = pk2(v1.x, v1.y); c.u[3] = pk2(v1.z, v1.w);
    Af[ks] = c.v;
  }

  float pk[4][4] = {};
#pragma unroll
  for (int nt = 0; nt < 16; ++nt) {
    const int col = nt * 16 + lrow;
    f32x4 acc = {0.f, 0.f, 0.f, 0.f};
#pragma unroll
    for (int ks = 0; ks < 4; ++ks) {
      bf16x8 Bf = *(const bf16x8*)&wpT[(size_t)col * F_IN + ks * 32 + kgrp * 8];
      acc = __builtin_amdgcn_mfma_f32_16x16x32_bf16(Af[ks], Bf, acc, 0, 0, 0);
    }
    const float bb = b[col];
    const float av0 = a0[col], av1 = a1[col], av2 = a2[col], av3 = a3[col];
#pragma unroll
    for (int i = 0; i < 4; ++i) {
      float hv = acc[i] + bb;
      int gr = base + w * 16 + kgrp * 4 + i;
      if (gr < N) hb[(size_t)gr * HID + col] = (ush)bfr(hv);
      pk[0][i] = fmaf(hv, av0, pk[0][i]);
      pk[1][i] = fmaf(hv, av1, pk[1][i]);
      pk[2][i] = fmaf(hv, av2, pk[2][i]);
      pk[3][i] = fmaf(hv, av3, pk[3][i]);
    }
    if (nt & 1) {
      const int head = nt >> 1;
#pragma unroll
      for (int k = 0; k < 4; ++k)
#pragma unroll
        for (int i = 0; i < 4; ++i) {
          float p = pk[k][i];
          p += __shfl_xor(p, 1);
          p += __shfl_xor(p, 2);
          p += __shfl_xor(p, 4);
          p += __shfl_xor(p, 8);
          int gr = base + w * 16 + kgrp * 4 + i;
          if (lrow == 0 && gr < N)
            sdst[(size_t)k * N8 + (size_t)gr * 8 + head] = p;
          pk[k][i] = 0.f;
        }
    }
  }
}

// ---------------------------------------------------------------------------
// scat2 single-pass (R14, unchanged).
// ---------------------------------------------------------------------------
__global__ __launch_bounds__(256) void scat2_kernel(
    const int* __restrict__ s0, const int* __restrict__ d0,
    const int* __restrict__ s1, const int* __restrict__ d1,
    const int* __restrict__ s2, const int* __restrict__ d2,
    const int* __restrict__ s3, const int* __restrict__ d3,
    int* __restrict__ bcnt, u32* __restrict__ bstage)
{
  __shared__ int lh[NBUK];
  const int rel = blockIdx.x / NB1;
  const int blk = blockIdx.x % NB1;
  const int* sp = rel == 0 ? s0 : rel == 1 ? s1 : rel == 2 ? s2 : s3;
  const int* dp = rel == 0 ? d0 : rel == 1 ? d1 : rel == 2 ? d2 : d3;
  for (int j = threadIdx.x; j < NBUK; j += 256) lh[j] = 0;
  __syncthreads();
  const int base = blk * EPB1;
  int sr[32], dr[32];
#pragma unroll
  for (int k = 0; k < 32; ++k) {
    int i = base + k * 256 + threadIdx.x;
    sr[k] = (i < E) ? sp[i] : -1;
    dr[k] = (i < E) ? dp[i] : -1;
  }
#pragma unroll
  for (int k = 0; k < 32; ++k)
    if (dr[k] >= 0) atomicAdd(&lh[dr[k] >> BSH], 1);
  __syncthreads();
  for (int j = threadIdx.x; j < NBUK; j += 256) {
    int c = lh[j];
    int gb = rel * NBUK + j;
    lh[j] = c ? gb * BCAP + atomicAdd(&bcnt[gb], c) : 0;
  }
  __syncthreads();
#pragma unroll
  for (int k = 0; k < 32; ++k)
    if (dr[k] >= 0) {
      int pos = atomicAdd(&lh[dr[k] >> BSH], 1);
      bstage[pos] = ((u32)dr[k] << 16) | (u32)sr[k];
    }
}

// ---------------------------------------------------------------------------
// Fused fillb (R13, unchanged).
// ---------------------------------------------------------------------------
__global__ __launch_bounds__(256) void fillb_kernel(
    const u32* __restrict__ bstage, const int* __restrict__ bcnt,
    int* __restrict__ start, int* __restrict__ count, int* __restrict__ csr)
{
  __shared__ int lcnt[128];
  __shared__ int lpos[128];
  const int bb = blockIdx.x;
  const int rel = bb / NBUK, b = bb % NBUK;
  const int base = bb * BCAP;
  const int cnt = bcnt[bb];
  const int t = threadIdx.x;
  if (t < 128) lcnt[t] = 0;
  __syncthreads();
  for (int k = t; k < cnt; k += 256)
    atomicAdd(&lcnt[(bstage[base + k] >> 16) & 127], 1);
  __syncthreads();
  if (t < 128) lpos[t] = lcnt[t];
  __syncthreads();
  for (int off = 1; off < 128; off <<= 1) {
    int v = (t < 128 && t >= off) ? lpos[t - off] : 0;
    __syncthreads();
    if (t < 128) lpos[t] += v;
    __syncthreads();
  }
  const int fb = rel * N + b * 128;
  const int lim = min(128, N - b * 128);
  if (t < 128) {
    int ex = base + lpos[t] - lcnt[t];
    if (t < lim) {
      start[fb + t] = ex;
      count[fb + t] = lcnt[t];
    }
    lcnt[t] = ex;
  }
  __syncthreads();
  for (int k = t; k < cnt; k += 256) {
    u32 pk = bstage[base + k];
    int pos = atomicAdd(&lcnt[(pk >> 16) & 127], 1);
    csr[pos] = (int)(pk & 0xffffu);
  }
}

// ---------------------------------------------------------------------------
// Relation conv (R11 single-pass, 8-edge batches) — at its gather-BW floor.
// ---------------------------------------------------------------------------
#define CONV_EDGE(sx)                                                     \
  {                                                                       \
    float al = __expf(lrelu(lg##sx + sdv2));                              \
    den += al;                                                            \
    a0 = fmaf(al, bf2f(v##sx.x), a0); a1 = fmaf(al, bf2f(v##sx.y), a1);   \
    a2 = fmaf(al, bf2f(v##sx.z), a2); a3 = fmaf(al, bf2f(v##sx.w), a3);   \
  }

__global__ __launch_bounds__(256) void conv_kernel(
    const ush* __restrict__ hub, const ush* __restrict__ hib,
    const float* __restrict__ su, const float* __restrict__ si,
    const int* __restrict__ csr,
    const int* __restrict__ start, const int* __restrict__ count,
    ush* __restrict__ zall)
{
  const int rel = blockIdx.x / (N / 4);
  const int lb  = blockIdx.x % (N / 4);
  const int dst = lb * 4 + (threadIdx.x >> 6);
  const int lane = threadIdx.x & 63;
  const ush* xsb = (rel == 0 || rel == 3) ? hib : hub;
  const float* ss = rel == 0 ? si : rel == 1 ? su + N8 :
                    rel == 2 ? su + 3 * (size_t)N8 : si + 2 * (size_t)N8;
  const float* sd = rel == 0 ? su : rel == 1 ? su + 2 * (size_t)N8 :
                    rel == 2 ? si + N8 : si + 3 * (size_t)N8;
  const int grow = rel * N + dst;
  const int e0 = start[grow];
  const int ne = count[grow];

  const int h2 = lane >> 3;
  const float sdv2 = sd[dst * 8 + h2];

  float den = 0.f;
  float a0 = 0.f, a1 = 0.f, a2 = 0.f, a3 = 0.f;
  int j = 0;
  for (; j + 8 <= ne; j += 8) {
    int s0_ = csr[e0 + j + 0], s1_ = csr[e0 + j + 1];
    int s2_ = csr[e0 + j + 2], s3_ = csr[e0 + j + 3];
    int s4_ = csr[e0 + j + 4], s5_ = csr[e0 + j + 5];
    int s6_ = csr[e0 + j + 6], s7_ = csr[e0 + j + 7];
    float lg0 = ss[s0_ * 8 + h2], lg1 = ss[s1_ * 8 + h2];
    float lg2 = ss[s2_ * 8 + h2], lg3 = ss[s3_ * 8 + h2];
    float lg4 = ss[s4_ * 8 + h2], lg5 = ss[s5_ * 8 + h2];
    float lg6 = ss[s6_ * 8 + h2], lg7 = ss[s7_ * 8 + h2];
    ushort4 v0 = *(const ushort4*)&xsb[(size_t)s0_ * HID + lane * 4];
    ushort4 v1 = *(const ushort4*)&xsb[(size_t)s1_ * HID + lane * 4];
    ushort4 v2 = *(const ushort4*)&xsb[(size_t)s2_ * HID + lane * 4];
    ushort4 v3 = *(const ushort4*)&xsb[(size_t)s3_ * HID + lane * 4];
    ushort4 v4 = *(const ushort4*)&xsb[(size_t)s4_ * HID + lane * 4];
    ushort4 v5 = *(const ushort4*)&xsb[(size_t)s5_ * HID + lane * 4];
    ushort4 v6 = *(const ushort4*)&xsb[(size_t)s6_ * HID + lane * 4];
    ushort4 v7 = *(const ushort4*)&xsb[(size_t)s7_ * HID + lane * 4];
    CONV_EDGE(0) CONV_EDGE(1) CONV_EDGE(2) CONV_EDGE(3)
    CONV_EDGE(4) CONV_EDGE(5) CONV_EDGE(6) CONV_EDGE(7)
  }
  for (; j + 2 <= ne; j += 2) {
    int s0_ = csr[e0 + j + 0], s1_ = csr[e0 + j + 1];
    float lg0 = ss[s0_ * 8 + h2], lg1 = ss[s1_ * 8 + h2];
    ushort4 v0 = *(const ushort4*)&xsb[(size_t)s0_ * HID + lane * 4];
    ushort4 v1 = *(const ushort4*)&xsb[(size_t)s1_ * HID + lane * 4];
    CONV_EDGE(0) CONV_EDGE(1)
  }
  if (j < ne) {
    int s0_ = csr[e0 + j];
    float lg0 = ss[s0_ * 8 + h2];
    ushort4 v0 = *(const ushort4*)&xsb[(size_t)s0_ * HID + lane * 4];
    CONV_EDGE(0)
  }
  const float inv = 1.f / (den + 1e-16f);
  ushort4 o;
  o.x = (ush)bfr(fmaxf(a0 * inv, 0.f));
  o.y = (ush)bfr(fmaxf(a1 * inv, 0.f));
  o.z = (ush)bfr(fmaxf(a2 * inv, 0.f));
  o.w = (ush)bfr(fmaxf(a3 * inv, 0.f));
  *(ushort4*)&zall[(size_t)grow * HID + lane * 4] = o;
}

// ---------------------------------------------------------------------------
// Semantic scores v6 — final_kernel structure: Af[8] register-resident
// straight from bf16 z (no LDS, no barriers, no vmcnt games), B from L2-hot
// wkT, fused tanh*q epilogue, block-reduce, ONE PLAIN STORE per block
// (parts[bid]).  Replaces v5's 12.5k same-address fp32 atomics (the inferred
// 100-200us serialization tail) with 3128 distinct stores.
// ---------------------------------------------------------------------------
__global__ __launch_bounds__(256) void semscore_kernel(
    const ush* __restrict__ zbu0, const ush* __restrict__ zbu1,
    const ush* __restrict__ zbi0, const ush* __restrict__ zbi1,
    const ush* __restrict__ wkT, const float* __restrict__ bk,
    const float* __restrict__ q, float* __restrict__ parts)
{
  __shared__ float red[4];
  const int bid = blockIdx.x;
  const int mat = bid / FB;
  const int mt  = bid % FB;
  const ush* zsrc = mat == 0 ? zbu0 : mat == 1 ? zbu1 : mat == 2 ? zbi0 : zbi1;
  const int t = threadIdx.x;
  const int w = t >> 6, l = t & 63;
  const int lrow = l & 15, kgrp = l >> 4;
  const int base = mt * 64;
  int arow = base + w * 16 + lrow;
  if (arow >= N) arow = N - 1;

  bf16x8 Af[8];
#pragma unroll
  for (int ks = 0; ks < 8; ++ks)
    Af[ks] = *(const bf16x8*)&zsrc[(size_t)arow * HID + ks * 32 + kgrp * 8];

  float s = 0.f;
#pragma unroll
  for (int nt = 0; nt < 16; ++nt) {
    const int col = nt * 16 + lrow;
    f32x4 acc = {0.f, 0.f, 0.f, 0.f};
#pragma unroll
    for (int ks = 0; ks < 8; ++ks) {
      bf16x8 Bf = *(const bf16x8*)&wkT[(size_t)col * HID + ks * 32 + kgrp * 8];
      acc = __builtin_amdgcn_mfma_f32_16x16x32_bf16(Af[ks], Bf, acc, 0, 0, 0);
    }
    const float bkv = bk[col], qv = q[col];
#pragma unroll
    for (int i = 0; i < 4; ++i) {
      int gr = base + w * 16 + kgrp * 4 + i;
      if (gr < N) s += tanh_fast(acc[i] + bkv) * qv;
    }
  }
#pragma unroll
  for (int off = 1; off < 64; off <<= 1) s += __shfl_xor(s, off);
  if (l == 0) red[w] = s;
  __syncthreads();
  if (t == 0) parts[bid] = red[0] + red[1] + red[2] + red[3];
}

// ---------------------------------------------------------------------------
// Final: out = (a0*z0 + a1*z1) @ Wl + bl via bf16 MFMA.  Each block
// redundantly reduces its side's 2x782 semscore partials (L2-broadcast, ~6KB)
// and computes the 2-way softmax inline — no atomics, no extra launch.
// ---------------------------------------------------------------------------
__global__ __launch_bounds__(256) void final_kernel(
    const ush* __restrict__ zbu0, const ush* __restrict__ zbu1,
    const ush* __restrict__ zbi0, const ush* __restrict__ zbi1,
    const float* __restrict__ parts, const ush* __restrict__ wlT,
    const float* __restrict__ bl, float* __restrict__ out)
{
  __shared__ float redA[4], redB[4], attn[2];
  const int bid = blockIdx.x;
  const int side = bid >= FB;
  const ush* z0 = side ? zbi0 : zbu0;
  const ush* z1 = side ? zbi1 : zbu1;
  float* op = out + (size_t)side * N * OUTD;
  const int t = threadIdx.x;
  const int w = t >> 6, l = t & 63;

  // reduce semscore partials for this side's two matrices
  const float* p0 = parts + (size_t)(side * 2) * FB;
  const float* p1 = p0 + FB;
  float s0 = 0.f, s1 = 0.f;
  for (int i = t; i < FB; i += 256) { s0 += p0[i]; s1 += p1[i]; }
#pragma unroll
  for (int off = 1; off < 64; off <<= 1) {
    s0 += __shfl_xor(s0, off);
    s1 += __shfl_xor(s1, off);
  }
  if (l == 0) { redA[w] = s0; redB[w] = s1; }
  __syncthreads();
  if (t == 0) {
    const float inv_n = 1.f / (float)N;
    float r0 = (redA[0] + redA[1] + redA[2] + redA[3]) * inv_n;
    float r1 = (redB[0] + redB[1] + redB[2] + redB[3]) * inv_n;
    float mm = fmaxf(r0, r1);
    float e0 = __expf(r0 - mm), e1 = __expf(r1 - mm);
    attn[0] = e0 / (e0 + e1);
    attn[1] = e1 / (e0 + e1);
  }
  __syncthreads();
  const float a0 = attn[0], a1 = attn[1];

  const int lrow = l & 15, kgrp = l >> 4;
  const int base = (bid - side * FB) * 64;
  int arow = base + w * 16 + lrow;
  if (arow >= N) arow = N - 1;

  bf16x8 Af[8];
#pragma unroll
  for (int ks = 0; ks < 8; ++ks) {
    const ush* pz0 = &z0[(size_t)arow * HID + ks * 32 + kgrp * 8];
    const ush* pz1 = &z1[(size_t)arow * HID + ks * 32 + kgrp * 8];
    ushort4 u0a = *(const ushort4*)pz0, u0b = *(const ushort4*)(pz0 + 4);
    ushort4 u1a = *(const ushort4*)pz1, u1b = *(const ushort4*)(pz1 + 4);
    union { u32 u[4]; bf16x8 v; } c;
    c.u[0] = pk2(a0 * bf2f(u0a.x) + a1 * bf2f(u1a.x),
                 a0 * bf2f(u0a.y) + a1 * bf2f(u1a.y));
    c.u[1] = pk2(a0 * bf2f(u0a.z) + a1 * bf2f(u1a.z),
                 a0 * bf2f(u0a.w) + a1 * bf2f(u1a.w));
    c.u[2] = pk2(a0 * bf2f(u0b.x) + a1 * bf2f(u1b.x),
                 a0 * bf2f(u0b.y) + a1 * bf2f(u1b.y));
    c.u[3] = pk2(a0 * bf2f(u0b.z) + a1 * bf2f(u1b.z),
                 a0 * bf2f(u0b.w) + a1 * bf2f(u1b.w));
    Af[ks] = c.v;
  }

#pragma unroll
  for (int nt = 0; nt < 4; ++nt) {
    const int col = nt * 16 + lrow;
    f32x4 acc = {0.f, 0.f, 0.f, 0.f};
#pragma unroll
    for (int ks = 0; ks < 8; ++ks) {
      bf16x8 Bf = *(const bf16x8*)&wlT[(size_t)col * HID + ks * 32 + kgrp * 8];
      acc = __builtin_amdgcn_mfma_f32_16x16x32_bf16(Af[ks], Bf, acc, 0, 0, 0);
    }
    const float bb = bl[col];
#pragma unroll
    for (int i = 0; i < 4; ++i) {
      int gr = base + w * 16 + kgrp * 4 + i;
      if (gr < N) op[(size_t)gr * OUTD + col] = acc[i] + bb;
    }
  }
}

// ---------------------------------------------------------------------------
extern "C" void kernel_launch(void* const* d_in, const int* in_sizes, int n_in,
                              void* d_out, int out_size, void* d_ws, size_t ws_size,
                              hipStream_t stream)
{
  const float* x_user = (const float*)d_in[0];
  const float* x_item = (const float*)d_in[1];
  const int*   e_ui   = (const int*)d_in[2];
  const int*   e_iu   = (const int*)d_in[3];
  const int*   e_uu   = (const int*)d_in[4];
  const int*   e_ii   = (const int*)d_in[5];
  const float* Wp_u   = (const float*)d_in[6];
  const float* bp_u   = (const float*)d_in[7];
  const float* Wp_i   = (const float*)d_in[8];
  const float* bp_i   = (const float*)d_in[9];
  const float* as_ui  = (const float*)d_in[10];
  const float* ad_ui  = (const float*)d_in[11];
  const float* as_iu  = (const float*)d_in[12];
  const float* ad_iu  = (const float*)d_in[13];
  const float* as_uu  = (const float*)d_in[14];
  const float* ad_uu  = (const float*)d_in[15];
  const float* as_ii  = (const float*)d_in[16];
  const float* ad_ii  = (const float*)d_in[17];
  const float* Wk     = (const float*)d_in[18];
  const float* bk     = (const float*)d_in[19];
  const float* q      = (const float*)d_in[20];
  const float* Wl     = (const float*)d_in[21];
  const float* bl     = (const float*)d_in[22];

  const size_t NH = (size_t)N * HID;
  const size_t WT = 65536 + 2 * 32768 + 16384;
  size_t need = (8 * (size_t)N8 + 4 * (size_t)FB) * 4
              + (6 * NH + WT) * 2
              + ((size_t)8 * N + (size_t)NBT * BCAP + NBT) * 4;
  if (ws_size < need) {
    hipMemsetAsync(d_out, 0x7f, (size_t)out_size * sizeof(float), stream);
    return;
  }
  float* su = (float*)d_ws;
  float* si = su + 4 * (size_t)N8;
  float* parts = si + 4 * (size_t)N8;          // 4*FB floats
  ush* zbu0 = (ush*)(parts + 4 * (size_t)FB);  // 16B-aligned (12512B offset)
  ush* zbu1 = zbu0 + NH;
  ush* zbi0 = zbu1 + NH;
  ush* zbi1 = zbi0 + NH;
  ush* hub  = zbi1 + NH;
  ush* hib  = hub + NH;
  ush* wkT  = hib + NH;
  ush* wpTu = wkT + 65536;
  ush* wpTi = wpTu + 32768;
  ush* wlT  = wpTi + 32768;
  int* count  = (int*)(wlT + 16384);
  int* start  = count + NTOT;
  int* bcnt   = start + NTOT;
  int* csr    = bcnt + NBT;
  u32* bstage = (u32*)zbu0;     // 16.0 MB <= 25.6 MB (dead until conv)

  // 1. weight transposes + zero bcnt
  tran_kernel<<<576, 256, 0, stream>>>(Wk, Wp_u, Wp_i, Wl, wkT, wpTu, wpTi, wlT,
                                       bcnt);
  // 2. projections + fused node scores (both types)
  proj_kernel<<<2 * FB, 256, 0, stream>>>(x_user, x_item, wpTu, wpTi, bp_u, bp_i,
                                          ad_iu, as_uu, ad_uu, as_ui,
                                          as_iu, ad_ui, as_ii, ad_ii,
                                          hub, hib, su, si);
  // 3. multisplit into fixed-capacity buckets (single edge pass)
  scat2_kernel<<<4 * NB1, 256, 0, stream>>>(e_iu, e_iu + E, e_uu, e_uu + E,
                                            e_ui, e_ui + E, e_ii, e_ii + E,
                                            bcnt, bstage);
  // 4. fused fine count + scan + csr fill
  fillb_kernel<<<NBT, 256, 0, stream>>>(bstage, bcnt, start, count, csr);
  // 5. all 4 relation convs
  conv_kernel<<<NTOT / 4, 256, 0, stream>>>(hub, hib, su, si, csr, start, count, zbu0);
  // 6. semantic attention partials (no atomics)
  semscore_kernel<<<4 * FB, 256, 0, stream>>>(zbu0, zbu1, zbi0, zbi1, wkT, bk, q, parts);
  // 7. final linear (partial-reduce + softmax inline)
  final_kernel<<<2 * FB, 256, 0, stream>>>(zbu0, zbu1, zbi0, zbi1, parts, wlT, bl,
                                           (float*)d_out);
}